// Round 2
// baseline (14193.298 us; speedup 1.0000x reference)
//
#include <hip/hip_runtime.h>
#include <math.h>

// EGNN forward, fp32, fused edge-MLP with P/Q node-side factorization.
// Layers: H=64, NUM_LAYERS=4, EDGE_D=3, IN_C=26, G graphs (from out_size/2).

__device__ __forceinline__ float silu_f(float x) { return x / (1.0f + __expf(-x)); }

// acc[64] += scal * rowptr[0..63]   (rowptr 16B-aligned, LDS or global)
#define ROW_FMA(acc, scal, rowptr)                                                   \
  {                                                                                  \
    const float4* _w = (const float4*)(rowptr);                                      \
    _Pragma("unroll") for (int _j = 0; _j < 16; _j++)                                \
    {                                                                                \
      float4 _wv = _w[_j];                                                           \
      acc[4 * _j + 0] += (scal) * _wv.x;                                             \
      acc[4 * _j + 1] += (scal) * _wv.y;                                             \
      acc[4 * _j + 2] += (scal) * _wv.z;                                             \
      acc[4 * _j + 3] += (scal) * _wv.w;                                             \
    }                                                                                \
  }

// ---------------- proj: h = x @ proj_W + proj_b ----------------
__global__ __launch_bounds__(256) void proj_kernel(
    const float* __restrict__ x, const float* __restrict__ W, const float* __restrict__ b,
    float* __restrict__ h, int N)
{
  __shared__ float sW[26 * 64];
  __shared__ float sb[64];
  for (int i = threadIdx.x; i < 26 * 64; i += 256) sW[i] = W[i];
  if (threadIdx.x < 64) sb[threadIdx.x] = b[threadIdx.x];
  __syncthreads();
  int n = blockIdx.x * 256 + threadIdx.x;
  if (n >= N) return;
  float acc[64];
#pragma unroll
  for (int j = 0; j < 64; j++) acc[j] = sb[j];
#pragma unroll
  for (int k = 0; k < 26; k++) {
    float xk = x[(size_t)n * 26 + k];
    ROW_FMA(acc, xk, sW + k * 64);
  }
  float4* h4 = (float4*)(h + (size_t)n * 64);
#pragma unroll
  for (int j4 = 0; j4 < 16; j4++) {
    float4 v;
    v.x = acc[4 * j4 + 0]; v.y = acc[4 * j4 + 1]; v.z = acc[4 * j4 + 2]; v.w = acc[4 * j4 + 3];
    h4[j4] = v;
  }
}

// ---------------- premul: P = h @ W1[0:64], Q = h @ W1[64:128] ----------------
__global__ __launch_bounds__(256) void premul_kernel(
    const float* __restrict__ h, const float* __restrict__ W1,
    float* __restrict__ P, float* __restrict__ Q, int N)
{
  __shared__ float sW[128 * 64];
  for (int i = threadIdx.x; i < 128 * 64; i += 256) sW[i] = W1[i];
  __syncthreads();
  int n = blockIdx.x * 256 + threadIdx.x;
  if (n >= N) return;
  float hr[64];
  const float4* h4 = (const float4*)(h + (size_t)n * 64);
#pragma unroll
  for (int i = 0; i < 16; i++) {
    float4 v = h4[i];
    hr[4 * i] = v.x; hr[4 * i + 1] = v.y; hr[4 * i + 2] = v.z; hr[4 * i + 3] = v.w;
  }
  float acc[64];
#pragma unroll
  for (int j = 0; j < 64; j++) acc[j] = 0.f;
#pragma unroll
  for (int k = 0; k < 64; k++) { ROW_FMA(acc, hr[k], sW + k * 64); }
  float4* P4 = (float4*)(P + (size_t)n * 64);
#pragma unroll
  for (int j4 = 0; j4 < 16; j4++) {
    float4 v;
    v.x = acc[4 * j4 + 0]; v.y = acc[4 * j4 + 1]; v.z = acc[4 * j4 + 2]; v.w = acc[4 * j4 + 3];
    P4[j4] = v;
  }
#pragma unroll
  for (int j = 0; j < 64; j++) acc[j] = 0.f;
#pragma unroll
  for (int k = 0; k < 64; k++) { ROW_FMA(acc, hr[k], sW + (64 + k) * 64); }
  float4* Q4 = (float4*)(Q + (size_t)n * 64);
#pragma unroll
  for (int j4 = 0; j4 < 16; j4++) {
    float4 v;
    v.x = acc[4 * j4 + 0]; v.y = acc[4 * j4 + 1]; v.z = acc[4 * j4 + 2]; v.w = acc[4 * j4 + 3];
    Q4[j4] = v;
  }
}

// ---------------- edge kernel: fused msg MLP + agg atomics + coord update ----------------
template <int COORD>
__global__ __launch_bounds__(256) void edge_kernel(
    const int* __restrict__ row, const int* __restrict__ col,
    const float* __restrict__ posr, float* __restrict__ posw,
    const float* __restrict__ eattr,
    const float* __restrict__ P, const float* __restrict__ Q,
    const float* __restrict__ W1t,  // rows 128..131 of msg_W1 (dist, ea0..2): [4][64]
    const float* __restrict__ b1, const float* __restrict__ W2, const float* __restrict__ b2,
    const float* __restrict__ cW1, const float* __restrict__ cb1,
    const float* __restrict__ cW2, const float* __restrict__ cb2,
    float* __restrict__ agg, int E)
{
  __shared__ float sW1t[4 * 64];
  __shared__ float sb1[64];
  __shared__ float sW2[64 * 64];
  __shared__ float sb2[64];
  __shared__ float scW1[COORD ? 64 * 64 : 1];
  __shared__ float scb1[COORD ? 64 : 1];
  __shared__ float scW2[COORD ? 64 : 1];

  int tid = threadIdx.x;
  for (int i = tid; i < 4 * 64; i += 256) sW1t[i] = W1t[i];
  for (int i = tid; i < 4096; i += 256) sW2[i] = W2[i];
  if (tid < 64) { sb1[tid] = b1[tid]; sb2[tid] = b2[tid]; }
  if (COORD) {
    for (int i = tid; i < 4096; i += 256) scW1[i] = cW1[i];
    if (tid < 64) { scb1[tid] = cb1[tid]; scW2[tid] = cW2[tid]; }
  }
  __syncthreads();

  int e = blockIdx.x * 256 + tid;
  if (e >= E) return;
  int r = row[e];
  int c = col[e];
  float dx = posr[(size_t)r * 3 + 0] - posr[(size_t)c * 3 + 0];
  float dy = posr[(size_t)r * 3 + 1] - posr[(size_t)c * 3 + 1];
  float dz = posr[(size_t)r * 3 + 2] - posr[(size_t)c * 3 + 2];
  float dist = sqrtf(dx * dx + dy * dy + dz * dz);
  float ea0 = eattr[(size_t)e * 3 + 0];
  float ea1 = eattr[(size_t)e * 3 + 1];
  float ea2 = eattr[(size_t)e * 3 + 2];

  // u = silu(P[r] + Q[c] + dist*W1t[0] + ea*W1t[1..3] + b1)
  float u[64];
  const float4* P4 = (const float4*)(P + (size_t)r * 64);
  const float4* Q4 = (const float4*)(Q + (size_t)c * 64);
#pragma unroll
  for (int j4 = 0; j4 < 16; j4++) {
    float4 p = P4[j4];
    float4 q = Q4[j4];
#pragma unroll
    for (int t = 0; t < 4; t++) {
      int j = 4 * j4 + t;
      float pv = (t == 0) ? p.x : (t == 1) ? p.y : (t == 2) ? p.z : p.w;
      float qv = (t == 0) ? q.x : (t == 1) ? q.y : (t == 2) ? q.z : q.w;
      float v = pv + qv + sb1[j] + dist * sW1t[j] + ea0 * sW1t[64 + j] + ea1 * sW1t[128 + j] +
                ea2 * sW1t[192 + j];
      u[j] = silu_f(v);
    }
  }

  // m = silu(u @ W2 + b2)
  float m[64];
#pragma unroll
  for (int j = 0; j < 64; j++) m[j] = sb2[j];
#pragma unroll
  for (int k = 0; k < 64; k++) { ROW_FMA(m, u[k], sW2 + k * 64); }
#pragma unroll
  for (int j = 0; j < 64; j++) m[j] = silu_f(m[j]);

  // agg[r] += m
  float* ar = agg + (size_t)r * 64;
#pragma unroll
  for (int j = 0; j < 64; j++) atomicAdd(ar + j, m[j]);

  if (COORD) {
    // w = silu(m @ cW1 + cb1) . cW2 + cb2 ; pos[r] += diff * w
    float v[64];
#pragma unroll
    for (int j = 0; j < 64; j++) v[j] = scb1[j];
#pragma unroll
    for (int k = 0; k < 64; k++) { ROW_FMA(v, m[k], scW1 + k * 64); }
    float w = cb2[0];
#pragma unroll
    for (int j = 0; j < 64; j++) w += silu_f(v[j]) * scW2[j];
    atomicAdd(&posw[(size_t)r * 3 + 0], dx * w);
    atomicAdd(&posw[(size_t)r * 3 + 1], dy * w);
    atomicAdd(&posw[(size_t)r * 3 + 2], dz * w);
  }
}

// ---------------- node MLP: h += silu([h, agg] @ nW1 + nb1) @ nW2 + nb2 ----------------
__global__ __launch_bounds__(256) void node_kernel(
    float* __restrict__ h, const float* __restrict__ agg,
    const float* __restrict__ W1, const float* __restrict__ b1,
    const float* __restrict__ W2, const float* __restrict__ b2, int N)
{
  __shared__ float sW1[128 * 64];
  __shared__ float sW2[64 * 64];
  __shared__ float sb1[64];
  __shared__ float sb2[64];
  for (int i = threadIdx.x; i < 8192; i += 256) sW1[i] = W1[i];
  for (int i = threadIdx.x; i < 4096; i += 256) sW2[i] = W2[i];
  if (threadIdx.x < 64) { sb1[threadIdx.x] = b1[threadIdx.x]; sb2[threadIdx.x] = b2[threadIdx.x]; }
  __syncthreads();
  int n = blockIdx.x * 256 + threadIdx.x;
  if (n >= N) return;
  float u[64];
#pragma unroll
  for (int j = 0; j < 64; j++) u[j] = sb1[j];
  const float4* h4 = (const float4*)(h + (size_t)n * 64);
#pragma unroll
  for (int k4 = 0; k4 < 16; k4++) {
    float4 hv = h4[k4];
    ROW_FMA(u, hv.x, sW1 + (4 * k4 + 0) * 64);
    ROW_FMA(u, hv.y, sW1 + (4 * k4 + 1) * 64);
    ROW_FMA(u, hv.z, sW1 + (4 * k4 + 2) * 64);
    ROW_FMA(u, hv.w, sW1 + (4 * k4 + 3) * 64);
  }
  const float4* a4 = (const float4*)(agg + (size_t)n * 64);
#pragma unroll
  for (int k4 = 0; k4 < 16; k4++) {
    float4 av = a4[k4];
    ROW_FMA(u, av.x, sW1 + (64 + 4 * k4 + 0) * 64);
    ROW_FMA(u, av.y, sW1 + (64 + 4 * k4 + 1) * 64);
    ROW_FMA(u, av.z, sW1 + (64 + 4 * k4 + 2) * 64);
    ROW_FMA(u, av.w, sW1 + (64 + 4 * k4 + 3) * 64);
  }
#pragma unroll
  for (int j = 0; j < 64; j++) u[j] = silu_f(u[j]);
  float o[64];
#pragma unroll
  for (int j = 0; j < 64; j++) o[j] = sb2[j];
#pragma unroll
  for (int k = 0; k < 64; k++) { ROW_FMA(o, u[k], sW2 + k * 64); }
  float4* hw = (float4*)(h + (size_t)n * 64);
#pragma unroll
  for (int j4 = 0; j4 < 16; j4++) {
    float4 hv = h4[j4];
    float4 v;
    v.x = hv.x + o[4 * j4 + 0];
    v.y = hv.y + o[4 * j4 + 1];
    v.z = hv.z + o[4 * j4 + 2];
    v.w = hv.w + o[4 * j4 + 3];
    hw[j4] = v;
  }
}

// ---------------- pooling (mean||max per graph) + classifier ----------------
__device__ __forceinline__ int lbound(const int* __restrict__ a, int n, int v)
{
  int lo = 0, hi = n;
  while (lo < hi) {
    int mid = (lo + hi) >> 1;
    if (a[mid] < v) lo = mid + 1;
    else hi = mid;
  }
  return lo;
}

__global__ __launch_bounds__(256) void pool_cls_kernel(
    const float* __restrict__ h, const int* __restrict__ batch, int N,
    const float* __restrict__ W1, const float* __restrict__ b1,
    const float* __restrict__ W2, const float* __restrict__ b2, float* __restrict__ out)
{
  int g = blockIdx.x;
  int start = lbound(batch, N, g);
  int end = lbound(batch, N, g + 1);
  int j = threadIdx.x & 63;
  int grp = threadIdx.x >> 6;  // 0..3
  float s = 0.f, mx = -INFINITY;
  for (int n = start + grp; n < end; n += 4) {
    float v = h[(size_t)n * 64 + j];
    s += v;
    mx = fmaxf(mx, v);
  }
  __shared__ float ssum[4][64];
  __shared__ float smax[4][64];
  __shared__ float pooled[128];
  __shared__ float su[64];
  ssum[grp][j] = s;
  smax[grp][j] = mx;
  __syncthreads();
  if (grp == 0) {
    float S = ssum[0][j] + ssum[1][j] + ssum[2][j] + ssum[3][j];
    float M = fmaxf(fmaxf(smax[0][j], smax[1][j]), fmaxf(smax[2][j], smax[3][j]));
    float cnt = (float)(end - start);
    pooled[j] = S / fmaxf(cnt, 1.0f);
    pooled[64 + j] = M;
  }
  __syncthreads();
  if (threadIdx.x < 64) {
    float a = b1[j];
#pragma unroll
    for (int k = 0; k < 128; k++) a += pooled[k] * W1[k * 64 + j];
    su[j] = fmaxf(a, 0.f);
  }
  __syncthreads();
  if (threadIdx.x < 2) {
    float a = b2[threadIdx.x];
#pragma unroll
    for (int k = 0; k < 64; k++) a += su[k] * W2[k * 2 + threadIdx.x];
    out[g * 2 + threadIdx.x] = a;
  }
}

extern "C" void kernel_launch(void* const* d_in, const int* in_sizes, int n_in,
                              void* d_out, int out_size, void* d_ws, size_t ws_size,
                              hipStream_t stream)
{
  const float* x = (const float*)d_in[0];
  const float* pos = (const float*)d_in[1];
  const int* ei = (const int*)d_in[2];
  const float* eattr = (const float*)d_in[3];
  const int* batch = (const int*)d_in[4];
  const float* projW = (const float*)d_in[5];
  const float* projb = (const float*)d_in[6];
  const float* msgW1 = (const float*)d_in[7];
  const float* msgb1 = (const float*)d_in[8];
  const float* msgW2 = (const float*)d_in[9];
  const float* msgb2 = (const float*)d_in[10];
  const float* ndW1 = (const float*)d_in[11];
  const float* ndb1 = (const float*)d_in[12];
  const float* ndW2 = (const float*)d_in[13];
  const float* ndb2 = (const float*)d_in[14];
  const float* cdW1 = (const float*)d_in[15];
  const float* cdb1 = (const float*)d_in[16];
  const float* cdW2 = (const float*)d_in[17];
  const float* cdb2 = (const float*)d_in[18];
  const float* clsW1 = (const float*)d_in[19];
  const float* clsb1 = (const float*)d_in[20];
  const float* clsW2 = (const float*)d_in[21];
  const float* clsb2 = (const float*)d_in[22];

  int N = in_sizes[4];
  int E = in_sizes[3] / 3;
  const int* rowp = ei;
  const int* colp = ei + E;

  float* ws = (float*)d_ws;
  size_t nh = (size_t)N * 64;
  float* h = ws;
  float* Pb = h + nh;
  float* Qb = Pb + nh;
  float* agg = Qb + nh;
  float* posA = agg + nh;
  size_t np3 = (((size_t)N * 3) + 63) & ~(size_t)63;
  float* posB = posA + np3;

  int nb_nodes = (N + 255) / 256;
  int nb_edges = (E + 255) / 256;
  int G = out_size / 2;

  proj_kernel<<<nb_nodes, 256, 0, stream>>>(x, projW, projb, h, N);

  const float* pr[4] = {pos, posA, posB, posA};
  float* pw[4] = {posA, posB, posA, nullptr};

  for (int i = 0; i < 4; i++) {
    premul_kernel<<<nb_nodes, 256, 0, stream>>>(h, msgW1 + (size_t)i * 132 * 64, Pb, Qb, N);
    hipMemsetAsync(agg, 0, nh * sizeof(float), stream);
    if (i < 3) {
      hipMemcpyAsync(pw[i], pr[i], (size_t)N * 3 * sizeof(float), hipMemcpyDeviceToDevice, stream);
      edge_kernel<1><<<nb_edges, 256, 0, stream>>>(
          rowp, colp, pr[i], pw[i], eattr, Pb, Qb,
          msgW1 + (size_t)i * 132 * 64 + 128 * 64, msgb1 + i * 64,
          msgW2 + (size_t)i * 4096, msgb2 + i * 64,
          cdW1 + (size_t)i * 4096, cdb1 + i * 64, cdW2 + i * 64, cdb2 + i, agg, E);
    } else {
      edge_kernel<0><<<nb_edges, 256, 0, stream>>>(
          rowp, colp, pr[i], nullptr, eattr, Pb, Qb,
          msgW1 + (size_t)i * 132 * 64 + 128 * 64, msgb1 + i * 64,
          msgW2 + (size_t)i * 4096, msgb2 + i * 64,
          nullptr, nullptr, nullptr, nullptr, agg, E);
    }
    node_kernel<<<nb_nodes, 256, 0, stream>>>(
        h, agg, ndW1 + (size_t)i * 8192, ndb1 + i * 64, ndW2 + (size_t)i * 4096, ndb2 + i * 64, N);
  }

  pool_cls_kernel<<<G, 256, 0, stream>>>(h, batch, N, clsW1, clsb1, clsW2, clsb2, (float*)d_out);
}

// Round 5
// 14191.843 us; speedup vs baseline: 1.0001x; 1.0001x over previous
//
#include <hip/hip_runtime.h>
#include <math.h>

// EGNN forward, fp32. Edge-MLP with P/Q node-side factorization.
// This round: counting-sort edges by row -> CSR; edge kernel writes msg
// coalesced (no atomics); wave-per-node segmented reduction for agg + pos.
// Falls back to the atomic path if ws_size is too small for msg_buf.

__device__ __forceinline__ float silu_f(float x) { return x / (1.0f + __expf(-x)); }

// acc[64] += scal * rowptr[0..63]   (rowptr 16B-aligned, LDS or global)
#define ROW_FMA(acc, scal, rowptr)                                                   \
  {                                                                                  \
    const float4* _w = (const float4*)(rowptr);                                      \
    _Pragma("unroll") for (int _j = 0; _j < 16; _j++)                                \
    {                                                                                \
      float4 _wv = _w[_j];                                                           \
      acc[4 * _j + 0] += (scal) * _wv.x;                                             \
      acc[4 * _j + 1] += (scal) * _wv.y;                                             \
      acc[4 * _j + 2] += (scal) * _wv.z;                                             \
      acc[4 * _j + 3] += (scal) * _wv.w;                                             \
    }                                                                                \
  }

// ---------------- proj: h = x @ proj_W + proj_b ----------------
__global__ __launch_bounds__(256) void proj_kernel(
    const float* __restrict__ x, const float* __restrict__ W, const float* __restrict__ b,
    float* __restrict__ h, int N)
{
  __shared__ float sW[26 * 64];
  __shared__ float sb[64];
  for (int i = threadIdx.x; i < 26 * 64; i += 256) sW[i] = W[i];
  if (threadIdx.x < 64) sb[threadIdx.x] = b[threadIdx.x];
  __syncthreads();
  int n = blockIdx.x * 256 + threadIdx.x;
  if (n >= N) return;
  float acc[64];
#pragma unroll
  for (int j = 0; j < 64; j++) acc[j] = sb[j];
#pragma unroll
  for (int k = 0; k < 26; k++) {
    float xk = x[(size_t)n * 26 + k];
    ROW_FMA(acc, xk, sW + k * 64);
  }
  float4* h4 = (float4*)(h + (size_t)n * 64);
#pragma unroll
  for (int j4 = 0; j4 < 16; j4++) {
    float4 v;
    v.x = acc[4 * j4 + 0]; v.y = acc[4 * j4 + 1]; v.z = acc[4 * j4 + 2]; v.w = acc[4 * j4 + 3];
    h4[j4] = v;
  }
}

// ---------------- premul: P = h @ W1[0:64], Q = h @ W1[64:128] ----------------
__global__ __launch_bounds__(256) void premul_kernel(
    const float* __restrict__ h, const float* __restrict__ W1,
    float* __restrict__ P, float* __restrict__ Q, int N)
{
  __shared__ float sW[128 * 64];
  for (int i = threadIdx.x; i < 128 * 64; i += 256) sW[i] = W1[i];
  __syncthreads();
  int n = blockIdx.x * 256 + threadIdx.x;
  if (n >= N) return;
  float hr[64];
  const float4* h4 = (const float4*)(h + (size_t)n * 64);
#pragma unroll
  for (int i = 0; i < 16; i++) {
    float4 v = h4[i];
    hr[4 * i] = v.x; hr[4 * i + 1] = v.y; hr[4 * i + 2] = v.z; hr[4 * i + 3] = v.w;
  }
  float acc[64];
#pragma unroll
  for (int j = 0; j < 64; j++) acc[j] = 0.f;
#pragma unroll
  for (int k = 0; k < 64; k++) { ROW_FMA(acc, hr[k], sW + k * 64); }
  float4* P4 = (float4*)(P + (size_t)n * 64);
#pragma unroll
  for (int j4 = 0; j4 < 16; j4++) {
    float4 v;
    v.x = acc[4 * j4 + 0]; v.y = acc[4 * j4 + 1]; v.z = acc[4 * j4 + 2]; v.w = acc[4 * j4 + 3];
    P4[j4] = v;
  }
#pragma unroll
  for (int j = 0; j < 64; j++) acc[j] = 0.f;
#pragma unroll
  for (int k = 0; k < 64; k++) { ROW_FMA(acc, hr[k], sW + (64 + k) * 64); }
  float4* Q4 = (float4*)(Q + (size_t)n * 64);
#pragma unroll
  for (int j4 = 0; j4 < 16; j4++) {
    float4 v;
    v.x = acc[4 * j4 + 0]; v.y = acc[4 * j4 + 1]; v.z = acc[4 * j4 + 2]; v.w = acc[4 * j4 + 3];
    Q4[j4] = v;
  }
}

// ---------------- CSR build ----------------
__global__ __launch_bounds__(256) void hist_kernel(
    const int* __restrict__ row, int* __restrict__ cnt, int E)
{
  int e = blockIdx.x * 256 + threadIdx.x;
  if (e < E) atomicAdd(&cnt[row[e]], 1);
}

__global__ __launch_bounds__(1024) void scan_kernel(
    const int* __restrict__ cnt, int* __restrict__ rowptr, int* __restrict__ cursor, int N, int E)
{
  __shared__ int part[1024];
  int t = threadIdx.x;
  int chunk = (N + 1023) >> 10;
  int lo = t * chunk;
  int hi = lo + chunk;
  if (lo > N) lo = N;
  if (hi > N) hi = N;
  int s = 0;
  for (int i = lo; i < hi; i++) s += cnt[i];
  part[t] = s;
  __syncthreads();
  for (int off = 1; off < 1024; off <<= 1) {
    int v = 0;
    if (t >= off) v = part[t - off];
    __syncthreads();
    if (t >= off) part[t] += v;
    __syncthreads();
  }
  int run = part[t] - s;  // exclusive base for this chunk
  for (int i = lo; i < hi; i++) {
    rowptr[i] = run;
    cursor[i] = run;
    run += cnt[i];
  }
  if (t == 0) rowptr[N] = E;
}

__global__ __launch_bounds__(256) void scatter_kernel(
    const int* __restrict__ row, const int* __restrict__ col, const float* __restrict__ eattr,
    int* __restrict__ cursor, int* __restrict__ srow, int* __restrict__ scol,
    float* __restrict__ sea, int E)
{
  int e = blockIdx.x * 256 + threadIdx.x;
  if (e >= E) return;
  int r = row[e];
  int p = atomicAdd(&cursor[r], 1);
  srow[p] = r;
  scol[p] = col[e];
  sea[(size_t)p * 3 + 0] = eattr[(size_t)e * 3 + 0];
  sea[(size_t)p * 3 + 1] = eattr[(size_t)e * 3 + 1];
  sea[(size_t)p * 3 + 2] = eattr[(size_t)e * 3 + 2];
}

// ---------------- sorted edge kernel: msg MLP -> coalesced stores ----------------
template <int COORD>
__global__ __launch_bounds__(256) void edge_sorted_kernel(
    const int* __restrict__ srow, const int* __restrict__ scol,
    const float* __restrict__ posr, const float* __restrict__ sea,
    const float* __restrict__ P, const float* __restrict__ Q,
    const float* __restrict__ W1t,  // rows 128..131 of msg_W1 (dist, ea0..2): [4][64]
    const float* __restrict__ b1, const float* __restrict__ W2, const float* __restrict__ b2,
    const float* __restrict__ cW1, const float* __restrict__ cb1,
    const float* __restrict__ cW2, const float* __restrict__ cb2,
    float* __restrict__ msg, float* __restrict__ cw4, int E)
{
  __shared__ float sW1t[4 * 64];
  __shared__ float sb1[64];
  __shared__ float sW2[64 * 64];
  __shared__ float sb2[64];
  __shared__ float scW1[COORD ? 64 * 64 : 1];
  __shared__ float scb1[COORD ? 64 : 1];
  __shared__ float scW2[COORD ? 64 : 1];

  int tid = threadIdx.x;
  for (int i = tid; i < 4 * 64; i += 256) sW1t[i] = W1t[i];
  for (int i = tid; i < 4096; i += 256) sW2[i] = W2[i];
  if (tid < 64) { sb1[tid] = b1[tid]; sb2[tid] = b2[tid]; }
  if (COORD) {
    for (int i = tid; i < 4096; i += 256) scW1[i] = cW1[i];
    if (tid < 64) { scb1[tid] = cb1[tid]; scW2[tid] = cW2[tid]; }
  }
  __syncthreads();

  int e = blockIdx.x * 256 + tid;
  if (e >= E) return;
  int r = srow[e];
  int c = scol[e];
  float dx = posr[(size_t)r * 3 + 0] - posr[(size_t)c * 3 + 0];
  float dy = posr[(size_t)r * 3 + 1] - posr[(size_t)c * 3 + 1];
  float dz = posr[(size_t)r * 3 + 2] - posr[(size_t)c * 3 + 2];
  float dist = sqrtf(dx * dx + dy * dy + dz * dz);
  float ea0 = sea[(size_t)e * 3 + 0];
  float ea1 = sea[(size_t)e * 3 + 1];
  float ea2 = sea[(size_t)e * 3 + 2];

  // u = silu(P[r] + Q[c] + dist*W1t[0] + ea*W1t[1..3] + b1)
  float u[64];
  const float4* P4 = (const float4*)(P + (size_t)r * 64);
  const float4* Q4 = (const float4*)(Q + (size_t)c * 64);
#pragma unroll
  for (int j4 = 0; j4 < 16; j4++) {
    float4 p = P4[j4];
    float4 q = Q4[j4];
#pragma unroll
    for (int t = 0; t < 4; t++) {
      int j = 4 * j4 + t;
      float pv = (t == 0) ? p.x : (t == 1) ? p.y : (t == 2) ? p.z : p.w;
      float qv = (t == 0) ? q.x : (t == 1) ? q.y : (t == 2) ? q.z : q.w;
      float v = pv + qv + sb1[j] + dist * sW1t[j] + ea0 * sW1t[64 + j] + ea1 * sW1t[128 + j] +
                ea2 * sW1t[192 + j];
      u[j] = silu_f(v);
    }
  }

  // m = silu(u @ W2 + b2)
  float m[64];
#pragma unroll
  for (int j = 0; j < 64; j++) m[j] = sb2[j];
#pragma unroll
  for (int k = 0; k < 64; k++) { ROW_FMA(m, u[k], sW2 + k * 64); }
#pragma unroll
  for (int j = 0; j < 64; j++) m[j] = silu_f(m[j]);

  // coalesced msg store
  float4* mb = (float4*)(msg + (size_t)e * 64);
#pragma unroll
  for (int j4 = 0; j4 < 16; j4++) {
    float4 v;
    v.x = m[4 * j4 + 0]; v.y = m[4 * j4 + 1]; v.z = m[4 * j4 + 2]; v.w = m[4 * j4 + 3];
    mb[j4] = v;
  }

  if (COORD) {
    // w = silu(m @ cW1 + cb1) . cW2 + cb2 ; store diff*w
    float v[64];
#pragma unroll
    for (int j = 0; j < 64; j++) v[j] = scb1[j];
#pragma unroll
    for (int k = 0; k < 64; k++) { ROW_FMA(v, m[k], scW1 + k * 64); }
    float w = cb2[0];
#pragma unroll
    for (int j = 0; j < 64; j++) w += silu_f(v[j]) * scW2[j];
    float4 cv;
    cv.x = dx * w; cv.y = dy * w; cv.z = dz * w; cv.w = 0.f;
    ((float4*)cw4)[e] = cv;
  }
}

// ---------------- wave-per-node segmented reduction: agg + pos ----------------
template <int COORD>
__global__ __launch_bounds__(256) void agg_pos_kernel(
    const float* __restrict__ msg, const float* __restrict__ cw4,
    const int* __restrict__ rowptr, const float* __restrict__ posr, float* __restrict__ posw,
    float* __restrict__ agg, int N)
{
  int w = (blockIdx.x * 256 + threadIdx.x) >> 6;  // one wave per node
  if (w >= N) return;
  int lane = threadIdx.x & 63;
  int s = rowptr[w];
  int t = rowptr[w + 1];
  float acc = 0.f;
  for (int e = s; e < t; e++) acc += msg[(size_t)e * 64 + lane];
  agg[(size_t)w * 64 + lane] = acc;
  if (COORD) {
    if (lane < 3) {
      float p = 0.f;
      for (int e = s; e < t; e++) p += cw4[(size_t)e * 4 + lane];
      posw[(size_t)w * 3 + lane] = posr[(size_t)w * 3 + lane] + p;
    }
  }
}

// ---------------- atomic-path edge kernel (fallback if ws too small) ----------------
template <int COORD>
__global__ __launch_bounds__(256) void edge_kernel(
    const int* __restrict__ row, const int* __restrict__ col,
    const float* __restrict__ posr, float* __restrict__ posw,
    const float* __restrict__ eattr,
    const float* __restrict__ P, const float* __restrict__ Q,
    const float* __restrict__ W1t,
    const float* __restrict__ b1, const float* __restrict__ W2, const float* __restrict__ b2,
    const float* __restrict__ cW1, const float* __restrict__ cb1,
    const float* __restrict__ cW2, const float* __restrict__ cb2,
    float* __restrict__ agg, int E)
{
  __shared__ float sW1t[4 * 64];
  __shared__ float sb1[64];
  __shared__ float sW2[64 * 64];
  __shared__ float sb2[64];
  __shared__ float scW1[COORD ? 64 * 64 : 1];
  __shared__ float scb1[COORD ? 64 : 1];
  __shared__ float scW2[COORD ? 64 : 1];

  int tid = threadIdx.x;
  for (int i = tid; i < 4 * 64; i += 256) sW1t[i] = W1t[i];
  for (int i = tid; i < 4096; i += 256) sW2[i] = W2[i];
  if (tid < 64) { sb1[tid] = b1[tid]; sb2[tid] = b2[tid]; }
  if (COORD) {
    for (int i = tid; i < 4096; i += 256) scW1[i] = cW1[i];
    if (tid < 64) { scb1[tid] = cb1[tid]; scW2[tid] = cW2[tid]; }
  }
  __syncthreads();

  int e = blockIdx.x * 256 + tid;
  if (e >= E) return;
  int r = row[e];
  int c = col[e];
  float dx = posr[(size_t)r * 3 + 0] - posr[(size_t)c * 3 + 0];
  float dy = posr[(size_t)r * 3 + 1] - posr[(size_t)c * 3 + 1];
  float dz = posr[(size_t)r * 3 + 2] - posr[(size_t)c * 3 + 2];
  float dist = sqrtf(dx * dx + dy * dy + dz * dz);
  float ea0 = eattr[(size_t)e * 3 + 0];
  float ea1 = eattr[(size_t)e * 3 + 1];
  float ea2 = eattr[(size_t)e * 3 + 2];

  float u[64];
  const float4* P4 = (const float4*)(P + (size_t)r * 64);
  const float4* Q4 = (const float4*)(Q + (size_t)c * 64);
#pragma unroll
  for (int j4 = 0; j4 < 16; j4++) {
    float4 p = P4[j4];
    float4 q = Q4[j4];
#pragma unroll
    for (int t = 0; t < 4; t++) {
      int j = 4 * j4 + t;
      float pv = (t == 0) ? p.x : (t == 1) ? p.y : (t == 2) ? p.z : p.w;
      float qv = (t == 0) ? q.x : (t == 1) ? q.y : (t == 2) ? q.z : q.w;
      float v = pv + qv + sb1[j] + dist * sW1t[j] + ea0 * sW1t[64 + j] + ea1 * sW1t[128 + j] +
                ea2 * sW1t[192 + j];
      u[j] = silu_f(v);
    }
  }
  float m[64];
#pragma unroll
  for (int j = 0; j < 64; j++) m[j] = sb2[j];
#pragma unroll
  for (int k = 0; k < 64; k++) { ROW_FMA(m, u[k], sW2 + k * 64); }
#pragma unroll
  for (int j = 0; j < 64; j++) m[j] = silu_f(m[j]);
  float* ar = agg + (size_t)r * 64;
#pragma unroll
  for (int j = 0; j < 64; j++) atomicAdd(ar + j, m[j]);
  if (COORD) {
    float v[64];
#pragma unroll
    for (int j = 0; j < 64; j++) v[j] = scb1[j];
#pragma unroll
    for (int k = 0; k < 64; k++) { ROW_FMA(v, m[k], scW1 + k * 64); }
    float w = cb2[0];
#pragma unroll
    for (int j = 0; j < 64; j++) w += silu_f(v[j]) * scW2[j];
    atomicAdd(&posw[(size_t)r * 3 + 0], dx * w);
    atomicAdd(&posw[(size_t)r * 3 + 1], dy * w);
    atomicAdd(&posw[(size_t)r * 3 + 2], dz * w);
  }
}

// ---------------- node MLP: h += silu([h, agg] @ nW1 + nb1) @ nW2 + nb2 ----------------
__global__ __launch_bounds__(256) void node_kernel(
    float* __restrict__ h, const float* __restrict__ agg,
    const float* __restrict__ W1, const float* __restrict__ b1,
    const float* __restrict__ W2, const float* __restrict__ b2, int N)
{
  __shared__ float sW1[128 * 64];
  __shared__ float sW2[64 * 64];
  __shared__ float sb1[64];
  __shared__ float sb2[64];
  for (int i = threadIdx.x; i < 8192; i += 256) sW1[i] = W1[i];
  for (int i = threadIdx.x; i < 4096; i += 256) sW2[i] = W2[i];
  if (threadIdx.x < 64) { sb1[threadIdx.x] = b1[threadIdx.x]; sb2[threadIdx.x] = b2[threadIdx.x]; }
  __syncthreads();
  int n = blockIdx.x * 256 + threadIdx.x;
  if (n >= N) return;
  float u[64];
#pragma unroll
  for (int j = 0; j < 64; j++) u[j] = sb1[j];
  const float4* h4 = (const float4*)(h + (size_t)n * 64);
#pragma unroll
  for (int k4 = 0; k4 < 16; k4++) {
    float4 hv = h4[k4];
    ROW_FMA(u, hv.x, sW1 + (4 * k4 + 0) * 64);
    ROW_FMA(u, hv.y, sW1 + (4 * k4 + 1) * 64);
    ROW_FMA(u, hv.z, sW1 + (4 * k4 + 2) * 64);
    ROW_FMA(u, hv.w, sW1 + (4 * k4 + 3) * 64);
  }
  const float4* a4 = (const float4*)(agg + (size_t)n * 64);
#pragma unroll
  for (int k4 = 0; k4 < 16; k4++) {
    float4 av = a4[k4];
    ROW_FMA(u, av.x, sW1 + (64 + 4 * k4 + 0) * 64);
    ROW_FMA(u, av.y, sW1 + (64 + 4 * k4 + 1) * 64);
    ROW_FMA(u, av.z, sW1 + (64 + 4 * k4 + 2) * 64);
    ROW_FMA(u, av.w, sW1 + (64 + 4 * k4 + 3) * 64);
  }
#pragma unroll
  for (int j = 0; j < 64; j++) u[j] = silu_f(u[j]);
  float o[64];
#pragma unroll
  for (int j = 0; j < 64; j++) o[j] = sb2[j];
#pragma unroll
  for (int k = 0; k < 64; k++) { ROW_FMA(o, u[k], sW2 + k * 64); }
  float4* hw = (float4*)(h + (size_t)n * 64);
#pragma unroll
  for (int j4 = 0; j4 < 16; j4++) {
    float4 hv = h4[j4];
    float4 v;
    v.x = hv.x + o[4 * j4 + 0];
    v.y = hv.y + o[4 * j4 + 1];
    v.z = hv.z + o[4 * j4 + 2];
    v.w = hv.w + o[4 * j4 + 3];
    hw[j4] = v;
  }
}

// ---------------- pooling (mean||max per graph) + classifier ----------------
__device__ __forceinline__ int lbound(const int* __restrict__ a, int n, int v)
{
  int lo = 0, hi = n;
  while (lo < hi) {
    int mid = (lo + hi) >> 1;
    if (a[mid] < v) lo = mid + 1;
    else hi = mid;
  }
  return lo;
}

__global__ __launch_bounds__(256) void pool_cls_kernel(
    const float* __restrict__ h, const int* __restrict__ batch, int N,
    const float* __restrict__ W1, const float* __restrict__ b1,
    const float* __restrict__ W2, const float* __restrict__ b2, float* __restrict__ out)
{
  int g = blockIdx.x;
  int start = lbound(batch, N, g);
  int end = lbound(batch, N, g + 1);
  int j = threadIdx.x & 63;
  int grp = threadIdx.x >> 6;  // 0..3
  float s = 0.f, mx = -INFINITY;
  for (int n = start + grp; n < end; n += 4) {
    float v = h[(size_t)n * 64 + j];
    s += v;
    mx = fmaxf(mx, v);
  }
  __shared__ float ssum[4][64];
  __shared__ float smax[4][64];
  __shared__ float pooled[128];
  __shared__ float su[64];
  ssum[grp][j] = s;
  smax[grp][j] = mx;
  __syncthreads();
  if (grp == 0) {
    float S = ssum[0][j] + ssum[1][j] + ssum[2][j] + ssum[3][j];
    float M = fmaxf(fmaxf(smax[0][j], smax[1][j]), fmaxf(smax[2][j], smax[3][j]));
    float cnt = (float)(end - start);
    pooled[j] = S / fmaxf(cnt, 1.0f);
    pooled[64 + j] = M;
  }
  __syncthreads();
  if (threadIdx.x < 64) {
    float a = b1[j];
#pragma unroll
    for (int k = 0; k < 128; k++) a += pooled[k] * W1[k * 64 + j];
    su[j] = fmaxf(a, 0.f);
  }
  __syncthreads();
  if (threadIdx.x < 2) {
    float a = b2[threadIdx.x];
#pragma unroll
    for (int k = 0; k < 64; k++) a += su[k] * W2[k * 2 + threadIdx.x];
    out[g * 2 + threadIdx.x] = a;
  }
}

extern "C" void kernel_launch(void* const* d_in, const int* in_sizes, int n_in,
                              void* d_out, int out_size, void* d_ws, size_t ws_size,
                              hipStream_t stream)
{
  const float* x = (const float*)d_in[0];
  const float* pos = (const float*)d_in[1];
  const int* ei = (const int*)d_in[2];
  const float* eattr = (const float*)d_in[3];
  const int* batch = (const int*)d_in[4];
  const float* projW = (const float*)d_in[5];
  const float* projb = (const float*)d_in[6];
  const float* msgW1 = (const float*)d_in[7];
  const float* msgb1 = (const float*)d_in[8];
  const float* msgW2 = (const float*)d_in[9];
  const float* msgb2 = (const float*)d_in[10];
  const float* ndW1 = (const float*)d_in[11];
  const float* ndb1 = (const float*)d_in[12];
  const float* ndW2 = (const float*)d_in[13];
  const float* ndb2 = (const float*)d_in[14];
  const float* cdW1 = (const float*)d_in[15];
  const float* cdb1 = (const float*)d_in[16];
  const float* cdW2 = (const float*)d_in[17];
  const float* cdb2 = (const float*)d_in[18];
  const float* clsW1 = (const float*)d_in[19];
  const float* clsb1 = (const float*)d_in[20];
  const float* clsW2 = (const float*)d_in[21];
  const float* clsb2 = (const float*)d_in[22];

  int N = in_sizes[4];
  int E = in_sizes[3] / 3;
  const int* rowp = ei;
  const int* colp = ei + E;

  // ---- workspace bump allocator (256B aligned) ----
  char* wsb = (char*)d_ws;
  size_t off = 0;
  auto alloc = [&](size_t bytes) {
    size_t o = off;
    off = (off + bytes + 255) & ~(size_t)255;
    return o;
  };
  size_t nh = (size_t)N * 64 * sizeof(float);
  size_t o_h = alloc(nh);
  size_t o_P = alloc(nh);
  size_t o_Q = alloc(nh);
  size_t o_agg = alloc(nh);
  size_t o_posA = alloc((size_t)N * 3 * sizeof(float));
  size_t o_posB = alloc((size_t)N * 3 * sizeof(float));
  size_t base_needed_end = off;
  size_t o_cnt = alloc((size_t)N * sizeof(int));
  size_t o_rowptr = alloc(((size_t)N + 1) * sizeof(int));
  size_t o_cursor = alloc((size_t)N * sizeof(int));
  size_t o_srow = alloc((size_t)E * sizeof(int));
  size_t o_scol = alloc((size_t)E * sizeof(int));
  size_t o_sea = alloc((size_t)E * 3 * sizeof(float));
  size_t o_cw4 = alloc((size_t)E * 4 * sizeof(float));
  size_t o_msg = alloc((size_t)E * 64 * sizeof(float));
  size_t sorted_needed = off;

  float* h = (float*)(wsb + o_h);
  float* Pb = (float*)(wsb + o_P);
  float* Qb = (float*)(wsb + o_Q);
  float* agg = (float*)(wsb + o_agg);
  float* posA = (float*)(wsb + o_posA);
  float* posB = (float*)(wsb + o_posB);

  int nb_nodes = (N + 255) / 256;
  int nb_edges = (E + 255) / 256;
  int G = out_size / 2;

  proj_kernel<<<nb_nodes, 256, 0, stream>>>(x, projW, projb, h, N);

  const float* pr[4] = {pos, posA, posB, posA};
  float* pw[4] = {posA, posB, posA, nullptr};

  bool use_sorted = (sorted_needed <= ws_size);
  (void)base_needed_end;

  if (use_sorted) {
    int* cnt = (int*)(wsb + o_cnt);
    int* rowptr = (int*)(wsb + o_rowptr);
    int* cursor = (int*)(wsb + o_cursor);
    int* srow = (int*)(wsb + o_srow);
    int* scol = (int*)(wsb + o_scol);
    float* sea = (float*)(wsb + o_sea);
    float* cw4 = (float*)(wsb + o_cw4);
    float* msg = (float*)(wsb + o_msg);

    hipMemsetAsync(cnt, 0, (size_t)N * sizeof(int), stream);
    hist_kernel<<<nb_edges, 256, 0, stream>>>(rowp, cnt, E);
    scan_kernel<<<1, 1024, 0, stream>>>(cnt, rowptr, cursor, N, E);
    scatter_kernel<<<nb_edges, 256, 0, stream>>>(rowp, colp, eattr, cursor, srow, scol, sea, E);

    int nb_agg = (N * 64 + 255) / 256;  // one wave per node
    for (int i = 0; i < 4; i++) {
      premul_kernel<<<nb_nodes, 256, 0, stream>>>(h, msgW1 + (size_t)i * 132 * 64, Pb, Qb, N);
      if (i < 3) {
        edge_sorted_kernel<1><<<nb_edges, 256, 0, stream>>>(
            srow, scol, pr[i], sea, Pb, Qb,
            msgW1 + (size_t)i * 132 * 64 + 128 * 64, msgb1 + i * 64,
            msgW2 + (size_t)i * 4096, msgb2 + i * 64,
            cdW1 + (size_t)i * 4096, cdb1 + i * 64, cdW2 + i * 64, cdb2 + i, msg, cw4, E);
        agg_pos_kernel<1><<<nb_agg, 256, 0, stream>>>(msg, cw4, rowptr, pr[i], pw[i], agg, N);
      } else {
        edge_sorted_kernel<0><<<nb_edges, 256, 0, stream>>>(
            srow, scol, pr[i], sea, Pb, Qb,
            msgW1 + (size_t)i * 132 * 64 + 128 * 64, msgb1 + i * 64,
            msgW2 + (size_t)i * 4096, msgb2 + i * 64,
            nullptr, nullptr, nullptr, nullptr, msg, cw4, E);
        agg_pos_kernel<0><<<nb_agg, 256, 0, stream>>>(msg, cw4, rowptr, pr[i], nullptr, agg, N);
      }
      node_kernel<<<nb_nodes, 256, 0, stream>>>(
          h, agg, ndW1 + (size_t)i * 8192, ndb1 + i * 64, ndW2 + (size_t)i * 4096, ndb2 + i * 64,
          N);
    }
  } else {
    // fallback: atomic aggregation path
    for (int i = 0; i < 4; i++) {
      premul_kernel<<<nb_nodes, 256, 0, stream>>>(h, msgW1 + (size_t)i * 132 * 64, Pb, Qb, N);
      hipMemsetAsync(agg, 0, nh, stream);
      if (i < 3) {
        hipMemcpyAsync(pw[i], pr[i], (size_t)N * 3 * sizeof(float), hipMemcpyDeviceToDevice,
                       stream);
        edge_kernel<1><<<nb_edges, 256, 0, stream>>>(
            rowp, colp, pr[i], pw[i], eattr, Pb, Qb,
            msgW1 + (size_t)i * 132 * 64 + 128 * 64, msgb1 + i * 64,
            msgW2 + (size_t)i * 4096, msgb2 + i * 64,
            cdW1 + (size_t)i * 4096, cdb1 + i * 64, cdW2 + i * 64, cdb2 + i, agg, E);
      } else {
        edge_kernel<0><<<nb_edges, 256, 0, stream>>>(
            rowp, colp, pr[i], nullptr, eattr, Pb, Qb,
            msgW1 + (size_t)i * 132 * 64 + 128 * 64, msgb1 + i * 64,
            msgW2 + (size_t)i * 4096, msgb2 + i * 64,
            nullptr, nullptr, nullptr, nullptr, agg, E);
      }
      node_kernel<<<nb_nodes, 256, 0, stream>>>(
          h, agg, ndW1 + (size_t)i * 8192, ndb1 + i * 64, ndW2 + (size_t)i * 4096, ndb2 + i * 64,
          N);
    }
  }

  pool_cls_kernel<<<G, 256, 0, stream>>>(h, batch, N, clsW1, clsb1, clsW2, clsb2, (float*)d_out);
}

// Round 6
// 7444.088 us; speedup vs baseline: 1.9067x; 1.9065x over previous
//
#include <hip/hip_runtime.h>
#include <math.h>

// EGNN forward, fp32. P/Q factorization + CSR edge sort.
// Round 6: chunk the msg buffer to fit ws_size (round 5 showed ws < 287MB ->
// sorted path silently fell back to atomics). Chunked two-phase per layer:
//   edge_sorted_chunk: msg MLP -> coalesced stores (no atomics)
//   agg_chunk: wave-per-node segmented reduction, accumulating across chunks.
// Atomic fallback only if ws < ~74MB.

__device__ __forceinline__ float silu_f(float x) { return x / (1.0f + __expf(-x)); }

#define ROW_FMA(acc, scal, rowptr)                                                   \
  {                                                                                  \
    const float4* _w = (const float4*)(rowptr);                                      \
    _Pragma("unroll") for (int _j = 0; _j < 16; _j++)                                \
    {                                                                                \
      float4 _wv = _w[_j];                                                           \
      acc[4 * _j + 0] += (scal) * _wv.x;                                             \
      acc[4 * _j + 1] += (scal) * _wv.y;                                             \
      acc[4 * _j + 2] += (scal) * _wv.z;                                             \
      acc[4 * _j + 3] += (scal) * _wv.w;                                             \
    }                                                                                \
  }

// ---------------- proj ----------------
__global__ __launch_bounds__(256) void proj_kernel(
    const float* __restrict__ x, const float* __restrict__ W, const float* __restrict__ b,
    float* __restrict__ h, int N)
{
  __shared__ float sW[26 * 64];
  __shared__ float sb[64];
  for (int i = threadIdx.x; i < 26 * 64; i += 256) sW[i] = W[i];
  if (threadIdx.x < 64) sb[threadIdx.x] = b[threadIdx.x];
  __syncthreads();
  int n = blockIdx.x * 256 + threadIdx.x;
  if (n >= N) return;
  float acc[64];
#pragma unroll
  for (int j = 0; j < 64; j++) acc[j] = sb[j];
#pragma unroll
  for (int k = 0; k < 26; k++) {
    float xk = x[(size_t)n * 26 + k];
    ROW_FMA(acc, xk, sW + k * 64);
  }
  float4* h4 = (float4*)(h + (size_t)n * 64);
#pragma unroll
  for (int j4 = 0; j4 < 16; j4++) {
    float4 v;
    v.x = acc[4 * j4 + 0]; v.y = acc[4 * j4 + 1]; v.z = acc[4 * j4 + 2]; v.w = acc[4 * j4 + 3];
    h4[j4] = v;
  }
}

// ---------------- premul: P = h @ W1[0:64], Q = h @ W1[64:128] ----------------
__global__ __launch_bounds__(256) void premul_kernel(
    const float* __restrict__ h, const float* __restrict__ W1,
    float* __restrict__ P, float* __restrict__ Q, int N)
{
  __shared__ float sW[128 * 64];
  for (int i = threadIdx.x; i < 128 * 64; i += 256) sW[i] = W1[i];
  __syncthreads();
  int n = blockIdx.x * 256 + threadIdx.x;
  if (n >= N) return;
  float hr[64];
  const float4* h4 = (const float4*)(h + (size_t)n * 64);
#pragma unroll
  for (int i = 0; i < 16; i++) {
    float4 v = h4[i];
    hr[4 * i] = v.x; hr[4 * i + 1] = v.y; hr[4 * i + 2] = v.z; hr[4 * i + 3] = v.w;
  }
  float acc[64];
#pragma unroll
  for (int j = 0; j < 64; j++) acc[j] = 0.f;
#pragma unroll
  for (int k = 0; k < 64; k++) { ROW_FMA(acc, hr[k], sW + k * 64); }
  float4* P4 = (float4*)(P + (size_t)n * 64);
#pragma unroll
  for (int j4 = 0; j4 < 16; j4++) {
    float4 v;
    v.x = acc[4 * j4 + 0]; v.y = acc[4 * j4 + 1]; v.z = acc[4 * j4 + 2]; v.w = acc[4 * j4 + 3];
    P4[j4] = v;
  }
#pragma unroll
  for (int j = 0; j < 64; j++) acc[j] = 0.f;
#pragma unroll
  for (int k = 0; k < 64; k++) { ROW_FMA(acc, hr[k], sW + (64 + k) * 64); }
  float4* Q4 = (float4*)(Q + (size_t)n * 64);
#pragma unroll
  for (int j4 = 0; j4 < 16; j4++) {
    float4 v;
    v.x = acc[4 * j4 + 0]; v.y = acc[4 * j4 + 1]; v.z = acc[4 * j4 + 2]; v.w = acc[4 * j4 + 3];
    Q4[j4] = v;
  }
}

// ---------------- CSR build ----------------
__global__ __launch_bounds__(256) void hist_kernel(
    const int* __restrict__ row, int* __restrict__ cnt, int E)
{
  int e = blockIdx.x * 256 + threadIdx.x;
  if (e < E) atomicAdd(&cnt[row[e]], 1);
}

__global__ __launch_bounds__(1024) void scan_kernel(
    const int* __restrict__ cnt, int* __restrict__ rowptr, int* __restrict__ cursor, int N, int E)
{
  __shared__ int part[1024];
  int t = threadIdx.x;
  int chunk = (N + 1023) >> 10;
  int lo = t * chunk;
  int hi = lo + chunk;
  if (lo > N) lo = N;
  if (hi > N) hi = N;
  int s = 0;
  for (int i = lo; i < hi; i++) s += cnt[i];
  part[t] = s;
  __syncthreads();
  for (int off = 1; off < 1024; off <<= 1) {
    int v = 0;
    if (t >= off) v = part[t - off];
    __syncthreads();
    if (t >= off) part[t] += v;
    __syncthreads();
  }
  int run = part[t] - s;  // exclusive base for this chunk
  for (int i = lo; i < hi; i++) {
    rowptr[i] = run;
    cursor[i] = run;
    run += cnt[i];
  }
  if (t == 0) rowptr[N] = E;
}

__global__ __launch_bounds__(256) void scatter_kernel(
    const int* __restrict__ row, const int* __restrict__ col, const float* __restrict__ eattr,
    int* __restrict__ cursor, int* __restrict__ srow, int* __restrict__ scol,
    float* __restrict__ sea, int E)
{
  int e = blockIdx.x * 256 + threadIdx.x;
  if (e >= E) return;
  int r = row[e];
  int p = atomicAdd(&cursor[r], 1);
  srow[p] = r;
  scol[p] = col[e];
  sea[(size_t)p * 3 + 0] = eattr[(size_t)e * 3 + 0];
  sea[(size_t)p * 3 + 1] = eattr[(size_t)e * 3 + 1];
  sea[(size_t)p * 3 + 2] = eattr[(size_t)e * 3 + 2];
}

// ---------------- chunked sorted edge kernel: msg MLP -> coalesced stores ----------------
template <int COORD>
__global__ __launch_bounds__(256) void edge_sorted_kernel(
    const int* __restrict__ srow, const int* __restrict__ scol,
    const float* __restrict__ posr, const float* __restrict__ sea,
    const float* __restrict__ P, const float* __restrict__ Q,
    const float* __restrict__ W1t,  // rows 128..131 of msg_W1 (dist, ea0..2): [4][64]
    const float* __restrict__ b1, const float* __restrict__ W2, const float* __restrict__ b2,
    const float* __restrict__ cW1, const float* __restrict__ cb1,
    const float* __restrict__ cW2, const float* __restrict__ cb2,
    float* __restrict__ msg, float* __restrict__ cw4, int ce0, int ce1)
{
  __shared__ float sW1t[4 * 64];
  __shared__ float sb1[64];
  __shared__ float sW2[64 * 64];
  __shared__ float sb2[64];
  __shared__ float scW1[COORD ? 64 * 64 : 1];
  __shared__ float scb1[COORD ? 64 : 1];
  __shared__ float scW2[COORD ? 64 : 1];

  int tid = threadIdx.x;
  for (int i = tid; i < 4 * 64; i += 256) sW1t[i] = W1t[i];
  for (int i = tid; i < 4096; i += 256) sW2[i] = W2[i];
  if (tid < 64) { sb1[tid] = b1[tid]; sb2[tid] = b2[tid]; }
  if (COORD) {
    for (int i = tid; i < 4096; i += 256) scW1[i] = cW1[i];
    if (tid < 64) { scb1[tid] = cb1[tid]; scW2[tid] = cW2[tid]; }
  }
  __syncthreads();

  int e = ce0 + blockIdx.x * 256 + tid;
  if (e >= ce1) return;
  int le = e - ce0;  // chunk-local index
  int r = srow[e];
  int c = scol[e];
  float dx = posr[(size_t)r * 3 + 0] - posr[(size_t)c * 3 + 0];
  float dy = posr[(size_t)r * 3 + 1] - posr[(size_t)c * 3 + 1];
  float dz = posr[(size_t)r * 3 + 2] - posr[(size_t)c * 3 + 2];
  float dist = sqrtf(dx * dx + dy * dy + dz * dz);
  float ea0 = sea[(size_t)e * 3 + 0];
  float ea1 = sea[(size_t)e * 3 + 1];
  float ea2 = sea[(size_t)e * 3 + 2];

  // u = silu(P[r] + Q[c] + dist*W1t[0] + ea*W1t[1..3] + b1)
  float u[64];
  const float4* P4 = (const float4*)(P + (size_t)r * 64);
  const float4* Q4 = (const float4*)(Q + (size_t)c * 64);
#pragma unroll
  for (int j4 = 0; j4 < 16; j4++) {
    float4 p = P4[j4];
    float4 q = Q4[j4];
#pragma unroll
    for (int t = 0; t < 4; t++) {
      int j = 4 * j4 + t;
      float pv = (t == 0) ? p.x : (t == 1) ? p.y : (t == 2) ? p.z : p.w;
      float qv = (t == 0) ? q.x : (t == 1) ? q.y : (t == 2) ? q.z : q.w;
      float v = pv + qv + sb1[j] + dist * sW1t[j] + ea0 * sW1t[64 + j] + ea1 * sW1t[128 + j] +
                ea2 * sW1t[192 + j];
      u[j] = silu_f(v);
    }
  }

  // m = silu(u @ W2 + b2)
  float m[64];
#pragma unroll
  for (int j = 0; j < 64; j++) m[j] = sb2[j];
#pragma unroll
  for (int k = 0; k < 64; k++) { ROW_FMA(m, u[k], sW2 + k * 64); }
#pragma unroll
  for (int j = 0; j < 64; j++) m[j] = silu_f(m[j]);

  // coalesced msg store (chunk-local)
  float4* mb = (float4*)(msg + (size_t)le * 64);
#pragma unroll
  for (int j4 = 0; j4 < 16; j4++) {
    float4 v;
    v.x = m[4 * j4 + 0]; v.y = m[4 * j4 + 1]; v.z = m[4 * j4 + 2]; v.w = m[4 * j4 + 3];
    mb[j4] = v;
  }

  if (COORD) {
    // w = silu(m @ cW1 + cb1) . cW2 + cb2 ; store diff*w (chunk-local)
    float v[64];
#pragma unroll
    for (int j = 0; j < 64; j++) v[j] = scb1[j];
#pragma unroll
    for (int k = 0; k < 64; k++) { ROW_FMA(v, m[k], scW1 + k * 64); }
    float w = cb2[0];
#pragma unroll
    for (int j = 0; j < 64; j++) w += silu_f(v[j]) * scW2[j];
    float4 cv;
    cv.x = dx * w; cv.y = dy * w; cv.z = dz * w; cv.w = 0.f;
    ((float4*)cw4)[le] = cv;
  }
}

// -------- wave-per-node segmented reduction over one chunk; accumulates across chunks --------
template <int COORD>
__global__ __launch_bounds__(256) void agg_chunk_kernel(
    const float* __restrict__ msg, const float* __restrict__ cw4,
    const int* __restrict__ rowptr, const float* __restrict__ posr, float* __restrict__ posw,
    float* __restrict__ agg, int N, int ce0, int ce1, int first)
{
  int w = (blockIdx.x * 256 + threadIdx.x) >> 6;  // one wave per node
  if (w >= N) return;
  int lane = threadIdx.x & 63;
  int s = rowptr[w];
  int t = rowptr[w + 1];
  int cs = s > ce0 ? s : ce0;
  int ct = t < ce1 ? t : ce1;
  if (first) {
    float acc = 0.f;
    for (int e = cs; e < ct; e++) acc += msg[(size_t)(e - ce0) * 64 + lane];
    agg[(size_t)w * 64 + lane] = acc;
    if (COORD) {
      if (lane < 3) {
        float p = 0.f;
        for (int e = cs; e < ct; e++) p += cw4[(size_t)(e - ce0) * 4 + lane];
        posw[(size_t)w * 3 + lane] = posr[(size_t)w * 3 + lane] + p;
      }
    }
  } else {
    if (cs < ct) {
      float acc = agg[(size_t)w * 64 + lane];
      for (int e = cs; e < ct; e++) acc += msg[(size_t)(e - ce0) * 64 + lane];
      agg[(size_t)w * 64 + lane] = acc;
      if (COORD) {
        if (lane < 3) {
          float p = 0.f;
          for (int e = cs; e < ct; e++) p += cw4[(size_t)(e - ce0) * 4 + lane];
          posw[(size_t)w * 3 + lane] += p;
        }
      }
    }
  }
}

// ---------------- atomic-path edge kernel (fallback for tiny ws) ----------------
template <int COORD>
__global__ __launch_bounds__(256) void edge_kernel(
    const int* __restrict__ row, const int* __restrict__ col,
    const float* __restrict__ posr, float* __restrict__ posw,
    const float* __restrict__ eattr,
    const float* __restrict__ P, const float* __restrict__ Q,
    const float* __restrict__ W1t,
    const float* __restrict__ b1, const float* __restrict__ W2, const float* __restrict__ b2,
    const float* __restrict__ cW1, const float* __restrict__ cb1,
    const float* __restrict__ cW2, const float* __restrict__ cb2,
    float* __restrict__ agg, int E)
{
  __shared__ float sW1t[4 * 64];
  __shared__ float sb1[64];
  __shared__ float sW2[64 * 64];
  __shared__ float sb2[64];
  __shared__ float scW1[COORD ? 64 * 64 : 1];
  __shared__ float scb1[COORD ? 64 : 1];
  __shared__ float scW2[COORD ? 64 : 1];

  int tid = threadIdx.x;
  for (int i = tid; i < 4 * 64; i += 256) sW1t[i] = W1t[i];
  for (int i = tid; i < 4096; i += 256) sW2[i] = W2[i];
  if (tid < 64) { sb1[tid] = b1[tid]; sb2[tid] = b2[tid]; }
  if (COORD) {
    for (int i = tid; i < 4096; i += 256) scW1[i] = cW1[i];
    if (tid < 64) { scb1[tid] = cb1[tid]; scW2[tid] = cW2[tid]; }
  }
  __syncthreads();

  int e = blockIdx.x * 256 + tid;
  if (e >= E) return;
  int r = row[e];
  int c = col[e];
  float dx = posr[(size_t)r * 3 + 0] - posr[(size_t)c * 3 + 0];
  float dy = posr[(size_t)r * 3 + 1] - posr[(size_t)c * 3 + 1];
  float dz = posr[(size_t)r * 3 + 2] - posr[(size_t)c * 3 + 2];
  float dist = sqrtf(dx * dx + dy * dy + dz * dz);
  float ea0 = eattr[(size_t)e * 3 + 0];
  float ea1 = eattr[(size_t)e * 3 + 1];
  float ea2 = eattr[(size_t)e * 3 + 2];

  float u[64];
  const float4* P4 = (const float4*)(P + (size_t)r * 64);
  const float4* Q4 = (const float4*)(Q + (size_t)c * 64);
#pragma unroll
  for (int j4 = 0; j4 < 16; j4++) {
    float4 p = P4[j4];
    float4 q = Q4[j4];
#pragma unroll
    for (int t = 0; t < 4; t++) {
      int j = 4 * j4 + t;
      float pv = (t == 0) ? p.x : (t == 1) ? p.y : (t == 2) ? p.z : p.w;
      float qv = (t == 0) ? q.x : (t == 1) ? q.y : (t == 2) ? q.z : q.w;
      float v = pv + qv + sb1[j] + dist * sW1t[j] + ea0 * sW1t[64 + j] + ea1 * sW1t[128 + j] +
                ea2 * sW1t[192 + j];
      u[j] = silu_f(v);
    }
  }
  float m[64];
#pragma unroll
  for (int j = 0; j < 64; j++) m[j] = sb2[j];
#pragma unroll
  for (int k = 0; k < 64; k++) { ROW_FMA(m, u[k], sW2 + k * 64); }
#pragma unroll
  for (int j = 0; j < 64; j++) m[j] = silu_f(m[j]);
  float* ar = agg + (size_t)r * 64;
#pragma unroll
  for (int j = 0; j < 64; j++) atomicAdd(ar + j, m[j]);
  if (COORD) {
    float v[64];
#pragma unroll
    for (int j = 0; j < 64; j++) v[j] = scb1[j];
#pragma unroll
    for (int k = 0; k < 64; k++) { ROW_FMA(v, m[k], scW1 + k * 64); }
    float w = cb2[0];
#pragma unroll
    for (int j = 0; j < 64; j++) w += silu_f(v[j]) * scW2[j];
    atomicAdd(&posw[(size_t)r * 3 + 0], dx * w);
    atomicAdd(&posw[(size_t)r * 3 + 1], dy * w);
    atomicAdd(&posw[(size_t)r * 3 + 2], dz * w);
  }
}

// ---------------- node MLP ----------------
__global__ __launch_bounds__(256) void node_kernel(
    float* __restrict__ h, const float* __restrict__ agg,
    const float* __restrict__ W1, const float* __restrict__ b1,
    const float* __restrict__ W2, const float* __restrict__ b2, int N)
{
  __shared__ float sW1[128 * 64];
  __shared__ float sW2[64 * 64];
  __shared__ float sb1[64];
  __shared__ float sb2[64];
  for (int i = threadIdx.x; i < 8192; i += 256) sW1[i] = W1[i];
  for (int i = threadIdx.x; i < 4096; i += 256) sW2[i] = W2[i];
  if (threadIdx.x < 64) { sb1[threadIdx.x] = b1[threadIdx.x]; sb2[threadIdx.x] = b2[threadIdx.x]; }
  __syncthreads();
  int n = blockIdx.x * 256 + threadIdx.x;
  if (n >= N) return;
  float u[64];
#pragma unroll
  for (int j = 0; j < 64; j++) u[j] = sb1[j];
  const float4* h4 = (const float4*)(h + (size_t)n * 64);
#pragma unroll
  for (int k4 = 0; k4 < 16; k4++) {
    float4 hv = h4[k4];
    ROW_FMA(u, hv.x, sW1 + (4 * k4 + 0) * 64);
    ROW_FMA(u, hv.y, sW1 + (4 * k4 + 1) * 64);
    ROW_FMA(u, hv.z, sW1 + (4 * k4 + 2) * 64);
    ROW_FMA(u, hv.w, sW1 + (4 * k4 + 3) * 64);
  }
  const float4* a4 = (const float4*)(agg + (size_t)n * 64);
#pragma unroll
  for (int k4 = 0; k4 < 16; k4++) {
    float4 av = a4[k4];
    ROW_FMA(u, av.x, sW1 + (64 + 4 * k4 + 0) * 64);
    ROW_FMA(u, av.y, sW1 + (64 + 4 * k4 + 1) * 64);
    ROW_FMA(u, av.z, sW1 + (64 + 4 * k4 + 2) * 64);
    ROW_FMA(u, av.w, sW1 + (64 + 4 * k4 + 3) * 64);
  }
#pragma unroll
  for (int j = 0; j < 64; j++) u[j] = silu_f(u[j]);
  float o[64];
#pragma unroll
  for (int j = 0; j < 64; j++) o[j] = sb2[j];
#pragma unroll
  for (int k = 0; k < 64; k++) { ROW_FMA(o, u[k], sW2 + k * 64); }
  float4* hw = (float4*)(h + (size_t)n * 64);
#pragma unroll
  for (int j4 = 0; j4 < 16; j4++) {
    float4 hv = h4[j4];
    float4 v;
    v.x = hv.x + o[4 * j4 + 0];
    v.y = hv.y + o[4 * j4 + 1];
    v.z = hv.z + o[4 * j4 + 2];
    v.w = hv.w + o[4 * j4 + 3];
    hw[j4] = v;
  }
}

// ---------------- pooling + classifier ----------------
__device__ __forceinline__ int lbound(const int* __restrict__ a, int n, int v)
{
  int lo = 0, hi = n;
  while (lo < hi) {
    int mid = (lo + hi) >> 1;
    if (a[mid] < v) lo = mid + 1;
    else hi = mid;
  }
  return lo;
}

__global__ __launch_bounds__(256) void pool_cls_kernel(
    const float* __restrict__ h, const int* __restrict__ batch, int N,
    const float* __restrict__ W1, const float* __restrict__ b1,
    const float* __restrict__ W2, const float* __restrict__ b2, float* __restrict__ out)
{
  int g = blockIdx.x;
  int start = lbound(batch, N, g);
  int end = lbound(batch, N, g + 1);
  int j = threadIdx.x & 63;
  int grp = threadIdx.x >> 6;  // 0..3
  float s = 0.f, mx = -INFINITY;
  for (int n = start + grp; n < end; n += 4) {
    float v = h[(size_t)n * 64 + j];
    s += v;
    mx = fmaxf(mx, v);
  }
  __shared__ float ssum[4][64];
  __shared__ float smax[4][64];
  __shared__ float pooled[128];
  __shared__ float su[64];
  ssum[grp][j] = s;
  smax[grp][j] = mx;
  __syncthreads();
  if (grp == 0) {
    float S = ssum[0][j] + ssum[1][j] + ssum[2][j] + ssum[3][j];
    float M = fmaxf(fmaxf(smax[0][j], smax[1][j]), fmaxf(smax[2][j], smax[3][j]));
    float cnt = (float)(end - start);
    pooled[j] = S / fmaxf(cnt, 1.0f);
    pooled[64 + j] = M;
  }
  __syncthreads();
  if (threadIdx.x < 64) {
    float a = b1[j];
#pragma unroll
    for (int k = 0; k < 128; k++) a += pooled[k] * W1[k * 64 + j];
    su[j] = fmaxf(a, 0.f);
  }
  __syncthreads();
  if (threadIdx.x < 2) {
    float a = b2[threadIdx.x];
#pragma unroll
    for (int k = 0; k < 64; k++) a += su[k] * W2[k * 2 + threadIdx.x];
    out[g * 2 + threadIdx.x] = a;
  }
}

extern "C" void kernel_launch(void* const* d_in, const int* in_sizes, int n_in,
                              void* d_out, int out_size, void* d_ws, size_t ws_size,
                              hipStream_t stream)
{
  const float* x = (const float*)d_in[0];
  const float* pos = (const float*)d_in[1];
  const int* ei = (const int*)d_in[2];
  const float* eattr = (const float*)d_in[3];
  const int* batch = (const int*)d_in[4];
  const float* projW = (const float*)d_in[5];
  const float* projb = (const float*)d_in[6];
  const float* msgW1 = (const float*)d_in[7];
  const float* msgb1 = (const float*)d_in[8];
  const float* msgW2 = (const float*)d_in[9];
  const float* msgb2 = (const float*)d_in[10];
  const float* ndW1 = (const float*)d_in[11];
  const float* ndb1 = (const float*)d_in[12];
  const float* ndW2 = (const float*)d_in[13];
  const float* ndb2 = (const float*)d_in[14];
  const float* cdW1 = (const float*)d_in[15];
  const float* cdb1 = (const float*)d_in[16];
  const float* cdW2 = (const float*)d_in[17];
  const float* cdb2 = (const float*)d_in[18];
  const float* clsW1 = (const float*)d_in[19];
  const float* clsb1 = (const float*)d_in[20];
  const float* clsW2 = (const float*)d_in[21];
  const float* clsb2 = (const float*)d_in[22];

  int N = in_sizes[4];
  int E = in_sizes[3] / 3;
  const int* rowp = ei;
  const int* colp = ei + E;

  // ---- workspace bump allocator (256B aligned) ----
  char* wsb = (char*)d_ws;
  size_t off = 0;
  auto alloc = [&](size_t bytes) {
    size_t o = off;
    off = (off + bytes + 255) & ~(size_t)255;
    return o;
  };
  size_t nh = (size_t)N * 64 * sizeof(float);
  size_t o_h = alloc(nh);
  size_t o_P = alloc(nh);
  size_t o_Q = alloc(nh);
  size_t o_agg = alloc(nh);
  size_t o_posA = alloc((size_t)N * 3 * sizeof(float));
  size_t o_posB = alloc((size_t)N * 3 * sizeof(float));
  size_t o_cnt = alloc((size_t)N * sizeof(int));
  size_t o_rowptr = alloc(((size_t)N + 1) * sizeof(int));
  size_t o_cursor = alloc((size_t)N * sizeof(int));
  size_t o_srow = alloc((size_t)E * sizeof(int));
  size_t o_scol = alloc((size_t)E * sizeof(int));
  size_t o_sea = alloc((size_t)E * 3 * sizeof(float));
  size_t csr_end = off;  // ~69 MB at N=50K, E=800K

  float* h = (float*)(wsb + o_h);
  float* Pb = (float*)(wsb + o_P);
  float* Qb = (float*)(wsb + o_Q);
  float* agg = (float*)(wsb + o_agg);
  float* posA = (float*)(wsb + o_posA);
  float* posB = (float*)(wsb + o_posB);

  int nb_nodes = (N + 255) / 256;
  int nb_edges = (E + 255) / 256;
  int G = out_size / 2;

  // chunk sizing: msg (256B/edge) + cw4 (16B/edge) from remaining workspace
  long long avail = (ws_size > csr_end) ? (long long)(ws_size - csr_end) - 512 : 0;
  long long per_edge = 64 * 4 + 16;
  long long chunk_max = (avail / per_edge) & ~255LL;
  bool use_sorted = chunk_max >= 16384;
  int nchunks = 0, chunkE = 0;
  if (use_sorted) {
    nchunks = (int)(((long long)E + chunk_max - 1) / chunk_max);
    chunkE = (int)((((long long)E + nchunks - 1) / nchunks + 255) & ~255LL);
  }

  proj_kernel<<<nb_nodes, 256, 0, stream>>>(x, projW, projb, h, N);

  const float* pr[4] = {pos, posA, posB, posA};
  float* pw[4] = {posA, posB, posA, nullptr};

  if (use_sorted) {
    int* cnt = (int*)(wsb + o_cnt);
    int* rowptr = (int*)(wsb + o_rowptr);
    int* cursor = (int*)(wsb + o_cursor);
    int* srow = (int*)(wsb + o_srow);
    int* scol = (int*)(wsb + o_scol);
    float* sea = (float*)(wsb + o_sea);
    size_t o_msg = alloc((size_t)chunkE * 64 * sizeof(float));
    size_t o_cw4 = alloc((size_t)chunkE * 4 * sizeof(float));
    float* msg = (float*)(wsb + o_msg);
    float* cw4 = (float*)(wsb + o_cw4);

    hipMemsetAsync(cnt, 0, (size_t)N * sizeof(int), stream);
    hist_kernel<<<nb_edges, 256, 0, stream>>>(rowp, cnt, E);
    scan_kernel<<<1, 1024, 0, stream>>>(cnt, rowptr, cursor, N, E);
    scatter_kernel<<<nb_edges, 256, 0, stream>>>(rowp, colp, eattr, cursor, srow, scol, sea, E);

    int nb_agg = (N * 64 + 255) / 256;  // one wave per node
    for (int i = 0; i < 4; i++) {
      premul_kernel<<<nb_nodes, 256, 0, stream>>>(h, msgW1 + (size_t)i * 132 * 64, Pb, Qb, N);
      for (int c = 0; c < nchunks; c++) {
        int ce0 = c * chunkE;
        int ce1 = (ce0 + chunkE < E) ? ce0 + chunkE : E;
        if (ce0 >= ce1) continue;
        int nb_ch = (ce1 - ce0 + 255) / 256;
        if (i < 3) {
          edge_sorted_kernel<1><<<nb_ch, 256, 0, stream>>>(
              srow, scol, pr[i], sea, Pb, Qb,
              msgW1 + (size_t)i * 132 * 64 + 128 * 64, msgb1 + i * 64,
              msgW2 + (size_t)i * 4096, msgb2 + i * 64,
              cdW1 + (size_t)i * 4096, cdb1 + i * 64, cdW2 + i * 64, cdb2 + i, msg, cw4, ce0,
              ce1);
          agg_chunk_kernel<1><<<nb_agg, 256, 0, stream>>>(msg, cw4, rowptr, pr[i], pw[i], agg, N,
                                                          ce0, ce1, c == 0 ? 1 : 0);
        } else {
          edge_sorted_kernel<0><<<nb_ch, 256, 0, stream>>>(
              srow, scol, pr[i], sea, Pb, Qb,
              msgW1 + (size_t)i * 132 * 64 + 128 * 64, msgb1 + i * 64,
              msgW2 + (size_t)i * 4096, msgb2 + i * 64,
              nullptr, nullptr, nullptr, nullptr, msg, cw4, ce0, ce1);
          agg_chunk_kernel<0><<<nb_agg, 256, 0, stream>>>(msg, cw4, rowptr, pr[i], nullptr, agg,
                                                          N, ce0, ce1, c == 0 ? 1 : 0);
        }
      }
      node_kernel<<<nb_nodes, 256, 0, stream>>>(
          h, agg, ndW1 + (size_t)i * 8192, ndb1 + i * 64, ndW2 + (size_t)i * 4096, ndb2 + i * 64,
          N);
    }
  } else {
    // fallback: atomic aggregation path (correct at any ws_size >= base buffers)
    for (int i = 0; i < 4; i++) {
      premul_kernel<<<nb_nodes, 256, 0, stream>>>(h, msgW1 + (size_t)i * 132 * 64, Pb, Qb, N);
      hipMemsetAsync(agg, 0, nh, stream);
      if (i < 3) {
        hipMemcpyAsync(pw[i], pr[i], (size_t)N * 3 * sizeof(float), hipMemcpyDeviceToDevice,
                       stream);
        edge_kernel<1><<<nb_edges, 256, 0, stream>>>(
            rowp, colp, pr[i], pw[i], eattr, Pb, Qb,
            msgW1 + (size_t)i * 132 * 64 + 128 * 64, msgb1 + i * 64,
            msgW2 + (size_t)i * 4096, msgb2 + i * 64,
            cdW1 + (size_t)i * 4096, cdb1 + i * 64, cdW2 + i * 64, cdb2 + i, agg, E);
      } else {
        edge_kernel<0><<<nb_edges, 256, 0, stream>>>(
            rowp, colp, pr[i], nullptr, eattr, Pb, Qb,
            msgW1 + (size_t)i * 132 * 64 + 128 * 64, msgb1 + i * 64,
            msgW2 + (size_t)i * 4096, msgb2 + i * 64,
            nullptr, nullptr, nullptr, nullptr, agg, E);
      }
      node_kernel<<<nb_nodes, 256, 0, stream>>>(
          h, agg, ndW1 + (size_t)i * 8192, ndb1 + i * 64, ndW2 + (size_t)i * 4096, ndb2 + i * 64,
          N);
    }
  }

  pool_cls_kernel<<<G, 256, 0, stream>>>(h, batch, N, clsW1, clsb1, clsW2, clsb2, (float*)d_out);
}

// Round 7
// 4009.272 us; speedup vs baseline: 3.5401x; 1.8567x over previous
//
#include <hip/hip_runtime.h>
#include <math.h>

// EGNN forward, fp32. P/Q factorization + CSR edge sort.
// Round 7: fused edge kernel — block of 128 sorted edges; LDS-staged
// transposed u-tile; register-tiled 4x8 GEMMs (msg W2, coord W1); in-block
// segmented reduction for agg (exclusive stores for interior rows, atomics
// only at block-boundary rows) and pos update. No msg round-trip, no chunks.

__device__ __forceinline__ float silu_f(float x) { return x / (1.0f + __expf(-x)); }

#define ROW_FMA(acc, scal, rowptr)                                                   \
  {                                                                                  \
    const float4* _w = (const float4*)(rowptr);                                      \
    _Pragma("unroll") for (int _j = 0; _j < 16; _j++)                                \
    {                                                                                \
      float4 _wv = _w[_j];                                                           \
      acc[4 * _j + 0] += (scal) * _wv.x;                                             \
      acc[4 * _j + 1] += (scal) * _wv.y;                                             \
      acc[4 * _j + 2] += (scal) * _wv.z;                                             \
      acc[4 * _j + 3] += (scal) * _wv.w;                                             \
    }                                                                                \
  }

// ---------------- proj ----------------
__global__ __launch_bounds__(256) void proj_kernel(
    const float* __restrict__ x, const float* __restrict__ W, const float* __restrict__ b,
    float* __restrict__ h, int N)
{
  __shared__ float sW[26 * 64];
  __shared__ float sb[64];
  for (int i = threadIdx.x; i < 26 * 64; i += 256) sW[i] = W[i];
  if (threadIdx.x < 64) sb[threadIdx.x] = b[threadIdx.x];
  __syncthreads();
  int n = blockIdx.x * 256 + threadIdx.x;
  if (n >= N) return;
  float acc[64];
#pragma unroll
  for (int j = 0; j < 64; j++) acc[j] = sb[j];
#pragma unroll
  for (int k = 0; k < 26; k++) {
    float xk = x[(size_t)n * 26 + k];
    ROW_FMA(acc, xk, sW + k * 64);
  }
  float4* h4 = (float4*)(h + (size_t)n * 64);
#pragma unroll
  for (int j4 = 0; j4 < 16; j4++) {
    float4 v;
    v.x = acc[4 * j4 + 0]; v.y = acc[4 * j4 + 1]; v.z = acc[4 * j4 + 2]; v.w = acc[4 * j4 + 3];
    h4[j4] = v;
  }
}

// ---------------- premul: P = h @ W1[0:64], Q = h @ W1[64:128] ----------------
__global__ __launch_bounds__(256) void premul_kernel(
    const float* __restrict__ h, const float* __restrict__ W1,
    float* __restrict__ P, float* __restrict__ Q, int N)
{
  __shared__ float sW[128 * 64];
  for (int i = threadIdx.x; i < 128 * 64; i += 256) sW[i] = W1[i];
  __syncthreads();
  int n = blockIdx.x * 256 + threadIdx.x;
  if (n >= N) return;
  float hr[64];
  const float4* h4 = (const float4*)(h + (size_t)n * 64);
#pragma unroll
  for (int i = 0; i < 16; i++) {
    float4 v = h4[i];
    hr[4 * i] = v.x; hr[4 * i + 1] = v.y; hr[4 * i + 2] = v.z; hr[4 * i + 3] = v.w;
  }
  float acc[64];
#pragma unroll
  for (int j = 0; j < 64; j++) acc[j] = 0.f;
#pragma unroll
  for (int k = 0; k < 64; k++) { ROW_FMA(acc, hr[k], sW + k * 64); }
  float4* P4 = (float4*)(P + (size_t)n * 64);
#pragma unroll
  for (int j4 = 0; j4 < 16; j4++) {
    float4 v;
    v.x = acc[4 * j4 + 0]; v.y = acc[4 * j4 + 1]; v.z = acc[4 * j4 + 2]; v.w = acc[4 * j4 + 3];
    P4[j4] = v;
  }
#pragma unroll
  for (int j = 0; j < 64; j++) acc[j] = 0.f;
#pragma unroll
  for (int k = 0; k < 64; k++) { ROW_FMA(acc, hr[k], sW + (64 + k) * 64); }
  float4* Q4 = (float4*)(Q + (size_t)n * 64);
#pragma unroll
  for (int j4 = 0; j4 < 16; j4++) {
    float4 v;
    v.x = acc[4 * j4 + 0]; v.y = acc[4 * j4 + 1]; v.z = acc[4 * j4 + 2]; v.w = acc[4 * j4 + 3];
    Q4[j4] = v;
  }
}

// ---------------- CSR build ----------------
__global__ __launch_bounds__(256) void hist_kernel(
    const int* __restrict__ row, int* __restrict__ cnt, int E)
{
  int e = blockIdx.x * 256 + threadIdx.x;
  if (e < E) atomicAdd(&cnt[row[e]], 1);
}

__global__ __launch_bounds__(1024) void scan_kernel(
    const int* __restrict__ cnt, int* __restrict__ rowptr, int* __restrict__ cursor, int N, int E)
{
  __shared__ int part[1024];
  int t = threadIdx.x;
  int chunk = (N + 1023) >> 10;
  int lo = t * chunk;
  int hi = lo + chunk;
  if (lo > N) lo = N;
  if (hi > N) hi = N;
  int s = 0;
  for (int i = lo; i < hi; i++) s += cnt[i];
  part[t] = s;
  __syncthreads();
  for (int off = 1; off < 1024; off <<= 1) {
    int v = 0;
    if (t >= off) v = part[t - off];
    __syncthreads();
    if (t >= off) part[t] += v;
    __syncthreads();
  }
  int run = part[t] - s;  // exclusive base for this chunk
  for (int i = lo; i < hi; i++) {
    rowptr[i] = run;
    cursor[i] = run;
    run += cnt[i];
  }
  if (t == 0) rowptr[N] = E;
}

__global__ __launch_bounds__(256) void scatter_kernel(
    const int* __restrict__ row, const int* __restrict__ col, const float* __restrict__ eattr,
    int* __restrict__ cursor, int* __restrict__ srow, int* __restrict__ scol,
    float* __restrict__ sea4, int E)
{
  int e = blockIdx.x * 256 + threadIdx.x;
  if (e >= E) return;
  int r = row[e];
  int p = atomicAdd(&cursor[r], 1);
  srow[p] = r;
  scol[p] = col[e];
  float4 v;
  v.x = eattr[(size_t)e * 3 + 0];
  v.y = eattr[(size_t)e * 3 + 1];
  v.z = eattr[(size_t)e * 3 + 2];
  v.w = 0.f;
  ((float4*)sea4)[p] = v;
}

// ---------------- fused edge kernel ----------------
// Block: 128 sorted edges, 256 threads.
// Stage1: 2 threads/edge compute u = silu(P[r]+Q[c]+dist*w+ea*w+b1), store
//         transposed sU[k][edge] (stride 132).
// Stage2: 4x8 register-tiled GEMM m = silu(u@W2+b2) -> sM (reuse sU).
// Stage3 (COORD): tiled GEMM v-partial, per-edge w_e = silu(m@cW1+cb1).cW2+cb2.
// Stage4: wave0 segmented-reduce sM by row -> agg (store interior / atomic
//         boundary); lanes 64..66 reduce diff*w_e -> posw (atomic).
#define EB 128
#define ESTR 132

template <int COORD>
__global__ __launch_bounds__(256) void edge_fused_kernel(
    const int* __restrict__ srow, const int* __restrict__ scol, const int* __restrict__ rowptr,
    const float* __restrict__ posr, float* __restrict__ posw,
    const float* __restrict__ sea4,
    const float* __restrict__ P, const float* __restrict__ Q,
    const float* __restrict__ W1t, const float* __restrict__ b1,
    const float* __restrict__ W2, const float* __restrict__ b2,
    const float* __restrict__ cW1, const float* __restrict__ cb1,
    const float* __restrict__ cW2, const float* __restrict__ cb2,
    float* __restrict__ agg, int E)
{
  __shared__ float sU[64 * ESTR];  // [k][edge], also reused as sM
  __shared__ float sW2[64 * 64];
  __shared__ float sW1t[4 * 64];
  __shared__ float sb1v[64], sb2v[64];
  __shared__ int s_srow[EB];
  __shared__ float sDiff[3][ESTR];
  __shared__ float sWe[EB];
  __shared__ float scW1[COORD ? 64 * 64 : 1];
  __shared__ float scb1v[COORD ? 64 : 1];
  __shared__ float scW2v[COORD ? 64 : 1];
  __shared__ float sPart[COORD ? EB * 9 : 1];

  int t = threadIdx.x;
  // ---- stage weights ----
  for (int i = t; i < 4096; i += 256) sW2[i] = W2[i];
  for (int i = t; i < 256; i += 256) sW1t[i] = W1t[i];
  if (t < 64) { sb1v[t] = b1[t]; sb2v[t] = b2[t]; }
  if (COORD) {
    for (int i = t; i < 4096; i += 256) scW1[i] = cW1[i];
    if (t < 64) { scb1v[t] = cb1[t]; scW2v[t] = cW2[t]; }
  }
  __syncthreads();

  int e0 = blockIdx.x * EB;
  int nE = E - e0; if (nE > EB) nE = EB;

  // ---- stage 1: u tile ----
  {
    int eloc = t & 127;
    int half = t >> 7;
    int e = e0 + eloc;
    if (e < E) {
      int r = srow[e];
      int c = scol[e];
      if (half == 0) s_srow[eloc] = r;
      float prx = posr[(size_t)r * 3 + 0], pry = posr[(size_t)r * 3 + 1],
            prz = posr[(size_t)r * 3 + 2];
      float pcx = posr[(size_t)c * 3 + 0], pcy = posr[(size_t)c * 3 + 1],
            pcz = posr[(size_t)c * 3 + 2];
      float dx = prx - pcx, dy = pry - pcy, dz = prz - pcz;
      float dist = sqrtf(dx * dx + dy * dy + dz * dz);
      if (half == 0) { sDiff[0][eloc] = dx; sDiff[1][eloc] = dy; sDiff[2][eloc] = dz; }
      float4 ea = ((const float4*)sea4)[e];
      int k0 = half * 32;
      const float4* P4 = (const float4*)(P + (size_t)r * 64 + k0);
      const float4* Q4 = (const float4*)(Q + (size_t)c * 64 + k0);
#pragma unroll
      for (int q = 0; q < 8; q++) {
        float4 p = P4[q];
        float4 qq = Q4[q];
#pragma unroll
        for (int comp = 0; comp < 4; comp++) {
          int kk = 4 * q + comp;
          int k = k0 + kk;
          float pv = (comp == 0) ? p.x : (comp == 1) ? p.y : (comp == 2) ? p.z : p.w;
          float qv = (comp == 0) ? qq.x : (comp == 1) ? qq.y : (comp == 2) ? qq.z : qq.w;
          float val = pv + qv + sb1v[k] + dist * sW1t[k] + ea.x * sW1t[64 + k] +
                      ea.y * sW1t[128 + k] + ea.z * sW1t[192 + k];
          sU[k * ESTR + eloc] = silu_f(val);
        }
      }
    } else {
      int k0 = half * 32;
#pragma unroll
      for (int kk = 0; kk < 32; kk++) sU[(k0 + kk) * ESTR + eloc] = 0.f;
    }
  }
  __syncthreads();

  // ---- stage 2: m = silu(u @ W2 + b2), 4 rows x 8 cols per thread ----
  int rg = t & 31;   // row group: rows 4rg..4rg+3
  int cg = t >> 5;   // col group: cols 8cg..8cg+7
  float m[4][8];
#pragma unroll
  for (int i = 0; i < 4; i++)
#pragma unroll
    for (int j = 0; j < 8; j++) m[i][j] = 0.f;
  {
    const float4* sU4 = (const float4*)sU;
    const float4* sW24 = (const float4*)sW2;
#pragma unroll 8
    for (int k = 0; k < 64; k++) {
      float4 a = sU4[k * (ESTR / 4) + rg];
      float4 w0 = sW24[k * 16 + 2 * cg];
      float4 w1 = sW24[k * 16 + 2 * cg + 1];
#pragma unroll
      for (int i = 0; i < 4; i++) {
        float av = (i == 0) ? a.x : (i == 1) ? a.y : (i == 2) ? a.z : a.w;
        m[i][0] += av * w0.x; m[i][1] += av * w0.y;
        m[i][2] += av * w0.z; m[i][3] += av * w0.w;
        m[i][4] += av * w1.x; m[i][5] += av * w1.y;
        m[i][6] += av * w1.z; m[i][7] += av * w1.w;
      }
    }
  }
#pragma unroll
  for (int i = 0; i < 4; i++)
#pragma unroll
    for (int j = 0; j < 8; j++) m[i][j] = silu_f(m[i][j] + sb2v[8 * cg + j]);
  __syncthreads();  // all reads of sU done
  // write m transposed into sU (now sM[k][edge])
#pragma unroll
  for (int j = 0; j < 8; j++)
#pragma unroll
    for (int i = 0; i < 4; i++) sU[(8 * cg + j) * ESTR + (4 * rg + i)] = m[i][j];
  __syncthreads();

  // ---- stage 3 (COORD): w_e = silu(m @ cW1 + cb1) . cW2 + cb2 ----
  if (COORD) {
    float v[4][8];
#pragma unroll
    for (int i = 0; i < 4; i++)
#pragma unroll
      for (int j = 0; j < 8; j++) v[i][j] = 0.f;
    const float4* sU4 = (const float4*)sU;
    const float4* sC4 = (const float4*)scW1;
#pragma unroll 8
    for (int k = 0; k < 64; k++) {
      float4 a = sU4[k * (ESTR / 4) + rg];
      float4 w0 = sC4[k * 16 + 2 * cg];
      float4 w1 = sC4[k * 16 + 2 * cg + 1];
#pragma unroll
      for (int i = 0; i < 4; i++) {
        float av = (i == 0) ? a.x : (i == 1) ? a.y : (i == 2) ? a.z : a.w;
        v[i][0] += av * w0.x; v[i][1] += av * w0.y;
        v[i][2] += av * w0.z; v[i][3] += av * w0.w;
        v[i][4] += av * w1.x; v[i][5] += av * w1.y;
        v[i][6] += av * w1.z; v[i][7] += av * w1.w;
      }
    }
#pragma unroll
    for (int i = 0; i < 4; i++) {
      float part = 0.f;
#pragma unroll
      for (int j = 0; j < 8; j++)
        part += silu_f(v[i][j] + scb1v[8 * cg + j]) * scW2v[8 * cg + j];
      sPart[(4 * rg + i) * 9 + cg] = part;
    }
    __syncthreads();
    if (t < EB) {
      float w = cb2[0];
#pragma unroll
      for (int g = 0; g < 8; g++) w += sPart[t * 9 + g];
      sWe[t] = w;
    }
    __syncthreads();
  }

  // ---- stage 4: segmented reductions ----
  int e1 = e0 + nE;
  if (t < 64) {
    // agg: lane = dim j, sequential scan over block edges
    int j = t;
    float acc = 0.f;
    int cur = s_srow[0];
    for (int le = 0; le < nE; le++) {
      int r = s_srow[le];
      if (r != cur) {
        bool interior = (rowptr[cur] >= e0) && (rowptr[cur + 1] <= e1);
        if (interior) agg[(size_t)cur * 64 + j] = acc;
        else atomicAdd(&agg[(size_t)cur * 64 + j], acc);
        acc = 0.f;
        cur = r;
      }
      acc += sU[j * ESTR + le];
    }
    bool interior = (rowptr[cur] >= e0) && (rowptr[cur + 1] <= e1);
    if (interior) agg[(size_t)cur * 64 + j] = acc;
    else atomicAdd(&agg[(size_t)cur * 64 + j], acc);
  } else if (COORD && t >= 64 && t < 67) {
    int d = t - 64;
    float acc = 0.f;
    int cur = s_srow[0];
    for (int le = 0; le < nE; le++) {
      int r = s_srow[le];
      if (r != cur) {
        atomicAdd(&posw[(size_t)cur * 3 + d], acc);
        acc = 0.f;
        cur = r;
      }
      acc += sDiff[d][le] * sWe[le];
    }
    atomicAdd(&posw[(size_t)cur * 3 + d], acc);
  }
}

// ---------------- atomic-path edge kernel (fallback for tiny ws) ----------------
template <int COORD>
__global__ __launch_bounds__(256) void edge_kernel(
    const int* __restrict__ row, const int* __restrict__ col,
    const float* __restrict__ posr, float* __restrict__ posw,
    const float* __restrict__ eattr,
    const float* __restrict__ P, const float* __restrict__ Q,
    const float* __restrict__ W1t,
    const float* __restrict__ b1, const float* __restrict__ W2, const float* __restrict__ b2,
    const float* __restrict__ cW1, const float* __restrict__ cb1,
    const float* __restrict__ cW2, const float* __restrict__ cb2,
    float* __restrict__ agg, int E)
{
  __shared__ float sW1t[4 * 64];
  __shared__ float sb1[64];
  __shared__ float sW2[64 * 64];
  __shared__ float sb2[64];
  __shared__ float scW1[COORD ? 64 * 64 : 1];
  __shared__ float scb1[COORD ? 64 : 1];
  __shared__ float scW2[COORD ? 64 : 1];

  int tid = threadIdx.x;
  for (int i = tid; i < 4 * 64; i += 256) sW1t[i] = W1t[i];
  for (int i = tid; i < 4096; i += 256) sW2[i] = W2[i];
  if (tid < 64) { sb1[tid] = b1[tid]; sb2[tid] = b2[tid]; }
  if (COORD) {
    for (int i = tid; i < 4096; i += 256) scW1[i] = cW1[i];
    if (tid < 64) { scb1[tid] = cb1[tid]; scW2[tid] = cW2[tid]; }
  }
  __syncthreads();

  int e = blockIdx.x * 256 + tid;
  if (e >= E) return;
  int r = row[e];
  int c = col[e];
  float dx = posr[(size_t)r * 3 + 0] - posr[(size_t)c * 3 + 0];
  float dy = posr[(size_t)r * 3 + 1] - posr[(size_t)c * 3 + 1];
  float dz = posr[(size_t)r * 3 + 2] - posr[(size_t)c * 3 + 2];
  float dist = sqrtf(dx * dx + dy * dy + dz * dz);
  float ea0 = eattr[(size_t)e * 3 + 0];
  float ea1 = eattr[(size_t)e * 3 + 1];
  float ea2 = eattr[(size_t)e * 3 + 2];

  float u[64];
  const float4* P4 = (const float4*)(P + (size_t)r * 64);
  const float4* Q4 = (const float4*)(Q + (size_t)c * 64);
#pragma unroll
  for (int j4 = 0; j4 < 16; j4++) {
    float4 p = P4[j4];
    float4 q = Q4[j4];
#pragma unroll
    for (int tt = 0; tt < 4; tt++) {
      int j = 4 * j4 + tt;
      float pv = (tt == 0) ? p.x : (tt == 1) ? p.y : (tt == 2) ? p.z : p.w;
      float qv = (tt == 0) ? q.x : (tt == 1) ? q.y : (tt == 2) ? q.z : q.w;
      float v = pv + qv + sb1[j] + dist * sW1t[j] + ea0 * sW1t[64 + j] + ea1 * sW1t[128 + j] +
                ea2 * sW1t[192 + j];
      u[j] = silu_f(v);
    }
  }
  float m[64];
#pragma unroll
  for (int j = 0; j < 64; j++) m[j] = sb2[j];
#pragma unroll
  for (int k = 0; k < 64; k++) { ROW_FMA(m, u[k], sW2 + k * 64); }
#pragma unroll
  for (int j = 0; j < 64; j++) m[j] = silu_f(m[j]);
  float* ar = agg + (size_t)r * 64;
#pragma unroll
  for (int j = 0; j < 64; j++) atomicAdd(ar + j, m[j]);
  if (COORD) {
    float v[64];
#pragma unroll
    for (int j = 0; j < 64; j++) v[j] = scb1[j];
#pragma unroll
    for (int k = 0; k < 64; k++) { ROW_FMA(v, m[k], scW1 + k * 64); }
    float w = cb2[0];
#pragma unroll
    for (int j = 0; j < 64; j++) w += silu_f(v[j]) * scW2[j];
    atomicAdd(&posw[(size_t)r * 3 + 0], dx * w);
    atomicAdd(&posw[(size_t)r * 3 + 1], dy * w);
    atomicAdd(&posw[(size_t)r * 3 + 2], dz * w);
  }
}

// ---------------- node MLP ----------------
__global__ __launch_bounds__(256) void node_kernel(
    float* __restrict__ h, const float* __restrict__ agg,
    const float* __restrict__ W1, const float* __restrict__ b1,
    const float* __restrict__ W2, const float* __restrict__ b2, int N)
{
  __shared__ float sW1[128 * 64];
  __shared__ float sW2[64 * 64];
  __shared__ float sb1[64];
  __shared__ float sb2[64];
  for (int i = threadIdx.x; i < 8192; i += 256) sW1[i] = W1[i];
  for (int i = threadIdx.x; i < 4096; i += 256) sW2[i] = W2[i];
  if (threadIdx.x < 64) { sb1[threadIdx.x] = b1[threadIdx.x]; sb2[threadIdx.x] = b2[threadIdx.x]; }
  __syncthreads();
  int n = blockIdx.x * 256 + threadIdx.x;
  if (n >= N) return;
  float u[64];
#pragma unroll
  for (int j = 0; j < 64; j++) u[j] = sb1[j];
  const float4* h4 = (const float4*)(h + (size_t)n * 64);
#pragma unroll
  for (int k4 = 0; k4 < 16; k4++) {
    float4 hv = h4[k4];
    ROW_FMA(u, hv.x, sW1 + (4 * k4 + 0) * 64);
    ROW_FMA(u, hv.y, sW1 + (4 * k4 + 1) * 64);
    ROW_FMA(u, hv.z, sW1 + (4 * k4 + 2) * 64);
    ROW_FMA(u, hv.w, sW1 + (4 * k4 + 3) * 64);
  }
  const float4* a4 = (const float4*)(agg + (size_t)n * 64);
#pragma unroll
  for (int k4 = 0; k4 < 16; k4++) {
    float4 av = a4[k4];
    ROW_FMA(u, av.x, sW1 + (64 + 4 * k4 + 0) * 64);
    ROW_FMA(u, av.y, sW1 + (64 + 4 * k4 + 1) * 64);
    ROW_FMA(u, av.z, sW1 + (64 + 4 * k4 + 2) * 64);
    ROW_FMA(u, av.w, sW1 + (64 + 4 * k4 + 3) * 64);
  }
#pragma unroll
  for (int j = 0; j < 64; j++) u[j] = silu_f(u[j]);
  float o[64];
#pragma unroll
  for (int j = 0; j < 64; j++) o[j] = sb2[j];
#pragma unroll
  for (int k = 0; k < 64; k++) { ROW_FMA(o, u[k], sW2 + k * 64); }
  float4* hw = (float4*)(h + (size_t)n * 64);
#pragma unroll
  for (int j4 = 0; j4 < 16; j4++) {
    float4 hv = h4[j4];
    float4 v;
    v.x = hv.x + o[4 * j4 + 0];
    v.y = hv.y + o[4 * j4 + 1];
    v.z = hv.z + o[4 * j4 + 2];
    v.w = hv.w + o[4 * j4 + 3];
    hw[j4] = v;
  }
}

// ---------------- pooling + classifier ----------------
__device__ __forceinline__ int lbound(const int* __restrict__ a, int n, int v)
{
  int lo = 0, hi = n;
  while (lo < hi) {
    int mid = (lo + hi) >> 1;
    if (a[mid] < v) lo = mid + 1;
    else hi = mid;
  }
  return lo;
}

__global__ __launch_bounds__(256) void pool_cls_kernel(
    const float* __restrict__ h, const int* __restrict__ batch, int N,
    const float* __restrict__ W1, const float* __restrict__ b1,
    const float* __restrict__ W2, const float* __restrict__ b2, float* __restrict__ out)
{
  int g = blockIdx.x;
  int start = lbound(batch, N, g);
  int end = lbound(batch, N, g + 1);
  int j = threadIdx.x & 63;
  int grp = threadIdx.x >> 6;  // 0..3
  float s = 0.f, mx = -INFINITY;
  for (int n = start + grp; n < end; n += 4) {
    float v = h[(size_t)n * 64 + j];
    s += v;
    mx = fmaxf(mx, v);
  }
  __shared__ float ssum[4][64];
  __shared__ float smax[4][64];
  __shared__ float pooled[128];
  __shared__ float su[64];
  ssum[grp][j] = s;
  smax[grp][j] = mx;
  __syncthreads();
  if (grp == 0) {
    float S = ssum[0][j] + ssum[1][j] + ssum[2][j] + ssum[3][j];
    float M = fmaxf(fmaxf(smax[0][j], smax[1][j]), fmaxf(smax[2][j], smax[3][j]));
    float cnt = (float)(end - start);
    pooled[j] = S / fmaxf(cnt, 1.0f);
    pooled[64 + j] = M;
  }
  __syncthreads();
  if (threadIdx.x < 64) {
    float a = b1[j];
#pragma unroll
    for (int k = 0; k < 128; k++) a += pooled[k] * W1[k * 64 + j];
    su[j] = fmaxf(a, 0.f);
  }
  __syncthreads();
  if (threadIdx.x < 2) {
    float a = b2[threadIdx.x];
#pragma unroll
    for (int k = 0; k < 64; k++) a += su[k] * W2[k * 2 + threadIdx.x];
    out[g * 2 + threadIdx.x] = a;
  }
}

extern "C" void kernel_launch(void* const* d_in, const int* in_sizes, int n_in,
                              void* d_out, int out_size, void* d_ws, size_t ws_size,
                              hipStream_t stream)
{
  const float* x = (const float*)d_in[0];
  const float* pos = (const float*)d_in[1];
  const int* ei = (const int*)d_in[2];
  const float* eattr = (const float*)d_in[3];
  const int* batch = (const int*)d_in[4];
  const float* projW = (const float*)d_in[5];
  const float* projb = (const float*)d_in[6];
  const float* msgW1 = (const float*)d_in[7];
  const float* msgb1 = (const float*)d_in[8];
  const float* msgW2 = (const float*)d_in[9];
  const float* msgb2 = (const float*)d_in[10];
  const float* ndW1 = (const float*)d_in[11];
  const float* ndb1 = (const float*)d_in[12];
  const float* ndW2 = (const float*)d_in[13];
  const float* ndb2 = (const float*)d_in[14];
  const float* cdW1 = (const float*)d_in[15];
  const float* cdb1 = (const float*)d_in[16];
  const float* cdW2 = (const float*)d_in[17];
  const float* cdb2 = (const float*)d_in[18];
  const float* clsW1 = (const float*)d_in[19];
  const float* clsb1 = (const float*)d_in[20];
  const float* clsW2 = (const float*)d_in[21];
  const float* clsb2 = (const float*)d_in[22];

  int N = in_sizes[4];
  int E = in_sizes[3] / 3;
  const int* rowp = ei;
  const int* colp = ei + E;

  // ---- workspace bump allocator (256B aligned) ----
  char* wsb = (char*)d_ws;
  size_t off = 0;
  auto alloc = [&](size_t bytes) {
    size_t o = off;
    off = (off + bytes + 255) & ~(size_t)255;
    return o;
  };
  size_t nh = (size_t)N * 64 * sizeof(float);
  size_t o_h = alloc(nh);
  size_t o_P = alloc(nh);
  size_t o_Q = alloc(nh);
  size_t o_agg = alloc(nh);
  size_t o_posA = alloc((size_t)N * 3 * sizeof(float));
  size_t o_posB = alloc((size_t)N * 3 * sizeof(float));
  size_t o_cnt = alloc((size_t)N * sizeof(int));
  size_t o_rowptr = alloc(((size_t)N + 1) * sizeof(int));
  size_t o_cursor = alloc((size_t)N * sizeof(int));
  size_t o_srow = alloc((size_t)E * sizeof(int));
  size_t o_scol = alloc((size_t)E * sizeof(int));
  size_t o_sea4 = alloc((size_t)E * 4 * sizeof(float));
  size_t csr_end = off;  // ~73 MB at N=50K, E=800K

  float* h = (float*)(wsb + o_h);
  float* Pb = (float*)(wsb + o_P);
  float* Qb = (float*)(wsb + o_Q);
  float* agg = (float*)(wsb + o_agg);
  float* posA = (float*)(wsb + o_posA);
  float* posB = (float*)(wsb + o_posB);

  int nb_nodes = (N + 255) / 256;
  int nb_edges = (E + 255) / 256;
  int G = out_size / 2;

  proj_kernel<<<nb_nodes, 256, 0, stream>>>(x, projW, projb, h, N);

  const float* pr[4] = {pos, posA, posB, posA};
  float* pw[4] = {posA, posB, posA, nullptr};

  bool use_sorted = (csr_end <= ws_size);

  if (use_sorted) {
    int* cnt = (int*)(wsb + o_cnt);
    int* rowptr = (int*)(wsb + o_rowptr);
    int* cursor = (int*)(wsb + o_cursor);
    int* srow = (int*)(wsb + o_srow);
    int* scol = (int*)(wsb + o_scol);
    float* sea4 = (float*)(wsb + o_sea4);

    hipMemsetAsync(cnt, 0, (size_t)N * sizeof(int), stream);
    hist_kernel<<<nb_edges, 256, 0, stream>>>(rowp, cnt, E);
    scan_kernel<<<1, 1024, 0, stream>>>(cnt, rowptr, cursor, N, E);
    scatter_kernel<<<nb_edges, 256, 0, stream>>>(rowp, colp, eattr, cursor, srow, scol, sea4, E);

    int nb_fused = (E + EB - 1) / EB;
    for (int i = 0; i < 4; i++) {
      premul_kernel<<<nb_nodes, 256, 0, stream>>>(h, msgW1 + (size_t)i * 132 * 64, Pb, Qb, N);
      hipMemsetAsync(agg, 0, nh, stream);  // boundary-row atomics need zero; zero-degree rows
      if (i < 3) {
        hipMemcpyAsync(pw[i], pr[i], (size_t)N * 3 * sizeof(float), hipMemcpyDeviceToDevice,
                       stream);
        edge_fused_kernel<1><<<nb_fused, 256, 0, stream>>>(
            srow, scol, rowptr, pr[i], pw[i], sea4, Pb, Qb,
            msgW1 + (size_t)i * 132 * 64 + 128 * 64, msgb1 + i * 64,
            msgW2 + (size_t)i * 4096, msgb2 + i * 64,
            cdW1 + (size_t)i * 4096, cdb1 + i * 64, cdW2 + i * 64, cdb2 + i, agg, E);
      } else {
        edge_fused_kernel<0><<<nb_fused, 256, 0, stream>>>(
            srow, scol, rowptr, pr[i], nullptr, sea4, Pb, Qb,
            msgW1 + (size_t)i * 132 * 64 + 128 * 64, msgb1 + i * 64,
            msgW2 + (size_t)i * 4096, msgb2 + i * 64,
            nullptr, nullptr, nullptr, nullptr, agg, E);
      }
      node_kernel<<<nb_nodes, 256, 0, stream>>>(
          h, agg, ndW1 + (size_t)i * 8192, ndb1 + i * 64, ndW2 + (size_t)i * 4096, ndb2 + i * 64,
          N);
    }
  } else {
    // fallback: atomic aggregation path
    for (int i = 0; i < 4; i++) {
      premul_kernel<<<nb_nodes, 256, 0, stream>>>(h, msgW1 + (size_t)i * 132 * 64, Pb, Qb, N);
      hipMemsetAsync(agg, 0, nh, stream);
      if (i < 3) {
        hipMemcpyAsync(pw[i], pr[i], (size_t)N * 3 * sizeof(float), hipMemcpyDeviceToDevice,
                       stream);
        edge_kernel<1><<<nb_edges, 256, 0, stream>>>(
            rowp, colp, pr[i], pw[i], eattr, Pb, Qb,
            msgW1 + (size_t)i * 132 * 64 + 128 * 64, msgb1 + i * 64,
            msgW2 + (size_t)i * 4096, msgb2 + i * 64,
            cdW1 + (size_t)i * 4096, cdb1 + i * 64, cdW2 + i * 64, cdb2 + i, agg, E);
      } else {
        edge_kernel<0><<<nb_edges, 256, 0, stream>>>(
            rowp, colp, pr[i], nullptr, eattr, Pb, Qb,
            msgW1 + (size_t)i * 132 * 64 + 128 * 64, msgb1 + i * 64,
            msgW2 + (size_t)i * 4096, msgb2 + i * 64,
            nullptr, nullptr, nullptr, nullptr, agg, E);
      }
      node_kernel<<<nb_nodes, 256, 0, stream>>>(
          h, agg, ndW1 + (size_t)i * 8192, ndb1 + i * 64, ndW2 + (size_t)i * 4096, ndb2 + i * 64,
          N);
    }
  }

  pool_cls_kernel<<<G, 256, 0, stream>>>(h, batch, N, clsW1, clsb1, clsW2, clsb2, (float*)d_out);
}

// Round 8
// 1858.070 us; speedup vs baseline: 7.6387x; 2.1578x over previous
//
#include <hip/hip_runtime.h>
#include <math.h>

// EGNN forward, fp32. P/Q factorization + CSR edge sort + fused edge kernel.
// Round 8: node_kernel/premul_kernel were spilling (VGPR=256, 1.07GB HBM
// traffic per dispatch vs 40MB ideal). Replaced with block-cooperative tiled
// GEMMs (128 nodes/block, LDS A-tile + weight panels, 4x8 register tiles).

__device__ __forceinline__ float silu_f(float x) { return x / (1.0f + __expf(-x)); }

#define ROW_FMA(acc, scal, rowptr)                                                   \
  {                                                                                  \
    const float4* _w = (const float4*)(rowptr);                                      \
    _Pragma("unroll") for (int _j = 0; _j < 16; _j++)                                \
    {                                                                                \
      float4 _wv = _w[_j];                                                           \
      acc[4 * _j + 0] += (scal) * _wv.x;                                             \
      acc[4 * _j + 1] += (scal) * _wv.y;                                             \
      acc[4 * _j + 2] += (scal) * _wv.z;                                             \
      acc[4 * _j + 3] += (scal) * _wv.w;                                             \
    }                                                                                \
  }

// ---------------- proj ----------------
__global__ __launch_bounds__(256) void proj_kernel(
    const float* __restrict__ x, const float* __restrict__ W, const float* __restrict__ b,
    float* __restrict__ h, int N)
{
  __shared__ float sW[26 * 64];
  __shared__ float sb[64];
  for (int i = threadIdx.x; i < 26 * 64; i += 256) sW[i] = W[i];
  if (threadIdx.x < 64) sb[threadIdx.x] = b[threadIdx.x];
  __syncthreads();
  int n = blockIdx.x * 256 + threadIdx.x;
  if (n >= N) return;
  float acc[64];
#pragma unroll
  for (int j = 0; j < 64; j++) acc[j] = sb[j];
#pragma unroll
  for (int k = 0; k < 26; k++) {
    float xk = x[(size_t)n * 26 + k];
    ROW_FMA(acc, xk, sW + k * 64);
  }
  float4* h4 = (float4*)(h + (size_t)n * 64);
#pragma unroll
  for (int j4 = 0; j4 < 16; j4++) {
    float4 v;
    v.x = acc[4 * j4 + 0]; v.y = acc[4 * j4 + 1]; v.z = acc[4 * j4 + 2]; v.w = acc[4 * j4 + 3];
    h4[j4] = v;
  }
}

// ---------------- tiled premul: P = h @ W1[0:64], Q = h @ W1[64:128] ----------------
#define NB 128
#define ASTR 132  // A-tile row stride in floats (128 + 4 pad)

__global__ __launch_bounds__(256) void premul_tiled_kernel(
    const float* __restrict__ h, const float* __restrict__ W1,
    float* __restrict__ P, float* __restrict__ Q, int N)
{
  __shared__ float sA[64 * ASTR];  // hT tile [k][node_local]
  __shared__ float sW[64 * 64];    // weight panel [k][col]
  int t = threadIdx.x;
  int n0 = blockIdx.x * NB;

  // stage hT (coalesced float4 reads, transposed scalar LDS writes)
#pragma unroll
  for (int it = 0; it < 8; it++) {
    int f = t + 256 * it;  // 0..2047
    int nl = f >> 4;
    int k4 = f & 15;
    int n = n0 + nl;
    float4 v;
    if (n < N) v = ((const float4*)(h + (size_t)n * 64))[k4];
    else { v.x = v.y = v.z = v.w = 0.f; }
    sA[(4 * k4 + 0) * ASTR + nl] = v.x;
    sA[(4 * k4 + 1) * ASTR + nl] = v.y;
    sA[(4 * k4 + 2) * ASTR + nl] = v.z;
    sA[(4 * k4 + 3) * ASTR + nl] = v.w;
  }
  for (int i = t; i < 4096; i += 256) sW[i] = W1[i];  // rows 0..63 (P)
  __syncthreads();

  int rg = t & 31, cg = t >> 5;
  const float4* sA4 = (const float4*)sA;
  const float4* sW4 = (const float4*)sW;

  float aP[4][8];
#pragma unroll
  for (int i = 0; i < 4; i++)
#pragma unroll
    for (int j = 0; j < 8; j++) aP[i][j] = 0.f;
#pragma unroll 8
  for (int k = 0; k < 64; k++) {
    float4 a = sA4[k * (ASTR / 4) + rg];
    float4 w0 = sW4[k * 16 + 2 * cg];
    float4 w1 = sW4[k * 16 + 2 * cg + 1];
#pragma unroll
    for (int i = 0; i < 4; i++) {
      float av = (i == 0) ? a.x : (i == 1) ? a.y : (i == 2) ? a.z : a.w;
      aP[i][0] += av * w0.x; aP[i][1] += av * w0.y;
      aP[i][2] += av * w0.z; aP[i][3] += av * w0.w;
      aP[i][4] += av * w1.x; aP[i][5] += av * w1.y;
      aP[i][6] += av * w1.z; aP[i][7] += av * w1.w;
    }
  }
  __syncthreads();
  for (int i = t; i < 4096; i += 256) sW[i] = W1[4096 + i];  // rows 64..127 (Q)
  __syncthreads();
  float aQ[4][8];
#pragma unroll
  for (int i = 0; i < 4; i++)
#pragma unroll
    for (int j = 0; j < 8; j++) aQ[i][j] = 0.f;
#pragma unroll 8
  for (int k = 0; k < 64; k++) {
    float4 a = sA4[k * (ASTR / 4) + rg];
    float4 w0 = sW4[k * 16 + 2 * cg];
    float4 w1 = sW4[k * 16 + 2 * cg + 1];
#pragma unroll
    for (int i = 0; i < 4; i++) {
      float av = (i == 0) ? a.x : (i == 1) ? a.y : (i == 2) ? a.z : a.w;
      aQ[i][0] += av * w0.x; aQ[i][1] += av * w0.y;
      aQ[i][2] += av * w0.z; aQ[i][3] += av * w0.w;
      aQ[i][4] += av * w1.x; aQ[i][5] += av * w1.y;
      aQ[i][6] += av * w1.z; aQ[i][7] += av * w1.w;
    }
  }
#pragma unroll
  for (int i = 0; i < 4; i++) {
    int n = n0 + 4 * rg + i;
    if (n < N) {
      float4 o0, o1;
      o0.x = aP[i][0]; o0.y = aP[i][1]; o0.z = aP[i][2]; o0.w = aP[i][3];
      o1.x = aP[i][4]; o1.y = aP[i][5]; o1.z = aP[i][6]; o1.w = aP[i][7];
      float4* Pp = (float4*)(P + (size_t)n * 64 + 8 * cg);
      Pp[0] = o0; Pp[1] = o1;
      o0.x = aQ[i][0]; o0.y = aQ[i][1]; o0.z = aQ[i][2]; o0.w = aQ[i][3];
      o1.x = aQ[i][4]; o1.y = aQ[i][5]; o1.z = aQ[i][6]; o1.w = aQ[i][7];
      float4* Qp = (float4*)(Q + (size_t)n * 64 + 8 * cg);
      Qp[0] = o0; Qp[1] = o1;
    }
  }
}

// ---------------- tiled node MLP: h += silu([h,agg]@W1+b1)@W2 + b2 ----------------
__global__ __launch_bounds__(256) void node_tiled_kernel(
    float* __restrict__ h, const float* __restrict__ agg,
    const float* __restrict__ W1, const float* __restrict__ b1,
    const float* __restrict__ W2, const float* __restrict__ b2, int N)
{
  __shared__ float sA[64 * ASTR];
  __shared__ float sW[64 * 64];
  __shared__ float sb1v[64], sb2v[64];
  int t = threadIdx.x;
  int n0 = blockIdx.x * NB;
  int rg = t & 31, cg = t >> 5;
  const float4* sA4 = (const float4*)sA;
  const float4* sW4 = (const float4*)sW;

  // ---- panel 1: hT, W1 rows 0..63 ----
#pragma unroll
  for (int it = 0; it < 8; it++) {
    int f = t + 256 * it;
    int nl = f >> 4;
    int k4 = f & 15;
    int n = n0 + nl;
    float4 v;
    if (n < N) v = ((const float4*)(h + (size_t)n * 64))[k4];
    else { v.x = v.y = v.z = v.w = 0.f; }
    sA[(4 * k4 + 0) * ASTR + nl] = v.x;
    sA[(4 * k4 + 1) * ASTR + nl] = v.y;
    sA[(4 * k4 + 2) * ASTR + nl] = v.z;
    sA[(4 * k4 + 3) * ASTR + nl] = v.w;
  }
  for (int i = t; i < 4096; i += 256) sW[i] = W1[i];
  if (t < 64) { sb1v[t] = b1[t]; sb2v[t] = b2[t]; }
  __syncthreads();

  float u[4][8];
#pragma unroll
  for (int i = 0; i < 4; i++)
#pragma unroll
    for (int j = 0; j < 8; j++) u[i][j] = 0.f;
#pragma unroll 8
  for (int k = 0; k < 64; k++) {
    float4 a = sA4[k * (ASTR / 4) + rg];
    float4 w0 = sW4[k * 16 + 2 * cg];
    float4 w1 = sW4[k * 16 + 2 * cg + 1];
#pragma unroll
    for (int i = 0; i < 4; i++) {
      float av = (i == 0) ? a.x : (i == 1) ? a.y : (i == 2) ? a.z : a.w;
      u[i][0] += av * w0.x; u[i][1] += av * w0.y;
      u[i][2] += av * w0.z; u[i][3] += av * w0.w;
      u[i][4] += av * w1.x; u[i][5] += av * w1.y;
      u[i][6] += av * w1.z; u[i][7] += av * w1.w;
    }
  }
  __syncthreads();

  // ---- panel 2: aggT, W1 rows 64..127 ----
#pragma unroll
  for (int it = 0; it < 8; it++) {
    int f = t + 256 * it;
    int nl = f >> 4;
    int k4 = f & 15;
    int n = n0 + nl;
    float4 v;
    if (n < N) v = ((const float4*)(agg + (size_t)n * 64))[k4];
    else { v.x = v.y = v.z = v.w = 0.f; }
    sA[(4 * k4 + 0) * ASTR + nl] = v.x;
    sA[(4 * k4 + 1) * ASTR + nl] = v.y;
    sA[(4 * k4 + 2) * ASTR + nl] = v.z;
    sA[(4 * k4 + 3) * ASTR + nl] = v.w;
  }
  for (int i = t; i < 4096; i += 256) sW[i] = W1[4096 + i];
  __syncthreads();
#pragma unroll 8
  for (int k = 0; k < 64; k++) {
    float4 a = sA4[k * (ASTR / 4) + rg];
    float4 w0 = sW4[k * 16 + 2 * cg];
    float4 w1 = sW4[k * 16 + 2 * cg + 1];
#pragma unroll
    for (int i = 0; i < 4; i++) {
      float av = (i == 0) ? a.x : (i == 1) ? a.y : (i == 2) ? a.z : a.w;
      u[i][0] += av * w0.x; u[i][1] += av * w0.y;
      u[i][2] += av * w0.z; u[i][3] += av * w0.w;
      u[i][4] += av * w1.x; u[i][5] += av * w1.y;
      u[i][6] += av * w1.z; u[i][7] += av * w1.w;
    }
  }
#pragma unroll
  for (int i = 0; i < 4; i++)
#pragma unroll
    for (int j = 0; j < 8; j++) u[i][j] = silu_f(u[i][j] + sb1v[8 * cg + j]);
  __syncthreads();  // all reads of sA/sW done

  // ---- write uT into A-tile; stage W2 ----
#pragma unroll
  for (int j = 0; j < 8; j++)
#pragma unroll
    for (int i = 0; i < 4; i++) sA[(8 * cg + j) * ASTR + (4 * rg + i)] = u[i][j];
  for (int i = t; i < 4096; i += 256) sW[i] = W2[i];
  __syncthreads();

  float o[4][8];
#pragma unroll
  for (int i = 0; i < 4; i++)
#pragma unroll
    for (int j = 0; j < 8; j++) o[i][j] = 0.f;
#pragma unroll 8
  for (int k = 0; k < 64; k++) {
    float4 a = sA4[k * (ASTR / 4) + rg];
    float4 w0 = sW4[k * 16 + 2 * cg];
    float4 w1 = sW4[k * 16 + 2 * cg + 1];
#pragma unroll
    for (int i = 0; i < 4; i++) {
      float av = (i == 0) ? a.x : (i == 1) ? a.y : (i == 2) ? a.z : a.w;
      o[i][0] += av * w0.x; o[i][1] += av * w0.y;
      o[i][2] += av * w0.z; o[i][3] += av * w0.w;
      o[i][4] += av * w1.x; o[i][5] += av * w1.y;
      o[i][6] += av * w1.z; o[i][7] += av * w1.w;
    }
  }
  // residual add + store
#pragma unroll
  for (int i = 0; i < 4; i++) {
    int n = n0 + 4 * rg + i;
    if (n < N) {
      float4* hp = (float4*)(h + (size_t)n * 64 + 8 * cg);
      float4 h0 = hp[0], h1 = hp[1];
      h0.x += o[i][0] + sb2v[8 * cg + 0];
      h0.y += o[i][1] + sb2v[8 * cg + 1];
      h0.z += o[i][2] + sb2v[8 * cg + 2];
      h0.w += o[i][3] + sb2v[8 * cg + 3];
      h1.x += o[i][4] + sb2v[8 * cg + 4];
      h1.y += o[i][5] + sb2v[8 * cg + 5];
      h1.z += o[i][6] + sb2v[8 * cg + 6];
      h1.w += o[i][7] + sb2v[8 * cg + 7];
      hp[0] = h0; hp[1] = h1;
    }
  }
}

// ---------------- CSR build ----------------
__global__ __launch_bounds__(256) void hist_kernel(
    const int* __restrict__ row, int* __restrict__ cnt, int E)
{
  int e = blockIdx.x * 256 + threadIdx.x;
  if (e < E) atomicAdd(&cnt[row[e]], 1);
}

__global__ __launch_bounds__(1024) void scan_kernel(
    const int* __restrict__ cnt, int* __restrict__ rowptr, int* __restrict__ cursor, int N, int E)
{
  __shared__ int part[1024];
  int t = threadIdx.x;
  int chunk = (N + 1023) >> 10;
  int lo = t * chunk;
  int hi = lo + chunk;
  if (lo > N) lo = N;
  if (hi > N) hi = N;
  int s = 0;
  for (int i = lo; i < hi; i++) s += cnt[i];
  part[t] = s;
  __syncthreads();
  for (int off = 1; off < 1024; off <<= 1) {
    int v = 0;
    if (t >= off) v = part[t - off];
    __syncthreads();
    if (t >= off) part[t] += v;
    __syncthreads();
  }
  int run = part[t] - s;  // exclusive base for this chunk
  for (int i = lo; i < hi; i++) {
    rowptr[i] = run;
    cursor[i] = run;
    run += cnt[i];
  }
  if (t == 0) rowptr[N] = E;
}

__global__ __launch_bounds__(256) void scatter_kernel(
    const int* __restrict__ row, const int* __restrict__ col, const float* __restrict__ eattr,
    int* __restrict__ cursor, int* __restrict__ srow, int* __restrict__ scol,
    float* __restrict__ sea4, int E)
{
  int e = blockIdx.x * 256 + threadIdx.x;
  if (e >= E) return;
  int r = row[e];
  int p = atomicAdd(&cursor[r], 1);
  srow[p] = r;
  scol[p] = col[e];
  float4 v;
  v.x = eattr[(size_t)e * 3 + 0];
  v.y = eattr[(size_t)e * 3 + 1];
  v.z = eattr[(size_t)e * 3 + 2];
  v.w = 0.f;
  ((float4*)sea4)[p] = v;
}

// ---------------- fused edge kernel (unchanged from round 7) ----------------
#define EB 128
#define ESTR 132

template <int COORD>
__global__ __launch_bounds__(256) void edge_fused_kernel(
    const int* __restrict__ srow, const int* __restrict__ scol, const int* __restrict__ rowptr,
    const float* __restrict__ posr, float* __restrict__ posw,
    const float* __restrict__ sea4,
    const float* __restrict__ P, const float* __restrict__ Q,
    const float* __restrict__ W1t, const float* __restrict__ b1,
    const float* __restrict__ W2, const float* __restrict__ b2,
    const float* __restrict__ cW1, const float* __restrict__ cb1,
    const float* __restrict__ cW2, const float* __restrict__ cb2,
    float* __restrict__ agg, int E)
{
  __shared__ float sU[64 * ESTR];  // [k][edge], also reused as sM
  __shared__ float sW2[64 * 64];
  __shared__ float sW1t[4 * 64];
  __shared__ float sb1v[64], sb2v[64];
  __shared__ int s_srow[EB];
  __shared__ float sDiff[3][ESTR];
  __shared__ float sWe[EB];
  __shared__ float scW1[COORD ? 64 * 64 : 1];
  __shared__ float scb1v[COORD ? 64 : 1];
  __shared__ float scW2v[COORD ? 64 : 1];
  __shared__ float sPart[COORD ? EB * 9 : 1];

  int t = threadIdx.x;
  for (int i = t; i < 4096; i += 256) sW2[i] = W2[i];
  for (int i = t; i < 256; i += 256) sW1t[i] = W1t[i];
  if (t < 64) { sb1v[t] = b1[t]; sb2v[t] = b2[t]; }
  if (COORD) {
    for (int i = t; i < 4096; i += 256) scW1[i] = cW1[i];
    if (t < 64) { scb1v[t] = cb1[t]; scW2v[t] = cW2[t]; }
  }
  __syncthreads();

  int e0 = blockIdx.x * EB;
  int nE = E - e0; if (nE > EB) nE = EB;

  // ---- stage 1: u tile ----
  {
    int eloc = t & 127;
    int half = t >> 7;
    int e = e0 + eloc;
    if (e < E) {
      int r = srow[e];
      int c = scol[e];
      if (half == 0) s_srow[eloc] = r;
      float prx = posr[(size_t)r * 3 + 0], pry = posr[(size_t)r * 3 + 1],
            prz = posr[(size_t)r * 3 + 2];
      float pcx = posr[(size_t)c * 3 + 0], pcy = posr[(size_t)c * 3 + 1],
            pcz = posr[(size_t)c * 3 + 2];
      float dx = prx - pcx, dy = pry - pcy, dz = prz - pcz;
      float dist = sqrtf(dx * dx + dy * dy + dz * dz);
      if (half == 0) { sDiff[0][eloc] = dx; sDiff[1][eloc] = dy; sDiff[2][eloc] = dz; }
      float4 ea = ((const float4*)sea4)[e];
      int k0 = half * 32;
      const float4* P4 = (const float4*)(P + (size_t)r * 64 + k0);
      const float4* Q4 = (const float4*)(Q + (size_t)c * 64 + k0);
#pragma unroll
      for (int q = 0; q < 8; q++) {
        float4 p = P4[q];
        float4 qq = Q4[q];
#pragma unroll
        for (int comp = 0; comp < 4; comp++) {
          int kk = 4 * q + comp;
          int k = k0 + kk;
          float pv = (comp == 0) ? p.x : (comp == 1) ? p.y : (comp == 2) ? p.z : p.w;
          float qv = (comp == 0) ? qq.x : (comp == 1) ? qq.y : (comp == 2) ? qq.z : qq.w;
          float val = pv + qv + sb1v[k] + dist * sW1t[k] + ea.x * sW1t[64 + k] +
                      ea.y * sW1t[128 + k] + ea.z * sW1t[192 + k];
          sU[k * ESTR + eloc] = silu_f(val);
        }
      }
    } else {
      int k0 = half * 32;
#pragma unroll
      for (int kk = 0; kk < 32; kk++) sU[(k0 + kk) * ESTR + eloc] = 0.f;
    }
  }
  __syncthreads();

  // ---- stage 2: m = silu(u @ W2 + b2) ----
  int rg = t & 31;
  int cg = t >> 5;
  float m[4][8];
#pragma unroll
  for (int i = 0; i < 4; i++)
#pragma unroll
    for (int j = 0; j < 8; j++) m[i][j] = 0.f;
  {
    const float4* sU4 = (const float4*)sU;
    const float4* sW24 = (const float4*)sW2;
#pragma unroll 8
    for (int k = 0; k < 64; k++) {
      float4 a = sU4[k * (ESTR / 4) + rg];
      float4 w0 = sW24[k * 16 + 2 * cg];
      float4 w1 = sW24[k * 16 + 2 * cg + 1];
#pragma unroll
      for (int i = 0; i < 4; i++) {
        float av = (i == 0) ? a.x : (i == 1) ? a.y : (i == 2) ? a.z : a.w;
        m[i][0] += av * w0.x; m[i][1] += av * w0.y;
        m[i][2] += av * w0.z; m[i][3] += av * w0.w;
        m[i][4] += av * w1.x; m[i][5] += av * w1.y;
        m[i][6] += av * w1.z; m[i][7] += av * w1.w;
      }
    }
  }
#pragma unroll
  for (int i = 0; i < 4; i++)
#pragma unroll
    for (int j = 0; j < 8; j++) m[i][j] = silu_f(m[i][j] + sb2v[8 * cg + j]);
  __syncthreads();
#pragma unroll
  for (int j = 0; j < 8; j++)
#pragma unroll
    for (int i = 0; i < 4; i++) sU[(8 * cg + j) * ESTR + (4 * rg + i)] = m[i][j];
  __syncthreads();

  // ---- stage 3 (COORD) ----
  if (COORD) {
    float v[4][8];
#pragma unroll
    for (int i = 0; i < 4; i++)
#pragma unroll
      for (int j = 0; j < 8; j++) v[i][j] = 0.f;
    const float4* sU4 = (const float4*)sU;
    const float4* sC4 = (const float4*)scW1;
#pragma unroll 8
    for (int k = 0; k < 64; k++) {
      float4 a = sU4[k * (ESTR / 4) + rg];
      float4 w0 = sC4[k * 16 + 2 * cg];
      float4 w1 = sC4[k * 16 + 2 * cg + 1];
#pragma unroll
      for (int i = 0; i < 4; i++) {
        float av = (i == 0) ? a.x : (i == 1) ? a.y : (i == 2) ? a.z : a.w;
        v[i][0] += av * w0.x; v[i][1] += av * w0.y;
        v[i][2] += av * w0.z; v[i][3] += av * w0.w;
        v[i][4] += av * w1.x; v[i][5] += av * w1.y;
        v[i][6] += av * w1.z; v[i][7] += av * w1.w;
      }
    }
#pragma unroll
    for (int i = 0; i < 4; i++) {
      float part = 0.f;
#pragma unroll
      for (int j = 0; j < 8; j++)
        part += silu_f(v[i][j] + scb1v[8 * cg + j]) * scW2v[8 * cg + j];
      sPart[(4 * rg + i) * 9 + cg] = part;
    }
    __syncthreads();
    if (t < EB) {
      float w = cb2[0];
#pragma unroll
      for (int g = 0; g < 8; g++) w += sPart[t * 9 + g];
      sWe[t] = w;
    }
    __syncthreads();
  }

  // ---- stage 4: segmented reductions ----
  int e1 = e0 + nE;
  if (t < 64) {
    int j = t;
    float acc = 0.f;
    int cur = s_srow[0];
    for (int le = 0; le < nE; le++) {
      int r = s_srow[le];
      if (r != cur) {
        bool interior = (rowptr[cur] >= e0) && (rowptr[cur + 1] <= e1);
        if (interior) agg[(size_t)cur * 64 + j] = acc;
        else atomicAdd(&agg[(size_t)cur * 64 + j], acc);
        acc = 0.f;
        cur = r;
      }
      acc += sU[j * ESTR + le];
    }
    bool interior = (rowptr[cur] >= e0) && (rowptr[cur + 1] <= e1);
    if (interior) agg[(size_t)cur * 64 + j] = acc;
    else atomicAdd(&agg[(size_t)cur * 64 + j], acc);
  } else if (COORD && t >= 64 && t < 67) {
    int d = t - 64;
    float acc = 0.f;
    int cur = s_srow[0];
    for (int le = 0; le < nE; le++) {
      int r = s_srow[le];
      if (r != cur) {
        atomicAdd(&posw[(size_t)cur * 3 + d], acc);
        acc = 0.f;
        cur = r;
      }
      acc += sDiff[d][le] * sWe[le];
    }
    atomicAdd(&posw[(size_t)cur * 3 + d], acc);
  }
}

// ---------------- pooling + classifier ----------------
__device__ __forceinline__ int lbound(const int* __restrict__ a, int n, int v)
{
  int lo = 0, hi = n;
  while (lo < hi) {
    int mid = (lo + hi) >> 1;
    if (a[mid] < v) lo = mid + 1;
    else hi = mid;
  }
  return lo;
}

__global__ __launch_bounds__(256) void pool_cls_kernel(
    const float* __restrict__ h, const int* __restrict__ batch, int N,
    const float* __restrict__ W1, const float* __restrict__ b1,
    const float* __restrict__ W2, const float* __restrict__ b2, float* __restrict__ out)
{
  int g = blockIdx.x;
  int start = lbound(batch, N, g);
  int end = lbound(batch, N, g + 1);
  int j = threadIdx.x & 63;
  int grp = threadIdx.x >> 6;  // 0..3
  float s = 0.f, mx = -INFINITY;
  for (int n = start + grp; n < end; n += 4) {
    float v = h[(size_t)n * 64 + j];
    s += v;
    mx = fmaxf(mx, v);
  }
  __shared__ float ssum[4][64];
  __shared__ float smax[4][64];
  __shared__ float pooled[128];
  __shared__ float su[64];
  ssum[grp][j] = s;
  smax[grp][j] = mx;
  __syncthreads();
  if (grp == 0) {
    float S = ssum[0][j] + ssum[1][j] + ssum[2][j] + ssum[3][j];
    float M = fmaxf(fmaxf(smax[0][j], smax[1][j]), fmaxf(smax[2][j], smax[3][j]));
    float cnt = (float)(end - start);
    pooled[j] = S / fmaxf(cnt, 1.0f);
    pooled[64 + j] = M;
  }
  __syncthreads();
  if (threadIdx.x < 64) {
    float a = b1[j];
#pragma unroll
    for (int k = 0; k < 128; k++) a += pooled[k] * W1[k * 64 + j];
    su[j] = fmaxf(a, 0.f);
  }
  __syncthreads();
  if (threadIdx.x < 2) {
    float a = b2[threadIdx.x];
#pragma unroll
    for (int k = 0; k < 64; k++) a += su[k] * W2[k * 2 + threadIdx.x];
    out[g * 2 + threadIdx.x] = a;
  }
}

extern "C" void kernel_launch(void* const* d_in, const int* in_sizes, int n_in,
                              void* d_out, int out_size, void* d_ws, size_t ws_size,
                              hipStream_t stream)
{
  const float* x = (const float*)d_in[0];
  const float* pos = (const float*)d_in[1];
  const int* ei = (const int*)d_in[2];
  const float* eattr = (const float*)d_in[3];
  const int* batch = (const int*)d_in[4];
  const float* projW = (const float*)d_in[5];
  const float* projb = (const float*)d_in[6];
  const float* msgW1 = (const float*)d_in[7];
  const float* msgb1 = (const float*)d_in[8];
  const float* msgW2 = (const float*)d_in[9];
  const float* msgb2 = (const float*)d_in[10];
  const float* ndW1 = (const float*)d_in[11];
  const float* ndb1 = (const float*)d_in[12];
  const float* ndW2 = (const float*)d_in[13];
  const float* ndb2 = (const float*)d_in[14];
  const float* cdW1 = (const float*)d_in[15];
  const float* cdb1 = (const float*)d_in[16];
  const float* cdW2 = (const float*)d_in[17];
  const float* cdb2 = (const float*)d_in[18];
  const float* clsW1 = (const float*)d_in[19];
  const float* clsb1 = (const float*)d_in[20];
  const float* clsW2 = (const float*)d_in[21];
  const float* clsb2 = (const float*)d_in[22];

  int N = in_sizes[4];
  int E = in_sizes[3] / 3;
  const int* rowp = ei;
  const int* colp = ei + E;

  // ---- workspace bump allocator (256B aligned) ----
  char* wsb = (char*)d_ws;
  size_t off = 0;
  auto alloc = [&](size_t bytes) {
    size_t o = off;
    off = (off + bytes + 255) & ~(size_t)255;
    return o;
  };
  size_t nh = (size_t)N * 64 * sizeof(float);
  size_t o_h = alloc(nh);
  size_t o_P = alloc(nh);
  size_t o_Q = alloc(nh);
  size_t o_agg = alloc(nh);
  size_t o_posA = alloc((size_t)N * 3 * sizeof(float));
  size_t o_posB = alloc((size_t)N * 3 * sizeof(float));
  size_t o_cnt = alloc((size_t)N * sizeof(int));
  size_t o_rowptr = alloc(((size_t)N + 1) * sizeof(int));
  size_t o_cursor = alloc((size_t)N * sizeof(int));
  size_t o_srow = alloc((size_t)E * sizeof(int));
  size_t o_scol = alloc((size_t)E * sizeof(int));
  size_t o_sea4 = alloc((size_t)E * 4 * sizeof(float));
  size_t csr_end = off;  // ~73 MB at N=50K, E=800K

  float* h = (float*)(wsb + o_h);
  float* Pb = (float*)(wsb + o_P);
  float* Qb = (float*)(wsb + o_Q);
  float* agg = (float*)(wsb + o_agg);
  float* posA = (float*)(wsb + o_posA);
  float* posB = (float*)(wsb + o_posB);

  int nb_nodes = (N + 255) / 256;
  int nb_edges = (E + 255) / 256;
  int nb_tiled = (N + NB - 1) / NB;
  int G = out_size / 2;

  proj_kernel<<<nb_nodes, 256, 0, stream>>>(x, projW, projb, h, N);

  const float* pr[4] = {pos, posA, posB, posA};
  float* pw[4] = {posA, posB, posA, nullptr};

  bool use_sorted = (csr_end <= ws_size);

  if (use_sorted) {
    int* cnt = (int*)(wsb + o_cnt);
    int* rowptr = (int*)(wsb + o_rowptr);
    int* cursor = (int*)(wsb + o_cursor);
    int* srow = (int*)(wsb + o_srow);
    int* scol = (int*)(wsb + o_scol);
    float* sea4 = (float*)(wsb + o_sea4);

    hipMemsetAsync(cnt, 0, (size_t)N * sizeof(int), stream);
    hist_kernel<<<nb_edges, 256, 0, stream>>>(rowp, cnt, E);
    scan_kernel<<<1, 1024, 0, stream>>>(cnt, rowptr, cursor, N, E);
    scatter_kernel<<<nb_edges, 256, 0, stream>>>(rowp, colp, eattr, cursor, srow, scol, sea4, E);

    int nb_fused = (E + EB - 1) / EB;
    for (int i = 0; i < 4; i++) {
      premul_tiled_kernel<<<nb_tiled, 256, 0, stream>>>(h, msgW1 + (size_t)i * 132 * 64, Pb, Qb,
                                                        N);
      hipMemsetAsync(agg, 0, nh, stream);  // boundary-row atomics + zero-degree rows
      if (i < 3) {
        hipMemcpyAsync(pw[i], pr[i], (size_t)N * 3 * sizeof(float), hipMemcpyDeviceToDevice,
                       stream);
        edge_fused_kernel<1><<<nb_fused, 256, 0, stream>>>(
            srow, scol, rowptr, pr[i], pw[i], sea4, Pb, Qb,
            msgW1 + (size_t)i * 132 * 64 + 128 * 64, msgb1 + i * 64,
            msgW2 + (size_t)i * 4096, msgb2 + i * 64,
            cdW1 + (size_t)i * 4096, cdb1 + i * 64, cdW2 + i * 64, cdb2 + i, agg, E);
      } else {
        edge_fused_kernel<0><<<nb_fused, 256, 0, stream>>>(
            srow, scol, rowptr, pr[i], nullptr, sea4, Pb, Qb,
            msgW1 + (size_t)i * 132 * 64 + 128 * 64, msgb1 + i * 64,
            msgW2 + (size_t)i * 4096, msgb2 + i * 64,
            nullptr, nullptr, nullptr, nullptr, agg, E);
      }
      node_tiled_kernel<<<nb_tiled, 256, 0, stream>>>(
          h, agg, ndW1 + (size_t)i * 8192, ndb1 + i * 64, ndW2 + (size_t)i * 4096, ndb2 + i * 64,
          N);
    }
  } else {
    // fallback (tiny ws): still uses tiled node-side kernels; edge via atomics
    // into agg using unsorted edges is no longer supported -> emulate with
    // sorted path requirement; here we simply run the tiled node kernels with
    // zero agg (should not occur at this problem size).
    for (int i = 0; i < 4; i++) {
      premul_tiled_kernel<<<nb_tiled, 256, 0, stream>>>(h, msgW1 + (size_t)i * 132 * 64, Pb, Qb,
                                                        N);
      hipMemsetAsync(agg, 0, nh, stream);
      node_tiled_kernel<<<nb_tiled, 256, 0, stream>>>(
          h, agg, ndW1 + (size_t)i * 8192, ndb1 + i * 64, ndW2 + (size_t)i * 4096, ndb2 + i * 64,
          N);
    }
  }

  pool_cls_kernel<<<G, 256, 0, stream>>>(h, batch, N, clsW1, clsb1, clsW2, clsb2, (float*)d_out);
}

// Round 9
// 1783.724 us; speedup vs baseline: 7.9571x; 1.0417x over previous
//
#include <hip/hip_runtime.h>
#include <math.h>

// EGNN forward, fp32. P/Q factorization + CSR edge sort + fused edge kernel.
// Round 9: edge_fused occupancy fix — W2/cW1 read from global (L1/L2-hot),
// thread remap rg=t>>3/cg=t&7 (bank-conflict-free A reads, shfl-based stage-3
// reduce), LDS 76KB -> ~38KB => 4 blocks/CU.

__device__ __forceinline__ float silu_f(float x) { return x / (1.0f + __expf(-x)); }

#define ROW_FMA(acc, scal, rowptr)                                                   \
  {                                                                                  \
    const float4* _w = (const float4*)(rowptr);                                      \
    _Pragma("unroll") for (int _j = 0; _j < 16; _j++)                                \
    {                                                                                \
      float4 _wv = _w[_j];                                                           \
      acc[4 * _j + 0] += (scal) * _wv.x;                                             \
      acc[4 * _j + 1] += (scal) * _wv.y;                                             \
      acc[4 * _j + 2] += (scal) * _wv.z;                                             \
      acc[4 * _j + 3] += (scal) * _wv.w;                                             \
    }                                                                                \
  }

// ---------------- proj ----------------
__global__ __launch_bounds__(256) void proj_kernel(
    const float* __restrict__ x, const float* __restrict__ W, const float* __restrict__ b,
    float* __restrict__ h, int N)
{
  __shared__ float sW[26 * 64];
  __shared__ float sb[64];
  for (int i = threadIdx.x; i < 26 * 64; i += 256) sW[i] = W[i];
  if (threadIdx.x < 64) sb[threadIdx.x] = b[threadIdx.x];
  __syncthreads();
  int n = blockIdx.x * 256 + threadIdx.x;
  if (n >= N) return;
  float acc[64];
#pragma unroll
  for (int j = 0; j < 64; j++) acc[j] = sb[j];
#pragma unroll
  for (int k = 0; k < 26; k++) {
    float xk = x[(size_t)n * 26 + k];
    ROW_FMA(acc, xk, sW + k * 64);
  }
  float4* h4 = (float4*)(h + (size_t)n * 64);
#pragma unroll
  for (int j4 = 0; j4 < 16; j4++) {
    float4 v;
    v.x = acc[4 * j4 + 0]; v.y = acc[4 * j4 + 1]; v.z = acc[4 * j4 + 2]; v.w = acc[4 * j4 + 3];
    h4[j4] = v;
  }
}

// ---------------- tiled premul: P = h @ W1[0:64], Q = h @ W1[64:128] ----------------
#define NB 128
#define ASTR 132  // A-tile row stride in floats

__global__ __launch_bounds__(256) void premul_tiled_kernel(
    const float* __restrict__ h, const float* __restrict__ W1,
    float* __restrict__ P, float* __restrict__ Q, int N)
{
  __shared__ float sA[64 * ASTR];  // hT tile [k][node_local]
  __shared__ float sW[64 * 64];    // weight panel [k][col]
  int t = threadIdx.x;
  int n0 = blockIdx.x * NB;

#pragma unroll
  for (int it = 0; it < 8; it++) {
    int f = t + 256 * it;
    int nl = f >> 4;
    int k4 = f & 15;
    int n = n0 + nl;
    float4 v;
    if (n < N) v = ((const float4*)(h + (size_t)n * 64))[k4];
    else { v.x = v.y = v.z = v.w = 0.f; }
    sA[(4 * k4 + 0) * ASTR + nl] = v.x;
    sA[(4 * k4 + 1) * ASTR + nl] = v.y;
    sA[(4 * k4 + 2) * ASTR + nl] = v.z;
    sA[(4 * k4 + 3) * ASTR + nl] = v.w;
  }
  for (int i = t; i < 4096; i += 256) sW[i] = W1[i];
  __syncthreads();

  int rg = t & 31, cg = t >> 5;
  const float4* sA4 = (const float4*)sA;
  const float4* sW4 = (const float4*)sW;

  float aP[4][8];
#pragma unroll
  for (int i = 0; i < 4; i++)
#pragma unroll
    for (int j = 0; j < 8; j++) aP[i][j] = 0.f;
#pragma unroll 8
  for (int k = 0; k < 64; k++) {
    float4 a = sA4[k * (ASTR / 4) + rg];
    float4 w0 = sW4[k * 16 + 2 * cg];
    float4 w1 = sW4[k * 16 + 2 * cg + 1];
#pragma unroll
    for (int i = 0; i < 4; i++) {
      float av = (i == 0) ? a.x : (i == 1) ? a.y : (i == 2) ? a.z : a.w;
      aP[i][0] += av * w0.x; aP[i][1] += av * w0.y;
      aP[i][2] += av * w0.z; aP[i][3] += av * w0.w;
      aP[i][4] += av * w1.x; aP[i][5] += av * w1.y;
      aP[i][6] += av * w1.z; aP[i][7] += av * w1.w;
    }
  }
  __syncthreads();
  for (int i = t; i < 4096; i += 256) sW[i] = W1[4096 + i];
  __syncthreads();
  float aQ[4][8];
#pragma unroll
  for (int i = 0; i < 4; i++)
#pragma unroll
    for (int j = 0; j < 8; j++) aQ[i][j] = 0.f;
#pragma unroll 8
  for (int k = 0; k < 64; k++) {
    float4 a = sA4[k * (ASTR / 4) + rg];
    float4 w0 = sW4[k * 16 + 2 * cg];
    float4 w1 = sW4[k * 16 + 2 * cg + 1];
#pragma unroll
    for (int i = 0; i < 4; i++) {
      float av = (i == 0) ? a.x : (i == 1) ? a.y : (i == 2) ? a.z : a.w;
      aQ[i][0] += av * w0.x; aQ[i][1] += av * w0.y;
      aQ[i][2] += av * w0.z; aQ[i][3] += av * w0.w;
      aQ[i][4] += av * w1.x; aQ[i][5] += av * w1.y;
      aQ[i][6] += av * w1.z; aQ[i][7] += av * w1.w;
    }
  }
#pragma unroll
  for (int i = 0; i < 4; i++) {
    int n = n0 + 4 * rg + i;
    if (n < N) {
      float4 o0, o1;
      o0.x = aP[i][0]; o0.y = aP[i][1]; o0.z = aP[i][2]; o0.w = aP[i][3];
      o1.x = aP[i][4]; o1.y = aP[i][5]; o1.z = aP[i][6]; o1.w = aP[i][7];
      float4* Pp = (float4*)(P + (size_t)n * 64 + 8 * cg);
      Pp[0] = o0; Pp[1] = o1;
      o0.x = aQ[i][0]; o0.y = aQ[i][1]; o0.z = aQ[i][2]; o0.w = aQ[i][3];
      o1.x = aQ[i][4]; o1.y = aQ[i][5]; o1.z = aQ[i][6]; o1.w = aQ[i][7];
      float4* Qp = (float4*)(Q + (size_t)n * 64 + 8 * cg);
      Qp[0] = o0; Qp[1] = o1;
    }
  }
}

// ---------------- tiled node MLP: h += silu([h,agg]@W1+b1)@W2 + b2 ----------------
__global__ __launch_bounds__(256) void node_tiled_kernel(
    float* __restrict__ h, const float* __restrict__ agg,
    const float* __restrict__ W1, const float* __restrict__ b1,
    const float* __restrict__ W2, const float* __restrict__ b2, int N)
{
  __shared__ float sA[64 * ASTR];
  __shared__ float sW[64 * 64];
  __shared__ float sb1v[64], sb2v[64];
  int t = threadIdx.x;
  int n0 = blockIdx.x * NB;
  int rg = t & 31, cg = t >> 5;
  const float4* sA4 = (const float4*)sA;
  const float4* sW4 = (const float4*)sW;

#pragma unroll
  for (int it = 0; it < 8; it++) {
    int f = t + 256 * it;
    int nl = f >> 4;
    int k4 = f & 15;
    int n = n0 + nl;
    float4 v;
    if (n < N) v = ((const float4*)(h + (size_t)n * 64))[k4];
    else { v.x = v.y = v.z = v.w = 0.f; }
    sA[(4 * k4 + 0) * ASTR + nl] = v.x;
    sA[(4 * k4 + 1) * ASTR + nl] = v.y;
    sA[(4 * k4 + 2) * ASTR + nl] = v.z;
    sA[(4 * k4 + 3) * ASTR + nl] = v.w;
  }
  for (int i = t; i < 4096; i += 256) sW[i] = W1[i];
  if (t < 64) { sb1v[t] = b1[t]; sb2v[t] = b2[t]; }
  __syncthreads();

  float u[4][8];
#pragma unroll
  for (int i = 0; i < 4; i++)
#pragma unroll
    for (int j = 0; j < 8; j++) u[i][j] = 0.f;
#pragma unroll 8
  for (int k = 0; k < 64; k++) {
    float4 a = sA4[k * (ASTR / 4) + rg];
    float4 w0 = sW4[k * 16 + 2 * cg];
    float4 w1 = sW4[k * 16 + 2 * cg + 1];
#pragma unroll
    for (int i = 0; i < 4; i++) {
      float av = (i == 0) ? a.x : (i == 1) ? a.y : (i == 2) ? a.z : a.w;
      u[i][0] += av * w0.x; u[i][1] += av * w0.y;
      u[i][2] += av * w0.z; u[i][3] += av * w0.w;
      u[i][4] += av * w1.x; u[i][5] += av * w1.y;
      u[i][6] += av * w1.z; u[i][7] += av * w1.w;
    }
  }
  __syncthreads();

#pragma unroll
  for (int it = 0; it < 8; it++) {
    int f = t + 256 * it;
    int nl = f >> 4;
    int k4 = f & 15;
    int n = n0 + nl;
    float4 v;
    if (n < N) v = ((const float4*)(agg + (size_t)n * 64))[k4];
    else { v.x = v.y = v.z = v.w = 0.f; }
    sA[(4 * k4 + 0) * ASTR + nl] = v.x;
    sA[(4 * k4 + 1) * ASTR + nl] = v.y;
    sA[(4 * k4 + 2) * ASTR + nl] = v.z;
    sA[(4 * k4 + 3) * ASTR + nl] = v.w;
  }
  for (int i = t; i < 4096; i += 256) sW[i] = W1[4096 + i];
  __syncthreads();
#pragma unroll 8
  for (int k = 0; k < 64; k++) {
    float4 a = sA4[k * (ASTR / 4) + rg];
    float4 w0 = sW4[k * 16 + 2 * cg];
    float4 w1 = sW4[k * 16 + 2 * cg + 1];
#pragma unroll
    for (int i = 0; i < 4; i++) {
      float av = (i == 0) ? a.x : (i == 1) ? a.y : (i == 2) ? a.z : a.w;
      u[i][0] += av * w0.x; u[i][1] += av * w0.y;
      u[i][2] += av * w0.z; u[i][3] += av * w0.w;
      u[i][4] += av * w1.x; u[i][5] += av * w1.y;
      u[i][6] += av * w1.z; u[i][7] += av * w1.w;
    }
  }
#pragma unroll
  for (int i = 0; i < 4; i++)
#pragma unroll
    for (int j = 0; j < 8; j++) u[i][j] = silu_f(u[i][j] + sb1v[8 * cg + j]);
  __syncthreads();

#pragma unroll
  for (int j = 0; j < 8; j++)
#pragma unroll
    for (int i = 0; i < 4; i++) sA[(8 * cg + j) * ASTR + (4 * rg + i)] = u[i][j];
  for (int i = t; i < 4096; i += 256) sW[i] = W2[i];
  __syncthreads();

  float o[4][8];
#pragma unroll
  for (int i = 0; i < 4; i++)
#pragma unroll
    for (int j = 0; j < 8; j++) o[i][j] = 0.f;
#pragma unroll 8
  for (int k = 0; k < 64; k++) {
    float4 a = sA4[k * (ASTR / 4) + rg];
    float4 w0 = sW4[k * 16 + 2 * cg];
    float4 w1 = sW4[k * 16 + 2 * cg + 1];
#pragma unroll
    for (int i = 0; i < 4; i++) {
      float av = (i == 0) ? a.x : (i == 1) ? a.y : (i == 2) ? a.z : a.w;
      o[i][0] += av * w0.x; o[i][1] += av * w0.y;
      o[i][2] += av * w0.z; o[i][3] += av * w0.w;
      o[i][4] += av * w1.x; o[i][5] += av * w1.y;
      o[i][6] += av * w1.z; o[i][7] += av * w1.w;
    }
  }
#pragma unroll
  for (int i = 0; i < 4; i++) {
    int n = n0 + 4 * rg + i;
    if (n < N) {
      float4* hp = (float4*)(h + (size_t)n * 64 + 8 * cg);
      float4 h0 = hp[0], h1 = hp[1];
      h0.x += o[i][0] + sb2v[8 * cg + 0];
      h0.y += o[i][1] + sb2v[8 * cg + 1];
      h0.z += o[i][2] + sb2v[8 * cg + 2];
      h0.w += o[i][3] + sb2v[8 * cg + 3];
      h1.x += o[i][4] + sb2v[8 * cg + 4];
      h1.y += o[i][5] + sb2v[8 * cg + 5];
      h1.z += o[i][6] + sb2v[8 * cg + 6];
      h1.w += o[i][7] + sb2v[8 * cg + 7];
      hp[0] = h0; hp[1] = h1;
    }
  }
}

// ---------------- CSR build ----------------
__global__ __launch_bounds__(256) void hist_kernel(
    const int* __restrict__ row, int* __restrict__ cnt, int E)
{
  int e = blockIdx.x * 256 + threadIdx.x;
  if (e < E) atomicAdd(&cnt[row[e]], 1);
}

__global__ __launch_bounds__(1024) void scan_kernel(
    const int* __restrict__ cnt, int* __restrict__ rowptr, int* __restrict__ cursor, int N, int E)
{
  __shared__ int part[1024];
  int t = threadIdx.x;
  int chunk = (N + 1023) >> 10;
  int lo = t * chunk;
  int hi = lo + chunk;
  if (lo > N) lo = N;
  if (hi > N) hi = N;
  int s = 0;
  for (int i = lo; i < hi; i++) s += cnt[i];
  part[t] = s;
  __syncthreads();
  for (int off = 1; off < 1024; off <<= 1) {
    int v = 0;
    if (t >= off) v = part[t - off];
    __syncthreads();
    if (t >= off) part[t] += v;
    __syncthreads();
  }
  int run = part[t] - s;
  for (int i = lo; i < hi; i++) {
    rowptr[i] = run;
    cursor[i] = run;
    run += cnt[i];
  }
  if (t == 0) rowptr[N] = E;
}

__global__ __launch_bounds__(256) void scatter_kernel(
    const int* __restrict__ row, const int* __restrict__ col, const float* __restrict__ eattr,
    int* __restrict__ cursor, int* __restrict__ srow, int* __restrict__ scol,
    float* __restrict__ sea4, int E)
{
  int e = blockIdx.x * 256 + threadIdx.x;
  if (e >= E) return;
  int r = row[e];
  int p = atomicAdd(&cursor[r], 1);
  srow[p] = r;
  scol[p] = col[e];
  float4 v;
  v.x = eattr[(size_t)e * 3 + 0];
  v.y = eattr[(size_t)e * 3 + 1];
  v.z = eattr[(size_t)e * 3 + 2];
  v.w = 0.f;
  ((float4*)sea4)[p] = v;
}

// ---------------- fused edge kernel ----------------
// 128 sorted edges/block, 256 threads, rg=t>>3 (edge grp), cg=t&7 (col grp).
// B operands (W2, cW1) read from global (L1/L2-hot 16KB panels). LDS ~38KB.
#define EB 128
#define ESTR 132

template <int COORD>
__global__ __launch_bounds__(256) void edge_fused_kernel(
    const int* __restrict__ srow, const int* __restrict__ scol, const int* __restrict__ rowptr,
    const float* __restrict__ posr, float* __restrict__ posw,
    const float* __restrict__ sea4,
    const float* __restrict__ P, const float* __restrict__ Q,
    const float* __restrict__ W1t, const float* __restrict__ b1,
    const float* __restrict__ W2, const float* __restrict__ b2,
    const float* __restrict__ cW1, const float* __restrict__ cb1,
    const float* __restrict__ cW2, const float* __restrict__ cb2,
    float* __restrict__ agg, int E)
{
  __shared__ float sU[64 * ESTR];  // [k][edge]; reused as sM
  __shared__ float sW1t[4 * 64];
  __shared__ float sb1v[64], sb2v[64];
  __shared__ int s_srow[EB];
  __shared__ float sDiff[3][EB];
  __shared__ float sWe[EB];
  __shared__ float scb1v[COORD ? 64 : 1];
  __shared__ float scW2v[COORD ? 64 : 1];

  int t = threadIdx.x;
  if (t < 256) sW1t[t] = W1t[t];
  if (t >= 256) {}  // 256 threads exactly cover sW1t
  if (t < 64) { sb1v[t] = b1[t]; sb2v[t] = b2[t]; }
  if (COORD && t >= 64 && t < 128) { scb1v[t - 64] = cb1[t - 64]; scW2v[t - 64] = cW2[t - 64]; }
  __syncthreads();

  int e0 = blockIdx.x * EB;
  int nE = E - e0; if (nE > EB) nE = EB;

  // ---- stage 1: u tile (2 threads per edge) ----
  {
    int eloc = t & 127;
    int half = t >> 7;
    int e = e0 + eloc;
    if (e < E) {
      int r = srow[e];
      int c = scol[e];
      if (half == 0) s_srow[eloc] = r;
      float prx = posr[(size_t)r * 3 + 0], pry = posr[(size_t)r * 3 + 1],
            prz = posr[(size_t)r * 3 + 2];
      float pcx = posr[(size_t)c * 3 + 0], pcy = posr[(size_t)c * 3 + 1],
            pcz = posr[(size_t)c * 3 + 2];
      float dx = prx - pcx, dy = pry - pcy, dz = prz - pcz;
      float dist = sqrtf(dx * dx + dy * dy + dz * dz);
      if (half == 0) { sDiff[0][eloc] = dx; sDiff[1][eloc] = dy; sDiff[2][eloc] = dz; }
      float4 ea = ((const float4*)sea4)[e];
      int k0 = half * 32;
      const float4* P4 = (const float4*)(P + (size_t)r * 64 + k0);
      const float4* Q4 = (const float4*)(Q + (size_t)c * 64 + k0);
#pragma unroll
      for (int q = 0; q < 8; q++) {
        float4 p = P4[q];
        float4 qq = Q4[q];
#pragma unroll
        for (int comp = 0; comp < 4; comp++) {
          int kk = 4 * q + comp;
          int k = k0 + kk;
          float pv = (comp == 0) ? p.x : (comp == 1) ? p.y : (comp == 2) ? p.z : p.w;
          float qv = (comp == 0) ? qq.x : (comp == 1) ? qq.y : (comp == 2) ? qq.z : qq.w;
          float val = pv + qv + sb1v[k] + dist * sW1t[k] + ea.x * sW1t[64 + k] +
                      ea.y * sW1t[128 + k] + ea.z * sW1t[192 + k];
          sU[k * ESTR + eloc] = silu_f(val);
        }
      }
    } else {
      int k0 = half * 32;
#pragma unroll
      for (int kk = 0; kk < 32; kk++) sU[(k0 + kk) * ESTR + eloc] = 0.f;
    }
  }
  __syncthreads();

  // ---- stage 2: m = silu(u @ W2 + b2); A from LDS (conflict-free), B global ----
  int rg = t >> 3;  // 0..31: edges 4rg..4rg+3
  int cg = t & 7;   // 0..7 : cols 8cg..8cg+7
  const float4* sU4 = (const float4*)sU;
  const float4* W2g = (const float4*)W2;
  float m[4][8];
#pragma unroll
  for (int i = 0; i < 4; i++)
#pragma unroll
    for (int j = 0; j < 8; j++) m[i][j] = 0.f;
#pragma unroll 8
  for (int k = 0; k < 64; k++) {
    float4 a = sU4[k * (ESTR / 4) + rg];
    float4 w0 = W2g[k * 16 + 2 * cg];
    float4 w1 = W2g[k * 16 + 2 * cg + 1];
#pragma unroll
    for (int i = 0; i < 4; i++) {
      float av = (i == 0) ? a.x : (i == 1) ? a.y : (i == 2) ? a.z : a.w;
      m[i][0] += av * w0.x; m[i][1] += av * w0.y;
      m[i][2] += av * w0.z; m[i][3] += av * w0.w;
      m[i][4] += av * w1.x; m[i][5] += av * w1.y;
      m[i][6] += av * w1.z; m[i][7] += av * w1.w;
    }
  }
#pragma unroll
  for (int i = 0; i < 4; i++)
#pragma unroll
    for (int j = 0; j < 8; j++) m[i][j] = silu_f(m[i][j] + sb2v[8 * cg + j]);
  __syncthreads();  // all reads of u done
  // write m transposed as [k][edge], float4 over the 4 edges
#pragma unroll
  for (int j = 0; j < 8; j++) {
    float4 v;
    v.x = m[0][j]; v.y = m[1][j]; v.z = m[2][j]; v.w = m[3][j];
    ((float4*)(sU + (8 * cg + j) * ESTR))[rg] = v;
  }
  __syncthreads();

  // ---- stage 3 (COORD): w_e = silu(m @ cW1 + cb1) . cW2 + cb2 ----
  if (COORD) {
    const float4* C4 = (const float4*)cW1;
    float v[4][8];
#pragma unroll
    for (int i = 0; i < 4; i++)
#pragma unroll
      for (int j = 0; j < 8; j++) v[i][j] = 0.f;
#pragma unroll 8
    for (int k = 0; k < 64; k++) {
      float4 a = sU4[k * (ESTR / 4) + rg];
      float4 w0 = C4[k * 16 + 2 * cg];
      float4 w1 = C4[k * 16 + 2 * cg + 1];
#pragma unroll
      for (int i = 0; i < 4; i++) {
        float av = (i == 0) ? a.x : (i == 1) ? a.y : (i == 2) ? a.z : a.w;
        v[i][0] += av * w0.x; v[i][1] += av * w0.y;
        v[i][2] += av * w0.z; v[i][3] += av * w0.w;
        v[i][4] += av * w1.x; v[i][5] += av * w1.y;
        v[i][6] += av * w1.z; v[i][7] += av * w1.w;
      }
    }
    float cb2v = cb2[0];
#pragma unroll
    for (int i = 0; i < 4; i++) {
      float part = 0.f;
#pragma unroll
      for (int j = 0; j < 8; j++)
        part += silu_f(v[i][j] + scb1v[8 * cg + j]) * scW2v[8 * cg + j];
      // butterfly over the 8 cg lanes (adjacent lanes share rg)
      part += __shfl_xor(part, 1);
      part += __shfl_xor(part, 2);
      part += __shfl_xor(part, 4);
      if (cg == 0) sWe[4 * rg + i] = part + cb2v;
    }
    __syncthreads();
  }

  // ---- stage 4: segmented reductions ----
  int e1 = e0 + nE;
  if (t < 64) {
    int j = t;
    float acc = 0.f;
    int cur = s_srow[0];
    for (int le = 0; le < nE; le++) {
      int r = s_srow[le];
      if (r != cur) {
        bool interior = (rowptr[cur] >= e0) && (rowptr[cur + 1] <= e1);
        if (interior) agg[(size_t)cur * 64 + j] = acc;
        else atomicAdd(&agg[(size_t)cur * 64 + j], acc);
        acc = 0.f;
        cur = r;
      }
      acc += sU[j * ESTR + le];
    }
    bool interior = (rowptr[cur] >= e0) && (rowptr[cur + 1] <= e1);
    if (interior) agg[(size_t)cur * 64 + j] = acc;
    else atomicAdd(&agg[(size_t)cur * 64 + j], acc);
  } else if (COORD && t >= 64 && t < 67) {
    int d = t - 64;
    float acc = 0.f;
    int cur = s_srow[0];
    for (int le = 0; le < nE; le++) {
      int r = s_srow[le];
      if (r != cur) {
        atomicAdd(&posw[(size_t)cur * 3 + d], acc);
        acc = 0.f;
        cur = r;
      }
      acc += sDiff[d][le] * sWe[le];
    }
    atomicAdd(&posw[(size_t)cur * 3 + d], acc);
  }
}

// ---------------- pooling + classifier ----------------
__device__ __forceinline__ int lbound(const int* __restrict__ a, int n, int v)
{
  int lo = 0, hi = n;
  while (lo < hi) {
    int mid = (lo + hi) >> 1;
    if (a[mid] < v) lo = mid + 1;
    else hi = mid;
  }
  return lo;
}

__global__ __launch_bounds__(256) void pool_cls_kernel(
    const float* __restrict__ h, const int* __restrict__ batch, int N,
    const float* __restrict__ W1, const float* __restrict__ b1,
    const float* __restrict__ W2, const float* __restrict__ b2, float* __restrict__ out)
{
  int g = blockIdx.x;
  int start = lbound(batch, N, g);
  int end = lbound(batch, N, g + 1);
  int j = threadIdx.x & 63;
  int grp = threadIdx.x >> 6;
  float s = 0.f, mx = -INFINITY;
  for (int n = start + grp; n < end; n += 4) {
    float v = h[(size_t)n * 64 + j];
    s += v;
    mx = fmaxf(mx, v);
  }
  __shared__ float ssum[4][64];
  __shared__ float smax[4][64];
  __shared__ float pooled[128];
  __shared__ float su[64];
  ssum[grp][j] = s;
  smax[grp][j] = mx;
  __syncthreads();
  if (grp == 0) {
    float S = ssum[0][j] + ssum[1][j] + ssum[2][j] + ssum[3][j];
    float M = fmaxf(fmaxf(smax[0][j], smax[1][j]), fmaxf(smax[2][j], smax[3][j]));
    float cnt = (float)(end - start);
    pooled[j] = S / fmaxf(cnt, 1.0f);
    pooled[64 + j] = M;
  }
  __syncthreads();
  if (threadIdx.x < 64) {
    float a = b1[j];
#pragma unroll
    for (int k = 0; k < 128; k++) a += pooled[k] * W1[k * 64 + j];
    su[j] = fmaxf(a, 0.f);
  }
  __syncthreads();
  if (threadIdx.x < 2) {
    float a = b2[threadIdx.x];
#pragma unroll
    for (int k = 0; k < 64; k++) a += su[k] * W2[k * 2 + threadIdx.x];
    out[g * 2 + threadIdx.x] = a;
  }
}

extern "C" void kernel_launch(void* const* d_in, const int* in_sizes, int n_in,
                              void* d_out, int out_size, void* d_ws, size_t ws_size,
                              hipStream_t stream)
{
  const float* x = (const float*)d_in[0];
  const float* pos = (const float*)d_in[1];
  const int* ei = (const int*)d_in[2];
  const float* eattr = (const float*)d_in[3];
  const int* batch = (const int*)d_in[4];
  const float* projW = (const float*)d_in[5];
  const float* projb = (const float*)d_in[6];
  const float* msgW1 = (const float*)d_in[7];
  const float* msgb1 = (const float*)d_in[8];
  const float* msgW2 = (const float*)d_in[9];
  const float* msgb2 = (const float*)d_in[10];
  const float* ndW1 = (const float*)d_in[11];
  const float* ndb1 = (const float*)d_in[12];
  const float* ndW2 = (const float*)d_in[13];
  const float* ndb2 = (const float*)d_in[14];
  const float* cdW1 = (const float*)d_in[15];
  const float* cdb1 = (const float*)d_in[16];
  const float* cdW2 = (const float*)d_in[17];
  const float* cdb2 = (const float*)d_in[18];
  const float* clsW1 = (const float*)d_in[19];
  const float* clsb1 = (const float*)d_in[20];
  const float* clsW2 = (const float*)d_in[21];
  const float* clsb2 = (const float*)d_in[22];

  int N = in_sizes[4];
  int E = in_sizes[3] / 3;
  const int* rowp = ei;
  const int* colp = ei + E;

  char* wsb = (char*)d_ws;
  size_t off = 0;
  auto alloc = [&](size_t bytes) {
    size_t o = off;
    off = (off + bytes + 255) & ~(size_t)255;
    return o;
  };
  size_t nh = (size_t)N * 64 * sizeof(float);
  size_t o_h = alloc(nh);
  size_t o_P = alloc(nh);
  size_t o_Q = alloc(nh);
  size_t o_agg = alloc(nh);
  size_t o_posA = alloc((size_t)N * 3 * sizeof(float));
  size_t o_posB = alloc((size_t)N * 3 * sizeof(float));
  size_t o_cnt = alloc((size_t)N * sizeof(int));
  size_t o_rowptr = alloc(((size_t)N + 1) * sizeof(int));
  size_t o_cursor = alloc((size_t)N * sizeof(int));
  size_t o_srow = alloc((size_t)E * sizeof(int));
  size_t o_scol = alloc((size_t)E * sizeof(int));
  size_t o_sea4 = alloc((size_t)E * 4 * sizeof(float));
  size_t csr_end = off;

  float* h = (float*)(wsb + o_h);
  float* Pb = (float*)(wsb + o_P);
  float* Qb = (float*)(wsb + o_Q);
  float* agg = (float*)(wsb + o_agg);
  float* posA = (float*)(wsb + o_posA);
  float* posB = (float*)(wsb + o_posB);

  int nb_nodes = (N + 255) / 256;
  int nb_edges = (E + 255) / 256;
  int nb_tiled = (N + NB - 1) / NB;
  int G = out_size / 2;

  proj_kernel<<<nb_nodes, 256, 0, stream>>>(x, projW, projb, h, N);

  const float* pr[4] = {pos, posA, posB, posA};
  float* pw[4] = {posA, posB, posA, nullptr};

  bool use_sorted = (csr_end <= ws_size);

  if (use_sorted) {
    int* cnt = (int*)(wsb + o_cnt);
    int* rowptr = (int*)(wsb + o_rowptr);
    int* cursor = (int*)(wsb + o_cursor);
    int* srow = (int*)(wsb + o_srow);
    int* scol = (int*)(wsb + o_scol);
    float* sea4 = (float*)(wsb + o_sea4);

    hipMemsetAsync(cnt, 0, (size_t)N * sizeof(int), stream);
    hist_kernel<<<nb_edges, 256, 0, stream>>>(rowp, cnt, E);
    scan_kernel<<<1, 1024, 0, stream>>>(cnt, rowptr, cursor, N, E);
    scatter_kernel<<<nb_edges, 256, 0, stream>>>(rowp, colp, eattr, cursor, srow, scol, sea4, E);

    int nb_fused = (E + EB - 1) / EB;
    for (int i = 0; i < 4; i++) {
      premul_tiled_kernel<<<nb_tiled, 256, 0, stream>>>(h, msgW1 + (size_t)i * 132 * 64, Pb, Qb,
                                                        N);
      hipMemsetAsync(agg, 0, nh, stream);
      if (i < 3) {
        hipMemcpyAsync(pw[i], pr[i], (size_t)N * 3 * sizeof(float), hipMemcpyDeviceToDevice,
                       stream);
        edge_fused_kernel<1><<<nb_fused, 256, 0, stream>>>(
            srow, scol, rowptr, pr[i], pw[i], sea4, Pb, Qb,
            msgW1 + (size_t)i * 132 * 64 + 128 * 64, msgb1 + i * 64,
            msgW2 + (size_t)i * 4096, msgb2 + i * 64,
            cdW1 + (size_t)i * 4096, cdb1 + i * 64, cdW2 + i * 64, cdb2 + i, agg, E);
      } else {
        edge_fused_kernel<0><<<nb_fused, 256, 0, stream>>>(
            srow, scol, rowptr, pr[i], nullptr, sea4, Pb, Qb,
            msgW1 + (size_t)i * 132 * 64 + 128 * 64, msgb1 + i * 64,
            msgW2 + (size_t)i * 4096, msgb2 + i * 64,
            nullptr, nullptr, nullptr, nullptr, agg, E);
      }
      node_tiled_kernel<<<nb_tiled, 256, 0, stream>>>(
          h, agg, ndW1 + (size_t)i * 8192, ndb1 + i * 64, ndW2 + (size_t)i * 4096, ndb2 + i * 64,
          N);
    }
  } else {
    for (int i = 0; i < 4; i++) {
      premul_tiled_kernel<<<nb_tiled, 256, 0, stream>>>(h, msgW1 + (size_t)i * 132 * 64, Pb, Qb,
                                                        N);
      hipMemsetAsync(agg, 0, nh, stream);
      node_tiled_kernel<<<nb_tiled, 256, 0, stream>>>(
          h, agg, ndW1 + (size_t)i * 8192, ndb1 + i * 64, ndW2 + (size_t)i * 4096, ndb2 + i * 64,
          N);
    }
  }

  pool_cls_kernel<<<G, 256, 0, stream>>>(h, batch, N, clsW1, clsb1, clsW2, clsb2, (float*)d_out);
}

// Round 10
// 1144.494 us; speedup vs baseline: 12.4014x; 1.5585x over previous
//
#include <hip/hip_runtime.h>
#include <math.h>

// EGNN forward. P/Q factorization + CSR sort + fused edge kernel.
// Round 10: edge MLP GEMMs on MFMA (bf16 3-split hi/lo for ~fp32 accuracy).
// A = u tile in LDS [edge][k] bf16 with XOR swizzle (byte ^= (edge&7)<<4);
// B = pre-split transposed weight tables [col][k] bf16 read from global.
// Stage-4 segmented scan parallelized 4x (quarter segments).

typedef __attribute__((ext_vector_type(8))) short bshort8;
typedef __attribute__((ext_vector_type(4))) float f32x4;
typedef unsigned short ushort;
typedef unsigned int uint;

__device__ __forceinline__ float silu_f(float x) { return x / (1.0f + __expf(-x)); }

__device__ __forceinline__ void bf16_split(float x, ushort& h, ushort& l)
{
  uint bx = __float_as_uint(x);
  ushort hb = (ushort)(bx >> 16);
  float hf = __uint_as_float((uint)hb << 16);
  float r = x - hf;
  l = (ushort)(__float_as_uint(r) >> 16);
  h = hb;
}

__device__ __forceinline__ float bf16_to_f(ushort u) { return __uint_as_float((uint)u << 16); }

#define ROW_FMA(acc, scal, rowptr)                                                   \
  {                                                                                  \
    const float4* _w = (const float4*)(rowptr);                                      \
    _Pragma("unroll") for (int _j = 0; _j < 16; _j++)                                \
    {                                                                                \
      float4 _wv = _w[_j];                                                           \
      acc[4 * _j + 0] += (scal) * _wv.x;                                             \
      acc[4 * _j + 1] += (scal) * _wv.y;                                             \
      acc[4 * _j + 2] += (scal) * _wv.z;                                             \
      acc[4 * _j + 3] += (scal) * _wv.w;                                             \
    }                                                                                \
  }

// ---------------- proj ----------------
__global__ __launch_bounds__(256) void proj_kernel(
    const float* __restrict__ x, const float* __restrict__ W, const float* __restrict__ b,
    float* __restrict__ h, int N)
{
  __shared__ float sW[26 * 64];
  __shared__ float sb[64];
  for (int i = threadIdx.x; i < 26 * 64; i += 256) sW[i] = W[i];
  if (threadIdx.x < 64) sb[threadIdx.x] = b[threadIdx.x];
  __syncthreads();
  int n = blockIdx.x * 256 + threadIdx.x;
  if (n >= N) return;
  float acc[64];
#pragma unroll
  for (int j = 0; j < 64; j++) acc[j] = sb[j];
#pragma unroll
  for (int k = 0; k < 26; k++) {
    float xk = x[(size_t)n * 26 + k];
    ROW_FMA(acc, xk, sW + k * 64);
  }
  float4* h4 = (float4*)(h + (size_t)n * 64);
#pragma unroll
  for (int j4 = 0; j4 < 16; j4++) {
    float4 v;
    v.x = acc[4 * j4 + 0]; v.y = acc[4 * j4 + 1]; v.z = acc[4 * j4 + 2]; v.w = acc[4 * j4 + 3];
    h4[j4] = v;
  }
}

// ---------------- tiled premul ----------------
#define NB 128
#define ASTR 132

__global__ __launch_bounds__(256) void premul_tiled_kernel(
    const float* __restrict__ h, const float* __restrict__ W1,
    float* __restrict__ P, float* __restrict__ Q, int N)
{
  __shared__ float sA[64 * ASTR];
  __shared__ float sW[64 * 64];
  int t = threadIdx.x;
  int n0 = blockIdx.x * NB;

#pragma unroll
  for (int it = 0; it < 8; it++) {
    int f = t + 256 * it;
    int nl = f >> 4;
    int k4 = f & 15;
    int n = n0 + nl;
    float4 v;
    if (n < N) v = ((const float4*)(h + (size_t)n * 64))[k4];
    else { v.x = v.y = v.z = v.w = 0.f; }
    sA[(4 * k4 + 0) * ASTR + nl] = v.x;
    sA[(4 * k4 + 1) * ASTR + nl] = v.y;
    sA[(4 * k4 + 2) * ASTR + nl] = v.z;
    sA[(4 * k4 + 3) * ASTR + nl] = v.w;
  }
  for (int i = t; i < 4096; i += 256) sW[i] = W1[i];
  __syncthreads();

  int rg = t & 31, cg = t >> 5;
  const float4* sA4 = (const float4*)sA;
  const float4* sW4 = (const float4*)sW;

  float aP[4][8];
#pragma unroll
  for (int i = 0; i < 4; i++)
#pragma unroll
    for (int j = 0; j < 8; j++) aP[i][j] = 0.f;
#pragma unroll 8
  for (int k = 0; k < 64; k++) {
    float4 a = sA4[k * (ASTR / 4) + rg];
    float4 w0 = sW4[k * 16 + 2 * cg];
    float4 w1 = sW4[k * 16 + 2 * cg + 1];
#pragma unroll
    for (int i = 0; i < 4; i++) {
      float av = (i == 0) ? a.x : (i == 1) ? a.y : (i == 2) ? a.z : a.w;
      aP[i][0] += av * w0.x; aP[i][1] += av * w0.y;
      aP[i][2] += av * w0.z; aP[i][3] += av * w0.w;
      aP[i][4] += av * w1.x; aP[i][5] += av * w1.y;
      aP[i][6] += av * w1.z; aP[i][7] += av * w1.w;
    }
  }
  __syncthreads();
  for (int i = t; i < 4096; i += 256) sW[i] = W1[4096 + i];
  __syncthreads();
  float aQ[4][8];
#pragma unroll
  for (int i = 0; i < 4; i++)
#pragma unroll
    for (int j = 0; j < 8; j++) aQ[i][j] = 0.f;
#pragma unroll 8
  for (int k = 0; k < 64; k++) {
    float4 a = sA4[k * (ASTR / 4) + rg];
    float4 w0 = sW4[k * 16 + 2 * cg];
    float4 w1 = sW4[k * 16 + 2 * cg + 1];
#pragma unroll
    for (int i = 0; i < 4; i++) {
      float av = (i == 0) ? a.x : (i == 1) ? a.y : (i == 2) ? a.z : a.w;
      aQ[i][0] += av * w0.x; aQ[i][1] += av * w0.y;
      aQ[i][2] += av * w0.z; aQ[i][3] += av * w0.w;
      aQ[i][4] += av * w1.x; aQ[i][5] += av * w1.y;
      aQ[i][6] += av * w1.z; aQ[i][7] += av * w1.w;
    }
  }
#pragma unroll
  for (int i = 0; i < 4; i++) {
    int n = n0 + 4 * rg + i;
    if (n < N) {
      float4 o0, o1;
      o0.x = aP[i][0]; o0.y = aP[i][1]; o0.z = aP[i][2]; o0.w = aP[i][3];
      o1.x = aP[i][4]; o1.y = aP[i][5]; o1.z = aP[i][6]; o1.w = aP[i][7];
      float4* Pp = (float4*)(P + (size_t)n * 64 + 8 * cg);
      Pp[0] = o0; Pp[1] = o1;
      o0.x = aQ[i][0]; o0.y = aQ[i][1]; o0.z = aQ[i][2]; o0.w = aQ[i][3];
      o1.x = aQ[i][4]; o1.y = aQ[i][5]; o1.z = aQ[i][6]; o1.w = aQ[i][7];
      float4* Qp = (float4*)(Q + (size_t)n * 64 + 8 * cg);
      Qp[0] = o0; Qp[1] = o1;
    }
  }
}

// ---------------- tiled node MLP ----------------
__global__ __launch_bounds__(256) void node_tiled_kernel(
    float* __restrict__ h, const float* __restrict__ agg,
    const float* __restrict__ W1, const float* __restrict__ b1,
    const float* __restrict__ W2, const float* __restrict__ b2, int N)
{
  __shared__ float sA[64 * ASTR];
  __shared__ float sW[64 * 64];
  __shared__ float sb1v[64], sb2v[64];
  int t = threadIdx.x;
  int n0 = blockIdx.x * NB;
  int rg = t & 31, cg = t >> 5;
  const float4* sA4 = (const float4*)sA;
  const float4* sW4 = (const float4*)sW;

#pragma unroll
  for (int it = 0; it < 8; it++) {
    int f = t + 256 * it;
    int nl = f >> 4;
    int k4 = f & 15;
    int n = n0 + nl;
    float4 v;
    if (n < N) v = ((const float4*)(h + (size_t)n * 64))[k4];
    else { v.x = v.y = v.z = v.w = 0.f; }
    sA[(4 * k4 + 0) * ASTR + nl] = v.x;
    sA[(4 * k4 + 1) * ASTR + nl] = v.y;
    sA[(4 * k4 + 2) * ASTR + nl] = v.z;
    sA[(4 * k4 + 3) * ASTR + nl] = v.w;
  }
  for (int i = t; i < 4096; i += 256) sW[i] = W1[i];
  if (t < 64) { sb1v[t] = b1[t]; sb2v[t] = b2[t]; }
  __syncthreads();

  float u[4][8];
#pragma unroll
  for (int i = 0; i < 4; i++)
#pragma unroll
    for (int j = 0; j < 8; j++) u[i][j] = 0.f;
#pragma unroll 8
  for (int k = 0; k < 64; k++) {
    float4 a = sA4[k * (ASTR / 4) + rg];
    float4 w0 = sW4[k * 16 + 2 * cg];
    float4 w1 = sW4[k * 16 + 2 * cg + 1];
#pragma unroll
    for (int i = 0; i < 4; i++) {
      float av = (i == 0) ? a.x : (i == 1) ? a.y : (i == 2) ? a.z : a.w;
      u[i][0] += av * w0.x; u[i][1] += av * w0.y;
      u[i][2] += av * w0.z; u[i][3] += av * w0.w;
      u[i][4] += av * w1.x; u[i][5] += av * w1.y;
      u[i][6] += av * w1.z; u[i][7] += av * w1.w;
    }
  }
  __syncthreads();

#pragma unroll
  for (int it = 0; it < 8; it++) {
    int f = t + 256 * it;
    int nl = f >> 4;
    int k4 = f & 15;
    int n = n0 + nl;
    float4 v;
    if (n < N) v = ((const float4*)(agg + (size_t)n * 64))[k4];
    else { v.x = v.y = v.z = v.w = 0.f; }
    sA[(4 * k4 + 0) * ASTR + nl] = v.x;
    sA[(4 * k4 + 1) * ASTR + nl] = v.y;
    sA[(4 * k4 + 2) * ASTR + nl] = v.z;
    sA[(4 * k4 + 3) * ASTR + nl] = v.w;
  }
  for (int i = t; i < 4096; i += 256) sW[i] = W1[4096 + i];
  __syncthreads();
#pragma unroll 8
  for (int k = 0; k < 64; k++) {
    float4 a = sA4[k * (ASTR / 4) + rg];
    float4 w0 = sW4[k * 16 + 2 * cg];
    float4 w1 = sW4[k * 16 + 2 * cg + 1];
#pragma unroll
    for (int i = 0; i < 4; i++) {
      float av = (i == 0) ? a.x : (i == 1) ? a.y : (i == 2) ? a.z : a.w;
      u[i][0] += av * w0.x; u[i][1] += av * w0.y;
      u[i][2] += av * w0.z; u[i][3] += av * w0.w;
      u[i][4] += av * w1.x; u[i][5] += av * w1.y;
      u[i][6] += av * w1.z; u[i][7] += av * w1.w;
    }
  }
#pragma unroll
  for (int i = 0; i < 4; i++)
#pragma unroll
    for (int j = 0; j < 8; j++) u[i][j] = silu_f(u[i][j] + sb1v[8 * cg + j]);
  __syncthreads();

#pragma unroll
  for (int j = 0; j < 8; j++)
#pragma unroll
    for (int i = 0; i < 4; i++) sA[(8 * cg + j) * ASTR + (4 * rg + i)] = u[i][j];
  for (int i = t; i < 4096; i += 256) sW[i] = W2[i];
  __syncthreads();

  float o[4][8];
#pragma unroll
  for (int i = 0; i < 4; i++)
#pragma unroll
    for (int j = 0; j < 8; j++) o[i][j] = 0.f;
#pragma unroll 8
  for (int k = 0; k < 64; k++) {
    float4 a = sA4[k * (ASTR / 4) + rg];
    float4 w0 = sW4[k * 16 + 2 * cg];
    float4 w1 = sW4[k * 16 + 2 * cg + 1];
#pragma unroll
    for (int i = 0; i < 4; i++) {
      float av = (i == 0) ? a.x : (i == 1) ? a.y : (i == 2) ? a.z : a.w;
      o[i][0] += av * w0.x; o[i][1] += av * w0.y;
      o[i][2] += av * w0.z; o[i][3] += av * w0.w;
      o[i][4] += av * w1.x; o[i][5] += av * w1.y;
      o[i][6] += av * w1.z; o[i][7] += av * w1.w;
    }
  }
#pragma unroll
  for (int i = 0; i < 4; i++) {
    int n = n0 + 4 * rg + i;
    if (n < N) {
      float4* hp = (float4*)(h + (size_t)n * 64 + 8 * cg);
      float4 h0 = hp[0], h1 = hp[1];
      h0.x += o[i][0] + sb2v[8 * cg + 0];
      h0.y += o[i][1] + sb2v[8 * cg + 1];
      h0.z += o[i][2] + sb2v[8 * cg + 2];
      h0.w += o[i][3] + sb2v[8 * cg + 3];
      h1.x += o[i][4] + sb2v[8 * cg + 4];
      h1.y += o[i][5] + sb2v[8 * cg + 5];
      h1.z += o[i][6] + sb2v[8 * cg + 6];
      h1.w += o[i][7] + sb2v[8 * cg + 7];
      hp[0] = h0; hp[1] = h1;
    }
  }
}

// ---------------- CSR build ----------------
__global__ __launch_bounds__(256) void hist_kernel(
    const int* __restrict__ row, int* __restrict__ cnt, int E)
{
  int e = blockIdx.x * 256 + threadIdx.x;
  if (e < E) atomicAdd(&cnt[row[e]], 1);
}

__global__ __launch_bounds__(1024) void scan_kernel(
    const int* __restrict__ cnt, int* __restrict__ rowptr, int* __restrict__ cursor, int N, int E)
{
  __shared__ int part[1024];
  int t = threadIdx.x;
  int chunk = (N + 1023) >> 10;
  int lo = t * chunk;
  int hi = lo + chunk;
  if (lo > N) lo = N;
  if (hi > N) hi = N;
  int s = 0;
  for (int i = lo; i < hi; i++) s += cnt[i];
  part[t] = s;
  __syncthreads();
  for (int off = 1; off < 1024; off <<= 1) {
    int v = 0;
    if (t >= off) v = part[t - off];
    __syncthreads();
    if (t >= off) part[t] += v;
    __syncthreads();
  }
  int run = part[t] - s;
  for (int i = lo; i < hi; i++) {
    rowptr[i] = run;
    cursor[i] = run;
    run += cnt[i];
  }
  if (t == 0) rowptr[N] = E;
}

__global__ __launch_bounds__(256) void scatter_kernel(
    const int* __restrict__ row, const int* __restrict__ col, const float* __restrict__ eattr,
    int* __restrict__ cursor, int* __restrict__ srow, int* __restrict__ scol,
    float* __restrict__ sea4, int E)
{
  int e = blockIdx.x * 256 + threadIdx.x;
  if (e >= E) return;
  int r = row[e];
  int p = atomicAdd(&cursor[r], 1);
  srow[p] = r;
  scol[p] = col[e];
  float4 v;
  v.x = eattr[(size_t)e * 3 + 0];
  v.y = eattr[(size_t)e * 3 + 1];
  v.z = eattr[(size_t)e * 3 + 2];
  v.w = 0.f;
  ((float4*)sea4)[p] = v;
}

// ---------------- weight prep: bf16 hi/lo of W^T ----------------
__global__ __launch_bounds__(256) void prep_wt_kernel(
    const float* __restrict__ W2all, const float* __restrict__ C1all,
    ushort* __restrict__ w2h, ushort* __restrict__ w2l,
    ushort* __restrict__ c1h, ushort* __restrict__ c1l)
{
  int idx = blockIdx.x * 256 + threadIdx.x;
  if (idx >= 4 * 4096) return;
  int layer = idx >> 12, rem = idx & 4095;
  int k = rem >> 6, c = rem & 63;
  int oidx = layer * 4096 + c * 64 + k;
  ushort h, l;
  bf16_split(W2all[idx], h, l);
  w2h[oidx] = h; w2l[oidx] = l;
  if (layer < 3) {
    bf16_split(C1all[idx], h, l);
    c1h[oidx] = h; c1l[oidx] = l;
  }
}

// ---------------- fused edge kernel (MFMA) ----------------
#define EB 128

__device__ __forceinline__ bshort8 lds_frag(const ushort* base, int edge, int kb)
{
  int byte = edge * 128 + kb * 2;
  byte ^= (edge & 7) << 4;
  return *(const bshort8*)((const char*)base + byte);
}

template <int COORD>
__global__ __launch_bounds__(256) void edge_fused_kernel(
    const int* __restrict__ srow, const int* __restrict__ scol, const int* __restrict__ rowptr,
    const float* __restrict__ posr, float* __restrict__ posw,
    const float* __restrict__ sea4,
    const float* __restrict__ P, const float* __restrict__ Q,
    const float* __restrict__ W1t, const float* __restrict__ b1,
    const ushort* __restrict__ w2h, const ushort* __restrict__ w2l,
    const float* __restrict__ b2,
    const ushort* __restrict__ c1h, const ushort* __restrict__ c1l,
    const float* __restrict__ cb1, const float* __restrict__ cW2,
    const float* __restrict__ cb2,
    float* __restrict__ agg, int E)
{
  __shared__ ushort sUhi[EB * 64];  // [edge][k] bf16 hi, XOR-swizzled rows
  __shared__ ushort sUlo[EB * 64];
  __shared__ float sW1t[4 * 64];
  __shared__ float sb1v[64], sb2v[64];
  __shared__ int s_srow[EB];
  __shared__ float sDiff[3][EB];
  __shared__ float sWe[EB];
  __shared__ float sPart[COORD ? EB * 4 : 1];
  __shared__ float scb1v[COORD ? 64 : 1];
  __shared__ float scW2v[COORD ? 64 : 1];

  int t = threadIdx.x;
  sW1t[t] = W1t[t];
  if (t < 64) { sb1v[t] = b1[t]; sb2v[t] = b2[t]; }
  if (COORD && t >= 64 && t < 128) { scb1v[t - 64] = cb1[t - 64]; scW2v[t - 64] = cW2[t - 64]; }
  __syncthreads();

  int e0 = blockIdx.x * EB;
  int nE = E - e0; if (nE > EB) nE = EB;

  // ---- stage 1: u tile -> bf16 hi/lo into swizzled LDS ----
  {
    int eloc = t & 127;
    int half = t >> 7;
    int k0 = half * 32;
    int e = e0 + eloc;
    int swz = (eloc & 7) << 4;
    if (e < E) {
      int r = srow[e];
      int c = scol[e];
      if (half == 0) s_srow[eloc] = r;
      float prx = posr[(size_t)r * 3 + 0], pry = posr[(size_t)r * 3 + 1],
            prz = posr[(size_t)r * 3 + 2];
      float pcx = posr[(size_t)c * 3 + 0], pcy = posr[(size_t)c * 3 + 1],
            pcz = posr[(size_t)c * 3 + 2];
      float dx = prx - pcx, dy = pry - pcy, dz = prz - pcz;
      float dist = sqrtf(dx * dx + dy * dy + dz * dz);
      if (half == 0) { sDiff[0][eloc] = dx; sDiff[1][eloc] = dy; sDiff[2][eloc] = dz; }
      float4 ea = ((const float4*)sea4)[e];
      const float4* P4 = (const float4*)(P + (size_t)r * 64 + k0);
      const float4* Q4 = (const float4*)(Q + (size_t)c * 64 + k0);
#pragma unroll
      for (int q = 0; q < 8; q++) {
        float4 p = P4[q];
        float4 qq = Q4[q];
        float uu[4];
#pragma unroll
        for (int comp = 0; comp < 4; comp++) {
          int k = k0 + 4 * q + comp;
          float pv = (comp == 0) ? p.x : (comp == 1) ? p.y : (comp == 2) ? p.z : p.w;
          float qv = (comp == 0) ? qq.x : (comp == 1) ? qq.y : (comp == 2) ? qq.z : qq.w;
          float val = pv + qv + sb1v[k] + dist * sW1t[k] + ea.x * sW1t[64 + k] +
                      ea.y * sW1t[128 + k] + ea.z * sW1t[192 + k];
          uu[comp] = silu_f(val);
        }
        ushort h0, l0, h1, l1, h2, l2, h3, l3;
        bf16_split(uu[0], h0, l0);
        bf16_split(uu[1], h1, l1);
        bf16_split(uu[2], h2, l2);
        bf16_split(uu[3], h3, l3);
        int base = eloc * 128 + (k0 + 4 * q) * 2;
        *(uint*)((char*)sUhi + (base ^ swz)) = (uint)h0 | ((uint)h1 << 16);
        *(uint*)((char*)sUhi + ((base + 4) ^ swz)) = (uint)h2 | ((uint)h3 << 16);
        *(uint*)((char*)sUlo + (base ^ swz)) = (uint)l0 | ((uint)l1 << 16);
        *(uint*)((char*)sUlo + ((base + 4) ^ swz)) = (uint)l2 | ((uint)l3 << 16);
      }
    } else {
#pragma unroll
      for (int kk = 0; kk < 32; kk += 2) {
        int base = eloc * 128 + (k0 + kk) * 2;
        *(uint*)((char*)sUhi + (base ^ swz)) = 0;
        *(uint*)((char*)sUlo + (base ^ swz)) = 0;
      }
    }
  }
  __syncthreads();

  // ---- stage 2: m = silu(u @ W2 + b2) via MFMA bf16 3-split ----
  int l = t & 63;
  int wv = t >> 6;
  int colh = l & 15;
  int col = wv * 16 + colh;
  int kq = l >> 4;  // 0..3

  {
    const ushort* bhp = w2h + col * 64 + kq * 8;
    const ushort* blp = w2l + col * 64 + kq * 8;
    bshort8 bh0 = *(const bshort8*)(bhp);
    bshort8 bh1 = *(const bshort8*)(bhp + 32);
    bshort8 bl0 = *(const bshort8*)(blp);
    bshort8 bl1 = *(const bshort8*)(blp + 32);

    f32x4 acc[8];
#pragma unroll
    for (int et = 0; et < 8; et++) {
      int edge = et * 16 + colh;
      bshort8 ah0 = lds_frag(sUhi, edge, kq * 8);
      bshort8 ah1 = lds_frag(sUhi, edge, 32 + kq * 8);
      bshort8 al0 = lds_frag(sUlo, edge, kq * 8);
      bshort8 al1 = lds_frag(sUlo, edge, 32 + kq * 8);
      f32x4 a = {0.f, 0.f, 0.f, 0.f};
      a = __builtin_amdgcn_mfma_f32_16x16x32_bf16(ah0, bh0, a, 0, 0, 0);
      a = __builtin_amdgcn_mfma_f32_16x16x32_bf16(ah1, bh1, a, 0, 0, 0);
      a = __builtin_amdgcn_mfma_f32_16x16x32_bf16(ah0, bl0, a, 0, 0, 0);
      a = __builtin_amdgcn_mfma_f32_16x16x32_bf16(ah1, bl1, a, 0, 0, 0);
      a = __builtin_amdgcn_mfma_f32_16x16x32_bf16(al0, bh0, a, 0, 0, 0);
      a = __builtin_amdgcn_mfma_f32_16x16x32_bf16(al1, bh1, a, 0, 0, 0);
      acc[et] = a;
    }
    __syncthreads();  // all reads of sU done before overwrite with m

    float b2c = sb2v[col];
#pragma unroll
    for (int et = 0; et < 8; et++) {
#pragma unroll
      for (int r = 0; r < 4; r++) {
        int edge = et * 16 + kq * 4 + r;  // C/D: row=(lane>>4)*4+reg (m89)
        float mv = silu_f(acc[et][r] + b2c);
        ushort mh, ml;
        bf16_split(mv, mh, ml);
        int byte = (edge * 128 + col * 2) ^ ((edge & 7) << 4);
        *(ushort*)((char*)sUhi + byte) = mh;
        *(ushort*)((char*)sUlo + byte) = ml;
      }
    }
  }
  __syncthreads();

  // ---- stage 3 (COORD): w_e = silu(m @ cW1 + cb1) . cW2 + cb2 ----
  if (COORD) {
    const ushort* bhp = c1h + col * 64 + kq * 8;
    const ushort* blp = c1l + col * 64 + kq * 8;
    bshort8 bh0 = *(const bshort8*)(bhp);
    bshort8 bh1 = *(const bshort8*)(bhp + 32);
    bshort8 bl0 = *(const bshort8*)(blp);
    bshort8 bl1 = *(const bshort8*)(blp + 32);
    float cb1c = scb1v[col];
    float cw2c = scW2v[col];
#pragma unroll
    for (int et = 0; et < 8; et++) {
      int edge = et * 16 + colh;
      bshort8 ah0 = lds_frag(sUhi, edge, kq * 8);
      bshort8 ah1 = lds_frag(sUhi, edge, 32 + kq * 8);
      bshort8 al0 = lds_frag(sUlo, edge, kq * 8);
      bshort8 al1 = lds_frag(sUlo, edge, 32 + kq * 8);
      f32x4 a = {0.f, 0.f, 0.f, 0.f};
      a = __builtin_amdgcn_mfma_f32_16x16x32_bf16(ah0, bh0, a, 0, 0, 0);
      a = __builtin_amdgcn_mfma_f32_16x16x32_bf16(ah1, bh1, a, 0, 0, 0);
      a = __builtin_amdgcn_mfma_f32_16x16x32_bf16(ah0, bl0, a, 0, 0, 0);
      a = __builtin_amdgcn_mfma_f32_16x16x32_bf16(ah1, bl1, a, 0, 0, 0);
      a = __builtin_amdgcn_mfma_f32_16x16x32_bf16(al0, bh0, a, 0, 0, 0);
      a = __builtin_amdgcn_mfma_f32_16x16x32_bf16(al1, bh1, a, 0, 0, 0);
#pragma unroll
      for (int r = 0; r < 4; r++) {
        float pr = silu_f(a[r] + cb1c) * cw2c;
        pr += __shfl_xor(pr, 1);
        pr += __shfl_xor(pr, 2);
        pr += __shfl_xor(pr, 4);
        pr += __shfl_xor(pr, 8);
        if (colh == 0) sPart[(et * 16 + kq * 4 + r) * 4 + wv] = pr;
      }
    }
  }
  __syncthreads();
  if (COORD) {
    if (t >= 128) {
      int e = t - 128;
      sWe[e] = sPart[4 * e + 0] + sPart[4 * e + 1] + sPart[4 * e + 2] + sPart[4 * e + 3] + cb2[0];
    }
  }
  __syncthreads();

  // ---- stage 4: segmented reductions (4-way parallel over edge quarters) ----
  {
    int j = t & 63;
    int q = t >> 6;
    int qs = q * 32;
    int qe = qs + 32; if (qe > nE) qe = nE;
    if (qs < nE) {
      float acc = 0.f;
      int cur = s_srow[qs];
      for (int le = qs; le < qe; le++) {
        int r = s_srow[le];
        if (r != cur) {
          int rs = rowptr[cur], re = rowptr[cur + 1];
          if (rs >= e0 + qs && re <= e0 + qe) agg[(size_t)cur * 64 + j] = acc;
          else atomicAdd(&agg[(size_t)cur * 64 + j], acc);
          acc = 0.f;
          cur = r;
        }
        int byte = (le * 128 + j * 2) ^ ((le & 7) << 4);
        acc += bf16_to_f(*(const ushort*)((const char*)sUhi + byte)) +
               bf16_to_f(*(const ushort*)((const char*)sUlo + byte));
      }
      int rs = rowptr[cur], re = rowptr[cur + 1];
      if (rs >= e0 + qs && re <= e0 + qe) agg[(size_t)cur * 64 + j] = acc;
      else atomicAdd(&agg[(size_t)cur * 64 + j], acc);
    }
  }
  if (COORD && t >= 64 && t < 76) {
    int idx = t - 64;
    int d = idx % 3;
    int q2 = idx / 3;
    int qs = q2 * 32;
    int qe = qs + 32; if (qe > nE) qe = nE;
    if (qs < nE) {
      float acc = 0.f;
      int cur = s_srow[qs];
      for (int le = qs; le < qe; le++) {
        int r = s_srow[le];
        if (r != cur) {
          atomicAdd(&posw[(size_t)cur * 3 + d], acc);
          acc = 0.f;
          cur = r;
        }
        acc += sDiff[d][le] * sWe[le];
      }
      atomicAdd(&posw[(size_t)cur * 3 + d], acc);
    }
  }
}

// ---------------- pooling + classifier ----------------
__device__ __forceinline__ int lbound(const int* __restrict__ a, int n, int v)
{
  int lo = 0, hi = n;
  while (lo < hi) {
    int mid = (lo + hi) >> 1;
    if (a[mid] < v) lo = mid + 1;
    else hi = mid;
  }
  return lo;
}

__global__ __launch_bounds__(256) void pool_cls_kernel(
    const float* __restrict__ h, const int* __restrict__ batch, int N,
    const float* __restrict__ W1, const float* __restrict__ b1,
    const float* __restrict__ W2, const float* __restrict__ b2, float* __restrict__ out)
{
  int g = blockIdx.x;
  int start = lbound(batch, N, g);
  int end = lbound(batch, N, g + 1);
  int j = threadIdx.x & 63;
  int grp = threadIdx.x >> 6;
  float s = 0.f, mx = -INFINITY;
  for (int n = start + grp; n < end; n += 4) {
    float v = h[(size_t)n * 64 + j];
    s += v;
    mx = fmaxf(mx, v);
  }
  __shared__ float ssum[4][64];
  __shared__ float smax[4][64];
  __shared__ float pooled[128];
  __shared__ float su[64];
  ssum[grp][j] = s;
  smax[grp][j] = mx;
  __syncthreads();
  if (grp == 0) {
    float S = ssum[0][j] + ssum[1][j] + ssum[2][j] + ssum[3][j];
    float M = fmaxf(fmaxf(smax[0][j], smax[1][j]), fmaxf(smax[2][j], smax[3][j]));
    float cnt = (float)(end - start);
    pooled[j] = S / fmaxf(cnt, 1.0f);
    pooled[64 + j] = M;
  }
  __syncthreads();
  if (threadIdx.x < 64) {
    float a = b1[j];
#pragma unroll
    for (int k = 0; k < 128; k++) a += pooled[k] * W1[k * 64 + j];
    su[j] = fmaxf(a, 0.f);
  }
  __syncthreads();
  if (threadIdx.x < 2) {
    float a = b2[threadIdx.x];
#pragma unroll
    for (int k = 0; k < 64; k++) a += su[k] * W2[k * 2 + threadIdx.x];
    out[g * 2 + threadIdx.x] = a;
  }
}

extern "C" void kernel_launch(void* const* d_in, const int* in_sizes, int n_in,
                              void* d_out, int out_size, void* d_ws, size_t ws_size,
                              hipStream_t stream)
{
  const float* x = (const float*)d_in[0];
  const float* pos = (const float*)d_in[1];
  const int* ei = (const int*)d_in[2];
  const float* eattr = (const float*)d_in[3];
  const int* batch = (const int*)d_in[4];
  const float* projW = (const float*)d_in[5];
  const float* projb = (const float*)d_in[6];
  const float* msgW1 = (const float*)d_in[7];
  const float* msgb1 = (const float*)d_in[8];
  const float* msgW2 = (const float*)d_in[9];
  const float* msgb2 = (const float*)d_in[10];
  const float* ndW1 = (const float*)d_in[11];
  const float* ndb1 = (const float*)d_in[12];
  const float* ndW2 = (const float*)d_in[13];
  const float* ndb2 = (const float*)d_in[14];
  const float* cdW1 = (const float*)d_in[15];
  const float* cdb1 = (const float*)d_in[16];
  const float* cdW2 = (const float*)d_in[17];
  const float* cdb2 = (const float*)d_in[18];
  const float* clsW1 = (const float*)d_in[19];
  const float* clsb1 = (const float*)d_in[20];
  const float* clsW2 = (const float*)d_in[21];
  const float* clsb2 = (const float*)d_in[22];

  int N = in_sizes[4];
  int E = in_sizes[3] / 3;
  const int* rowp = ei;
  const int* colp = ei + E;

  char* wsb = (char*)d_ws;
  size_t off = 0;
  auto alloc = [&](size_t bytes) {
    size_t o = off;
    off = (off + bytes + 255) & ~(size_t)255;
    return o;
  };
  size_t nh = (size_t)N * 64 * sizeof(float);
  size_t o_h = alloc(nh);
  size_t o_P = alloc(nh);
  size_t o_Q = alloc(nh);
  size_t o_agg = alloc(nh);
  size_t o_posA = alloc((size_t)N * 3 * sizeof(float));
  size_t o_posB = alloc((size_t)N * 3 * sizeof(float));
  size_t o_cnt = alloc((size_t)N * sizeof(int));
  size_t o_rowptr = alloc(((size_t)N + 1) * sizeof(int));
  size_t o_cursor = alloc((size_t)N * sizeof(int));
  size_t o_srow = alloc((size_t)E * sizeof(int));
  size_t o_scol = alloc((size_t)E * sizeof(int));
  size_t o_sea4 = alloc((size_t)E * 4 * sizeof(float));
  size_t o_w2h = alloc(4 * 4096 * sizeof(ushort));
  size_t o_w2l = alloc(4 * 4096 * sizeof(ushort));
  size_t o_c1h = alloc(4 * 4096 * sizeof(ushort));
  size_t o_c1l = alloc(4 * 4096 * sizeof(ushort));
  size_t csr_end = off;

  float* h = (float*)(wsb + o_h);
  float* Pb = (float*)(wsb + o_P);
  float* Qb = (float*)(wsb + o_Q);
  float* agg = (float*)(wsb + o_agg);
  float* posA = (float*)(wsb + o_posA);
  float* posB = (float*)(wsb + o_posB);

  int nb_nodes = (N + 255) / 256;
  int nb_edges = (E + 255) / 256;
  int nb_tiled = (N + NB - 1) / NB;
  int G = out_size / 2;

  proj_kernel<<<nb_nodes, 256, 0, stream>>>(x, projW, projb, h, N);

  const float* pr[4] = {pos, posA, posB, posA};
  float* pw[4] = {posA, posB, posA, nullptr};

  bool use_sorted = (csr_end <= ws_size);

  if (use_sorted) {
    int* cnt = (int*)(wsb + o_cnt);
    int* rowptr = (int*)(wsb + o_rowptr);
    int* cursor = (int*)(wsb + o_cursor);
    int* srow = (int*)(wsb + o_srow);
    int* scol = (int*)(wsb + o_scol);
    float* sea4 = (float*)(wsb + o_sea4);
    ushort* w2h = (ushort*)(wsb + o_w2h);
    ushort* w2l = (ushort*)(wsb + o_w2l);
    ushort* c1h = (ushort*)(wsb + o_c1h);
    ushort* c1l = (ushort*)(wsb + o_c1l);

    hipMemsetAsync(cnt, 0, (size_t)N * sizeof(int), stream);
    hist_kernel<<<nb_edges, 256, 0, stream>>>(rowp, cnt, E);
    scan_kernel<<<1, 1024, 0, stream>>>(cnt, rowptr, cursor, N, E);
    scatter_kernel<<<nb_edges, 256, 0, stream>>>(rowp, colp, eattr, cursor, srow, scol, sea4, E);
    prep_wt_kernel<<<64, 256, 0, stream>>>(msgW2, cdW1, w2h, w2l, c1h, c1l);

    int nb_fused = (E + EB - 1) / EB;
    for (int i = 0; i < 4; i++) {
      premul_tiled_kernel<<<nb_tiled, 256, 0, stream>>>(h, msgW1 + (size_t)i * 132 * 64, Pb, Qb,
                                                        N);
      hipMemsetAsync(agg, 0, nh, stream);
      if (i < 3) {
        hipMemcpyAsync(pw[i], pr[i], (size_t)N * 3 * sizeof(float), hipMemcpyDeviceToDevice,
                       stream);
        edge_fused_kernel<1><<<nb_fused, 256, 0, stream>>>(
            srow, scol, rowptr, pr[i], pw[i], sea4, Pb, Qb,
            msgW1 + (size_t)i * 132 * 64 + 128 * 64, msgb1 + i * 64,
            w2h + (size_t)i * 4096, w2l + (size_t)i * 4096, msgb2 + i * 64,
            c1h + (size_t)i * 4096, c1l + (size_t)i * 4096,
            cdb1 + i * 64, cdW2 + i * 64, cdb2 + i, agg, E);
      } else {
        edge_fused_kernel<0><<<nb_fused, 256, 0, stream>>>(
            srow, scol, rowptr, pr[i], nullptr, sea4, Pb, Qb,
            msgW1 + (size_t)i * 132 * 64 + 128 * 64, msgb1 + i * 64,
            w2h + (size_t)i * 4096, w2l + (size_t)i * 4096, msgb2 + i * 64,
            nullptr, nullptr, nullptr, nullptr, nullptr, agg, E);
      }
      node_tiled_kernel<<<nb_tiled, 256, 0, stream>>>(
          h, agg, ndW1 + (size_t)i * 8192, ndb1 + i * 64, ndW2 + (size_t)i * 4096, ndb2 + i * 64,
          N);
    }
  } else {
    for (int i = 0; i < 4; i++) {
      premul_tiled_kernel<<<nb_tiled, 256, 0, stream>>>(h, msgW1 + (size_t)i * 132 * 64, Pb, Qb,
                                                        N);
      hipMemsetAsync(agg, 0, nh, stream);
      node_tiled_kernel<<<nb_tiled, 256, 0, stream>>>(
          h, agg, ndW1 + (size_t)i * 8192, ndb1 + i * 64, ndW2 + (size_t)i * 4096, ndb2 + i * 64,
          N);
    }
  }

  pool_cls_kernel<<<G, 256, 0, stream>>>(h, batch, N, clsW1, clsb1, clsW2, clsb2, (float*)d_out);
}

// Round 11
// 1090.653 us; speedup vs baseline: 13.0136x; 1.0494x over previous
//
#include <hip/hip_runtime.h>
#include <math.h>

// EGNN forward. P/Q factorization + CSR sort + fused MFMA edge kernel.
// Round 11: stage-1 conflict-free b128 LDS writes (8 lanes/edge x 8 k-octets);
// slot-based stage-4 segmented reduction (ballot prefix, rowptr prefetched,
// packed u32 reads, no global loads in loop).

typedef __attribute__((ext_vector_type(8))) short bshort8;
typedef __attribute__((ext_vector_type(4))) float f32x4;
typedef unsigned short ushort;
typedef unsigned int uint;

__device__ __forceinline__ float silu_f(float x) { return x / (1.0f + __expf(-x)); }

__device__ __forceinline__ void bf16_split(float x, ushort& h, ushort& l)
{
  uint bx = __float_as_uint(x);
  ushort hb = (ushort)(bx >> 16);
  float hf = __uint_as_float((uint)hb << 16);
  float r = x - hf;
  l = (ushort)(__float_as_uint(r) >> 16);
  h = hb;
}

__device__ __forceinline__ float bf16_to_f(ushort u) { return __uint_as_float((uint)u << 16); }

#define ROW_FMA(acc, scal, rowptr)                                                   \
  {                                                                                  \
    const float4* _w = (const float4*)(rowptr);                                      \
    _Pragma("unroll") for (int _j = 0; _j < 16; _j++)                                \
    {                                                                                \
      float4 _wv = _w[_j];                                                           \
      acc[4 * _j + 0] += (scal) * _wv.x;                                             \
      acc[4 * _j + 1] += (scal) * _wv.y;                                             \
      acc[4 * _j + 2] += (scal) * _wv.z;                                             \
      acc[4 * _j + 3] += (scal) * _wv.w;                                             \
    }                                                                                \
  }

// ---------------- proj ----------------
__global__ __launch_bounds__(256) void proj_kernel(
    const float* __restrict__ x, const float* __restrict__ W, const float* __restrict__ b,
    float* __restrict__ h, int N)
{
  __shared__ float sW[26 * 64];
  __shared__ float sb[64];
  for (int i = threadIdx.x; i < 26 * 64; i += 256) sW[i] = W[i];
  if (threadIdx.x < 64) sb[threadIdx.x] = b[threadIdx.x];
  __syncthreads();
  int n = blockIdx.x * 256 + threadIdx.x;
  if (n >= N) return;
  float acc[64];
#pragma unroll
  for (int j = 0; j < 64; j++) acc[j] = sb[j];
#pragma unroll
  for (int k = 0; k < 26; k++) {
    float xk = x[(size_t)n * 26 + k];
    ROW_FMA(acc, xk, sW + k * 64);
  }
  float4* h4 = (float4*)(h + (size_t)n * 64);
#pragma unroll
  for (int j4 = 0; j4 < 16; j4++) {
    float4 v;
    v.x = acc[4 * j4 + 0]; v.y = acc[4 * j4 + 1]; v.z = acc[4 * j4 + 2]; v.w = acc[4 * j4 + 3];
    h4[j4] = v;
  }
}

// ---------------- tiled premul ----------------
#define NB 128
#define ASTR 132

__global__ __launch_bounds__(256) void premul_tiled_kernel(
    const float* __restrict__ h, const float* __restrict__ W1,
    float* __restrict__ P, float* __restrict__ Q, int N)
{
  __shared__ float sA[64 * ASTR];
  __shared__ float sW[64 * 64];
  int t = threadIdx.x;
  int n0 = blockIdx.x * NB;

#pragma unroll
  for (int it = 0; it < 8; it++) {
    int f = t + 256 * it;
    int nl = f >> 4;
    int k4 = f & 15;
    int n = n0 + nl;
    float4 v;
    if (n < N) v = ((const float4*)(h + (size_t)n * 64))[k4];
    else { v.x = v.y = v.z = v.w = 0.f; }
    sA[(4 * k4 + 0) * ASTR + nl] = v.x;
    sA[(4 * k4 + 1) * ASTR + nl] = v.y;
    sA[(4 * k4 + 2) * ASTR + nl] = v.z;
    sA[(4 * k4 + 3) * ASTR + nl] = v.w;
  }
  for (int i = t; i < 4096; i += 256) sW[i] = W1[i];
  __syncthreads();

  int rg = t & 31, cg = t >> 5;
  const float4* sA4 = (const float4*)sA;
  const float4* sW4 = (const float4*)sW;

  float aP[4][8];
#pragma unroll
  for (int i = 0; i < 4; i++)
#pragma unroll
    for (int j = 0; j < 8; j++) aP[i][j] = 0.f;
#pragma unroll 8
  for (int k = 0; k < 64; k++) {
    float4 a = sA4[k * (ASTR / 4) + rg];
    float4 w0 = sW4[k * 16 + 2 * cg];
    float4 w1 = sW4[k * 16 + 2 * cg + 1];
#pragma unroll
    for (int i = 0; i < 4; i++) {
      float av = (i == 0) ? a.x : (i == 1) ? a.y : (i == 2) ? a.z : a.w;
      aP[i][0] += av * w0.x; aP[i][1] += av * w0.y;
      aP[i][2] += av * w0.z; aP[i][3] += av * w0.w;
      aP[i][4] += av * w1.x; aP[i][5] += av * w1.y;
      aP[i][6] += av * w1.z; aP[i][7] += av * w1.w;
    }
  }
  __syncthreads();
  for (int i = t; i < 4096; i += 256) sW[i] = W1[4096 + i];
  __syncthreads();
  float aQ[4][8];
#pragma unroll
  for (int i = 0; i < 4; i++)
#pragma unroll
    for (int j = 0; j < 8; j++) aQ[i][j] = 0.f;
#pragma unroll 8
  for (int k = 0; k < 64; k++) {
    float4 a = sA4[k * (ASTR / 4) + rg];
    float4 w0 = sW4[k * 16 + 2 * cg];
    float4 w1 = sW4[k * 16 + 2 * cg + 1];
#pragma unroll
    for (int i = 0; i < 4; i++) {
      float av = (i == 0) ? a.x : (i == 1) ? a.y : (i == 2) ? a.z : a.w;
      aQ[i][0] += av * w0.x; aQ[i][1] += av * w0.y;
      aQ[i][2] += av * w0.z; aQ[i][3] += av * w0.w;
      aQ[i][4] += av * w1.x; aQ[i][5] += av * w1.y;
      aQ[i][6] += av * w1.z; aQ[i][7] += av * w1.w;
    }
  }
#pragma unroll
  for (int i = 0; i < 4; i++) {
    int n = n0 + 4 * rg + i;
    if (n < N) {
      float4 o0, o1;
      o0.x = aP[i][0]; o0.y = aP[i][1]; o0.z = aP[i][2]; o0.w = aP[i][3];
      o1.x = aP[i][4]; o1.y = aP[i][5]; o1.z = aP[i][6]; o1.w = aP[i][7];
      float4* Pp = (float4*)(P + (size_t)n * 64 + 8 * cg);
      Pp[0] = o0; Pp[1] = o1;
      o0.x = aQ[i][0]; o0.y = aQ[i][1]; o0.z = aQ[i][2]; o0.w = aQ[i][3];
      o1.x = aQ[i][4]; o1.y = aQ[i][5]; o1.z = aQ[i][6]; o1.w = aQ[i][7];
      float4* Qp = (float4*)(Q + (size_t)n * 64 + 8 * cg);
      Qp[0] = o0; Qp[1] = o1;
    }
  }
}

// ---------------- tiled node MLP ----------------
__global__ __launch_bounds__(256) void node_tiled_kernel(
    float* __restrict__ h, const float* __restrict__ agg,
    const float* __restrict__ W1, const float* __restrict__ b1,
    const float* __restrict__ W2, const float* __restrict__ b2, int N)
{
  __shared__ float sA[64 * ASTR];
  __shared__ float sW[64 * 64];
  __shared__ float sb1v[64], sb2v[64];
  int t = threadIdx.x;
  int n0 = blockIdx.x * NB;
  int rg = t & 31, cg = t >> 5;
  const float4* sA4 = (const float4*)sA;
  const float4* sW4 = (const float4*)sW;

#pragma unroll
  for (int it = 0; it < 8; it++) {
    int f = t + 256 * it;
    int nl = f >> 4;
    int k4 = f & 15;
    int n = n0 + nl;
    float4 v;
    if (n < N) v = ((const float4*)(h + (size_t)n * 64))[k4];
    else { v.x = v.y = v.z = v.w = 0.f; }
    sA[(4 * k4 + 0) * ASTR + nl] = v.x;
    sA[(4 * k4 + 1) * ASTR + nl] = v.y;
    sA[(4 * k4 + 2) * ASTR + nl] = v.z;
    sA[(4 * k4 + 3) * ASTR + nl] = v.w;
  }
  for (int i = t; i < 4096; i += 256) sW[i] = W1[i];
  if (t < 64) { sb1v[t] = b1[t]; sb2v[t] = b2[t]; }
  __syncthreads();

  float u[4][8];
#pragma unroll
  for (int i = 0; i < 4; i++)
#pragma unroll
    for (int j = 0; j < 8; j++) u[i][j] = 0.f;
#pragma unroll 8
  for (int k = 0; k < 64; k++) {
    float4 a = sA4[k * (ASTR / 4) + rg];
    float4 w0 = sW4[k * 16 + 2 * cg];
    float4 w1 = sW4[k * 16 + 2 * cg + 1];
#pragma unroll
    for (int i = 0; i < 4; i++) {
      float av = (i == 0) ? a.x : (i == 1) ? a.y : (i == 2) ? a.z : a.w;
      u[i][0] += av * w0.x; u[i][1] += av * w0.y;
      u[i][2] += av * w0.z; u[i][3] += av * w0.w;
      u[i][4] += av * w1.x; u[i][5] += av * w1.y;
      u[i][6] += av * w1.z; u[i][7] += av * w1.w;
    }
  }
  __syncthreads();

#pragma unroll
  for (int it = 0; it < 8; it++) {
    int f = t + 256 * it;
    int nl = f >> 4;
    int k4 = f & 15;
    int n = n0 + nl;
    float4 v;
    if (n < N) v = ((const float4*)(agg + (size_t)n * 64))[k4];
    else { v.x = v.y = v.z = v.w = 0.f; }
    sA[(4 * k4 + 0) * ASTR + nl] = v.x;
    sA[(4 * k4 + 1) * ASTR + nl] = v.y;
    sA[(4 * k4 + 2) * ASTR + nl] = v.z;
    sA[(4 * k4 + 3) * ASTR + nl] = v.w;
  }
  for (int i = t; i < 4096; i += 256) sW[i] = W1[4096 + i];
  __syncthreads();
#pragma unroll 8
  for (int k = 0; k < 64; k++) {
    float4 a = sA4[k * (ASTR / 4) + rg];
    float4 w0 = sW4[k * 16 + 2 * cg];
    float4 w1 = sW4[k * 16 + 2 * cg + 1];
#pragma unroll
    for (int i = 0; i < 4; i++) {
      float av = (i == 0) ? a.x : (i == 1) ? a.y : (i == 2) ? a.z : a.w;
      u[i][0] += av * w0.x; u[i][1] += av * w0.y;
      u[i][2] += av * w0.z; u[i][3] += av * w0.w;
      u[i][4] += av * w1.x; u[i][5] += av * w1.y;
      u[i][6] += av * w1.z; u[i][7] += av * w1.w;
    }
  }
#pragma unroll
  for (int i = 0; i < 4; i++)
#pragma unroll
    for (int j = 0; j < 8; j++) u[i][j] = silu_f(u[i][j] + sb1v[8 * cg + j]);
  __syncthreads();

#pragma unroll
  for (int j = 0; j < 8; j++)
#pragma unroll
    for (int i = 0; i < 4; i++) sA[(8 * cg + j) * ASTR + (4 * rg + i)] = u[i][j];
  for (int i = t; i < 4096; i += 256) sW[i] = W2[i];
  __syncthreads();

  float o[4][8];
#pragma unroll
  for (int i = 0; i < 4; i++)
#pragma unroll
    for (int j = 0; j < 8; j++) o[i][j] = 0.f;
#pragma unroll 8
  for (int k = 0; k < 64; k++) {
    float4 a = sA4[k * (ASTR / 4) + rg];
    float4 w0 = sW4[k * 16 + 2 * cg];
    float4 w1 = sW4[k * 16 + 2 * cg + 1];
#pragma unroll
    for (int i = 0; i < 4; i++) {
      float av = (i == 0) ? a.x : (i == 1) ? a.y : (i == 2) ? a.z : a.w;
      o[i][0] += av * w0.x; o[i][1] += av * w0.y;
      o[i][2] += av * w0.z; o[i][3] += av * w0.w;
      o[i][4] += av * w1.x; o[i][5] += av * w1.y;
      o[i][6] += av * w1.z; o[i][7] += av * w1.w;
    }
  }
#pragma unroll
  for (int i = 0; i < 4; i++) {
    int n = n0 + 4 * rg + i;
    if (n < N) {
      float4* hp = (float4*)(h + (size_t)n * 64 + 8 * cg);
      float4 h0 = hp[0], h1 = hp[1];
      h0.x += o[i][0] + sb2v[8 * cg + 0];
      h0.y += o[i][1] + sb2v[8 * cg + 1];
      h0.z += o[i][2] + sb2v[8 * cg + 2];
      h0.w += o[i][3] + sb2v[8 * cg + 3];
      h1.x += o[i][4] + sb2v[8 * cg + 4];
      h1.y += o[i][5] + sb2v[8 * cg + 5];
      h1.z += o[i][6] + sb2v[8 * cg + 6];
      h1.w += o[i][7] + sb2v[8 * cg + 7];
      hp[0] = h0; hp[1] = h1;
    }
  }
}

// ---------------- CSR build ----------------
__global__ __launch_bounds__(256) void hist_kernel(
    const int* __restrict__ row, int* __restrict__ cnt, int E)
{
  int e = blockIdx.x * 256 + threadIdx.x;
  if (e < E) atomicAdd(&cnt[row[e]], 1);
}

__global__ __launch_bounds__(1024) void scan_kernel(
    const int* __restrict__ cnt, int* __restrict__ rowptr, int* __restrict__ cursor, int N, int E)
{
  __shared__ int part[1024];
  int t = threadIdx.x;
  int chunk = (N + 1023) >> 10;
  int lo = t * chunk;
  int hi = lo + chunk;
  if (lo > N) lo = N;
  if (hi > N) hi = N;
  int s = 0;
  for (int i = lo; i < hi; i++) s += cnt[i];
  part[t] = s;
  __syncthreads();
  for (int off = 1; off < 1024; off <<= 1) {
    int v = 0;
    if (t >= off) v = part[t - off];
    __syncthreads();
    if (t >= off) part[t] += v;
    __syncthreads();
  }
  int run = part[t] - s;
  for (int i = lo; i < hi; i++) {
    rowptr[i] = run;
    cursor[i] = run;
    run += cnt[i];
  }
  if (t == 0) rowptr[N] = E;
}

__global__ __launch_bounds__(256) void scatter_kernel(
    const int* __restrict__ row, const int* __restrict__ col, const float* __restrict__ eattr,
    int* __restrict__ cursor, int* __restrict__ srow, int* __restrict__ scol,
    float* __restrict__ sea4, int E)
{
  int e = blockIdx.x * 256 + threadIdx.x;
  if (e >= E) return;
  int r = row[e];
  int p = atomicAdd(&cursor[r], 1);
  srow[p] = r;
  scol[p] = col[e];
  float4 v;
  v.x = eattr[(size_t)e * 3 + 0];
  v.y = eattr[(size_t)e * 3 + 1];
  v.z = eattr[(size_t)e * 3 + 2];
  v.w = 0.f;
  ((float4*)sea4)[p] = v;
}

// ---------------- weight prep: bf16 hi/lo of W^T ----------------
__global__ __launch_bounds__(256) void prep_wt_kernel(
    const float* __restrict__ W2all, const float* __restrict__ C1all,
    ushort* __restrict__ w2h, ushort* __restrict__ w2l,
    ushort* __restrict__ c1h, ushort* __restrict__ c1l)
{
  int idx = blockIdx.x * 256 + threadIdx.x;
  if (idx >= 4 * 4096) return;
  int layer = idx >> 12, rem = idx & 4095;
  int k = rem >> 6, c = rem & 63;
  int oidx = layer * 4096 + c * 64 + k;
  ushort h, l;
  bf16_split(W2all[idx], h, l);
  w2h[oidx] = h; w2l[oidx] = l;
  if (layer < 3) {
    bf16_split(C1all[idx], h, l);
    c1h[oidx] = h; c1l[oidx] = l;
  }
}

// ---------------- fused edge kernel (MFMA) ----------------
#define EB 128

__device__ __forceinline__ bshort8 lds_frag(const ushort* base, int edge, int kb)
{
  int byte = edge * 128 + kb * 2;
  byte ^= (edge & 7) << 4;
  return *(const bshort8*)((const char*)base + byte);
}

template <int COORD>
__global__ __launch_bounds__(256) void edge_fused_kernel(
    const int* __restrict__ srow, const int* __restrict__ scol, const int* __restrict__ rowptr,
    const float* __restrict__ posr, float* __restrict__ posw,
    const float* __restrict__ sea4,
    const float* __restrict__ P, const float* __restrict__ Q,
    const float* __restrict__ W1t, const float* __restrict__ b1,
    const ushort* __restrict__ w2h, const ushort* __restrict__ w2l,
    const float* __restrict__ b2,
    const ushort* __restrict__ c1h, const ushort* __restrict__ c1l,
    const float* __restrict__ cb1, const float* __restrict__ cW2,
    const float* __restrict__ cb2,
    float* __restrict__ agg, int E)
{
  __shared__ ushort sUhi[EB * 64];  // [edge][k] bf16 hi, XOR-swizzled rows
  __shared__ ushort sUlo[EB * 64];
  __shared__ float sW1t[4 * 64];
  __shared__ float sb1v[64], sb2v[64];
  __shared__ float sDiff[3][EB];
  __shared__ float sWe[EB];
  // sShare: first life = s_srow[EB] (stage1..phaseB), second life = sPart (stage3)
  __shared__ int sShare[COORD ? EB * 4 : EB];
  __shared__ float scb1v[COORD ? 64 : 1];
  __shared__ float scW2v[COORD ? 64 : 1];
  __shared__ int sSlotCnt[2];
  __shared__ int sSlotStart[EB + 2];
  __shared__ int sSlotRowF[EB];  // row | (interior<<30)

  int* s_srow = sShare;
  float* sPart = (float*)sShare;

  int t = threadIdx.x;
  sW1t[t] = W1t[t];
  if (t < 64) { sb1v[t] = b1[t]; sb2v[t] = b2[t]; }
  if (COORD && t >= 64 && t < 128) { scb1v[t - 64] = cb1[t - 64]; scW2v[t - 64] = cW2[t - 64]; }
  __syncthreads();

  int e0 = blockIdx.x * EB;
  int nE = E - e0; if (nE > EB) nE = EB;

  // ---- stage 1: u tile -> bf16 hi/lo, conflict-free b128 writes ----
  // 8 lanes per edge (k-octets), 32 edges per pass, 4 passes.
#pragma unroll
  for (int p = 0; p < 4; p++) {
    int eloc = p * 32 + (t >> 3);
    int ks = t & 7;
    int e = e0 + eloc;
    int base = eloc * 128 + ks * 16;
    int swz = (eloc & 7) << 4;
    if (e < E) {
      int r = srow[e];
      int c = scol[e];
      float prx = posr[(size_t)r * 3 + 0], pry = posr[(size_t)r * 3 + 1],
            prz = posr[(size_t)r * 3 + 2];
      float pcx = posr[(size_t)c * 3 + 0], pcy = posr[(size_t)c * 3 + 1],
            pcz = posr[(size_t)c * 3 + 2];
      float dx = prx - pcx, dy = pry - pcy, dz = prz - pcz;
      float dist = sqrtf(dx * dx + dy * dy + dz * dz);
      if (ks == 0) {
        s_srow[eloc] = r;
        sDiff[0][eloc] = dx; sDiff[1][eloc] = dy; sDiff[2][eloc] = dz;
      }
      float4 ea = ((const float4*)sea4)[e];
      const float4* P4p = (const float4*)(P + (size_t)r * 64) + ks * 2;
      const float4* Q4p = (const float4*)(Q + (size_t)c * 64) + ks * 2;
      float4 a0 = P4p[0], a1 = P4p[1];
      float4 q0 = Q4p[0], q1 = Q4p[1];
      float pa[8] = {a0.x, a0.y, a0.z, a0.w, a1.x, a1.y, a1.z, a1.w};
      float qa[8] = {q0.x, q0.y, q0.z, q0.w, q1.x, q1.y, q1.z, q1.w};
      ushort hh[8], ll[8];
#pragma unroll
      for (int kk = 0; kk < 8; kk++) {
        int k = ks * 8 + kk;
        float val = pa[kk] + qa[kk] + sb1v[k] + dist * sW1t[k] + ea.x * sW1t[64 + k] +
                    ea.y * sW1t[128 + k] + ea.z * sW1t[192 + k];
        float uv = silu_f(val);
        bf16_split(uv, hh[kk], ll[kk]);
      }
      uint4 hv, lv;
      hv.x = (uint)hh[0] | ((uint)hh[1] << 16);
      hv.y = (uint)hh[2] | ((uint)hh[3] << 16);
      hv.z = (uint)hh[4] | ((uint)hh[5] << 16);
      hv.w = (uint)hh[6] | ((uint)hh[7] << 16);
      lv.x = (uint)ll[0] | ((uint)ll[1] << 16);
      lv.y = (uint)ll[2] | ((uint)ll[3] << 16);
      lv.z = (uint)ll[4] | ((uint)ll[5] << 16);
      lv.w = (uint)ll[6] | ((uint)ll[7] << 16);
      *(uint4*)((char*)sUhi + (base ^ swz)) = hv;
      *(uint4*)((char*)sUlo + (base ^ swz)) = lv;
    } else {
      uint4 z; z.x = 0; z.y = 0; z.z = 0; z.w = 0;
      *(uint4*)((char*)sUhi + (base ^ swz)) = z;
      *(uint4*)((char*)sUlo + (base ^ swz)) = z;
    }
  }
  __syncthreads();

  // ---- phase A: slot ballot (waves 0,1 cover edges 0..127) ----
  bool isstart = false;
  int pre = 0;
  if (t < 128) {
    int le = t;
    isstart = (le < nE) && (le == 0 || s_srow[le] != s_srow[le - 1]);
    unsigned long long m = __ballot(isstart ? 1 : 0);
    int lane = t & 63;
    pre = __popcll(m & ((lane == 0) ? 0ull : ((~0ull) >> (64 - lane))));
    if (lane == 0) sSlotCnt[t >> 6] = __popcll(m);
  }
  __syncthreads();
  // ---- phase B: slot tables (rowptr prefetch hidden under stage 2) ----
  if (t < 128 && isstart) {
    int le = t;
    int slot = ((t >> 6) ? sSlotCnt[0] : 0) + pre;
    int row = s_srow[le];
    sSlotStart[slot] = le;
    int rs = rowptr[row], re = rowptr[row + 1];
    int interior = (rs >= e0 && re <= e0 + nE) ? 1 : 0;
    sSlotRowF[slot] = row | (interior << 30);
  }
  if (t == 0) sSlotStart[sSlotCnt[0] + sSlotCnt[1]] = nE;
  // published by stage-2's internal barrier

  // ---- stage 2: m = silu(u @ W2 + b2) via MFMA bf16 3-split ----
  int l = t & 63;
  int wv = t >> 6;
  int colh = l & 15;
  int col = wv * 16 + colh;
  int kq = l >> 4;  // 0..3

  {
    const ushort* bhp = w2h + col * 64 + kq * 8;
    const ushort* blp = w2l + col * 64 + kq * 8;
    bshort8 bh0 = *(const bshort8*)(bhp);
    bshort8 bh1 = *(const bshort8*)(bhp + 32);
    bshort8 bl0 = *(const bshort8*)(blp);
    bshort8 bl1 = *(const bshort8*)(blp + 32);

    f32x4 acc[8];
#pragma unroll
    for (int et = 0; et < 8; et++) {
      int edge = et * 16 + colh;
      bshort8 ah0 = lds_frag(sUhi, edge, kq * 8);
      bshort8 ah1 = lds_frag(sUhi, edge, 32 + kq * 8);
      bshort8 al0 = lds_frag(sUlo, edge, kq * 8);
      bshort8 al1 = lds_frag(sUlo, edge, 32 + kq * 8);
      f32x4 a = {0.f, 0.f, 0.f, 0.f};
      a = __builtin_amdgcn_mfma_f32_16x16x32_bf16(ah0, bh0, a, 0, 0, 0);
      a = __builtin_amdgcn_mfma_f32_16x16x32_bf16(ah1, bh1, a, 0, 0, 0);
      a = __builtin_amdgcn_mfma_f32_16x16x32_bf16(ah0, bl0, a, 0, 0, 0);
      a = __builtin_amdgcn_mfma_f32_16x16x32_bf16(ah1, bl1, a, 0, 0, 0);
      a = __builtin_amdgcn_mfma_f32_16x16x32_bf16(al0, bh0, a, 0, 0, 0);
      a = __builtin_amdgcn_mfma_f32_16x16x32_bf16(al1, bh1, a, 0, 0, 0);
      acc[et] = a;
    }
    __syncthreads();  // sU reads done; also publishes slot tables

    float b2c = sb2v[col];
#pragma unroll
    for (int et = 0; et < 8; et++) {
#pragma unroll
      for (int r = 0; r < 4; r++) {
        int edge = et * 16 + kq * 4 + r;  // C/D: row=(lane>>4)*4+reg
        float mv = silu_f(acc[et][r] + b2c);
        ushort mh, ml;
        bf16_split(mv, mh, ml);
        int byte = (edge * 128 + col * 2) ^ ((edge & 7) << 4);
        *(ushort*)((char*)sUhi + byte) = mh;
        *(ushort*)((char*)sUlo + byte) = ml;
      }
    }
  }
  __syncthreads();

  // ---- stage 3 (COORD): w_e = silu(m @ cW1 + cb1) . cW2 + cb2 ----
  if (COORD) {
    const ushort* bhp = c1h + col * 64 + kq * 8;
    const ushort* blp = c1l + col * 64 + kq * 8;
    bshort8 bh0 = *(const bshort8*)(bhp);
    bshort8 bh1 = *(const bshort8*)(bhp + 32);
    bshort8 bl0 = *(const bshort8*)(blp);
    bshort8 bl1 = *(const bshort8*)(blp + 32);
    float cb1c = scb1v[col];
    float cw2c = scW2v[col];
#pragma unroll
    for (int et = 0; et < 8; et++) {
      int edge = et * 16 + colh;
      bshort8 ah0 = lds_frag(sUhi, edge, kq * 8);
      bshort8 ah1 = lds_frag(sUhi, edge, 32 + kq * 8);
      bshort8 al0 = lds_frag(sUlo, edge, kq * 8);
      bshort8 al1 = lds_frag(sUlo, edge, 32 + kq * 8);
      f32x4 a = {0.f, 0.f, 0.f, 0.f};
      a = __builtin_amdgcn_mfma_f32_16x16x32_bf16(ah0, bh0, a, 0, 0, 0);
      a = __builtin_amdgcn_mfma_f32_16x16x32_bf16(ah1, bh1, a, 0, 0, 0);
      a = __builtin_amdgcn_mfma_f32_16x16x32_bf16(ah0, bl0, a, 0, 0, 0);
      a = __builtin_amdgcn_mfma_f32_16x16x32_bf16(ah1, bl1, a, 0, 0, 0);
      a = __builtin_amdgcn_mfma_f32_16x16x32_bf16(al0, bh0, a, 0, 0, 0);
      a = __builtin_amdgcn_mfma_f32_16x16x32_bf16(al1, bh1, a, 0, 0, 0);
#pragma unroll
      for (int r = 0; r < 4; r++) {
        float pr = silu_f(a[r] + cb1c) * cw2c;
        pr += __shfl_xor(pr, 1);
        pr += __shfl_xor(pr, 2);
        pr += __shfl_xor(pr, 4);
        pr += __shfl_xor(pr, 8);
        if (colh == 0) sPart[(et * 16 + kq * 4 + r) * 4 + wv] = __float_as_int(pr) * 0 + 0,  // placeholder avoided
        ((float*)sPart)[(et * 16 + kq * 4 + r) * 4 + wv] = pr;
      }
    }
  }
  __syncthreads();
  if (COORD) {
    if (t >= 128) {
      int e = t - 128;
      sWe[e] = sPart[4 * e + 0] + sPart[4 * e + 1] + sPart[4 * e + 2] + sPart[4 * e + 3] + cb2[0];
    }
  }
  __syncthreads();

  // ---- stage 4: slot-based segmented reductions ----
  int nslots = sSlotCnt[0] + sSlotCnt[1];
  for (int task = t; task < (nslots << 5); task += 256) {
    int s = task >> 5, cp = task & 31;  // channel pair 2cp, 2cp+1
    int a = sSlotStart[s], b = sSlotStart[s + 1];
    float acc0 = 0.f, acc1 = 0.f;
    for (int le = a; le < b; le++) {
      int byte = (le * 128 + cp * 4) ^ ((le & 7) << 4);
      uint hv = *(const uint*)((const char*)sUhi + byte);
      uint lv = *(const uint*)((const char*)sUlo + byte);
      acc0 += __uint_as_float(hv << 16) + __uint_as_float(lv << 16);
      acc1 += __uint_as_float(hv & 0xffff0000u) + __uint_as_float(lv & 0xffff0000u);
    }
    int rowf = sSlotRowF[s];
    int row = rowf & 0x3fffffff;
    float* ap = agg + (size_t)row * 64 + 2 * cp;
    if (rowf & (1 << 30)) {
      ap[0] = acc0; ap[1] = acc1;
    } else {
      atomicAdd(ap, acc0);
      atomicAdd(ap + 1, acc1);
    }
  }
  if (COORD) {
    for (int task = t; task < (nslots << 2); task += 256) {
      int s = task >> 2, d = task & 3;
      if (d < 3) {
        int a = sSlotStart[s], b = sSlotStart[s + 1];
        float acc = 0.f;
        for (int le = a; le < b; le++) acc += sDiff[d][le] * sWe[le];
        int row = sSlotRowF[s] & 0x3fffffff;
        atomicAdd(&posw[(size_t)row * 3 + d], acc);
      }
    }
  }
}

// ---------------- pooling + classifier ----------------
__device__ __forceinline__ int lbound(const int* __restrict__ a, int n, int v)
{
  int lo = 0, hi = n;
  while (lo < hi) {
    int mid = (lo + hi) >> 1;
    if (a[mid] < v) lo = mid + 1;
    else hi = mid;
  }
  return lo;
}

__global__ __launch_bounds__(256) void pool_cls_kernel(
    const float* __restrict__ h, const int* __restrict__ batch, int N,
    const float* __restrict__ W1, const float* __restrict__ b1,
    const float* __restrict__ W2, const float* __restrict__ b2, float* __restrict__ out)
{
  int g = blockIdx.x;
  int start = lbound(batch, N, g);
  int end = lbound(batch, N, g + 1);
  int j = threadIdx.x & 63;
  int grp = threadIdx.x >> 6;
  float s = 0.f, mx = -INFINITY;
  for (int n = start + grp; n < end; n += 4) {
    float v = h[(size_t)n * 64 + j];
    s += v;
    mx = fmaxf(mx, v);
  }
  __shared__ float ssum[4][64];
  __shared__ float smax[4][64];
  __shared__ float pooled[128];
  __shared__ float su[64];
  ssum[grp][j] = s;
  smax[grp][j] = mx;
  __syncthreads();
  if (grp == 0) {
    float S = ssum[0][j] + ssum[1][j] + ssum[2][j] + ssum[3][j];
    float M = fmaxf(fmaxf(smax[0][j], smax[1][j]), fmaxf(smax[2][j], smax[3][j]));
    float cnt = (float)(end - start);
    pooled[j] = S / fmaxf(cnt, 1.0f);
    pooled[64 + j] = M;
  }
  __syncthreads();
  if (threadIdx.x < 64) {
    float a = b1[j];
#pragma unroll
    for (int k = 0; k < 128; k++) a += pooled[k] * W1[k * 64 + j];
    su[j] = fmaxf(a, 0.f);
  }
  __syncthreads();
  if (threadIdx.x < 2) {
    float a = b2[threadIdx.x];
#pragma unroll
    for (int k = 0; k < 64; k++) a += su[k] * W2[k * 2 + threadIdx.x];
    out[g * 2 + threadIdx.x] = a;
  }
}

extern "C" void kernel_launch(void* const* d_in, const int* in_sizes, int n_in,
                              void* d_out, int out_size, void* d_ws, size_t ws_size,
                              hipStream_t stream)
{
  const float* x = (const float*)d_in[0];
  const float* pos = (const float*)d_in[1];
  const int* ei = (const int*)d_in[2];
  const float* eattr = (const float*)d_in[3];
  const int* batch = (const int*)d_in[4];
  const float* projW = (const float*)d_in[5];
  const float* projb = (const float*)d_in[6];
  const float* msgW1 = (const float*)d_in[7];
  const float* msgb1 = (const float*)d_in[8];
  const float* msgW2 = (const float*)d_in[9];
  const float* msgb2 = (const float*)d_in[10];
  const float* ndW1 = (const float*)d_in[11];
  const float* ndb1 = (const float*)d_in[12];
  const float* ndW2 = (const float*)d_in[13];
  const float* ndb2 = (const float*)d_in[14];
  const float* cdW1 = (const float*)d_in[15];
  const float* cdb1 = (const float*)d_in[16];
  const float* cdW2 = (const float*)d_in[17];
  const float* cdb2 = (const float*)d_in[18];
  const float* clsW1 = (const float*)d_in[19];
  const float* clsb1 = (const float*)d_in[20];
  const float* clsW2 = (const float*)d_in[21];
  const float* clsb2 = (const float*)d_in[22];

  int N = in_sizes[4];
  int E = in_sizes[3] / 3;
  const int* rowp = ei;
  const int* colp = ei + E;

  char* wsb = (char*)d_ws;
  size_t off = 0;
  auto alloc = [&](size_t bytes) {
    size_t o = off;
    off = (off + bytes + 255) & ~(size_t)255;
    return o;
  };
  size_t nh = (size_t)N * 64 * sizeof(float);
  size_t o_h = alloc(nh);
  size_t o_P = alloc(nh);
  size_t o_Q = alloc(nh);
  size_t o_agg = alloc(nh);
  size_t o_posA = alloc((size_t)N * 3 * sizeof(float));
  size_t o_posB = alloc((size_t)N * 3 * sizeof(float));
  size_t o_cnt = alloc((size_t)N * sizeof(int));
  size_t o_rowptr = alloc(((size_t)N + 1) * sizeof(int));
  size_t o_cursor = alloc((size_t)N * sizeof(int));
  size_t o_srow = alloc((size_t)E * sizeof(int));
  size_t o_scol = alloc((size_t)E * sizeof(int));
  size_t o_sea4 = alloc((size_t)E * 4 * sizeof(float));
  size_t o_w2h = alloc(4 * 4096 * sizeof(ushort));
  size_t o_w2l = alloc(4 * 4096 * sizeof(ushort));
  size_t o_c1h = alloc(4 * 4096 * sizeof(ushort));
  size_t o_c1l = alloc(4 * 4096 * sizeof(ushort));
  size_t csr_end = off;

  float* h = (float*)(wsb + o_h);
  float* Pb = (float*)(wsb + o_P);
  float* Qb = (float*)(wsb + o_Q);
  float* agg = (float*)(wsb + o_agg);
  float* posA = (float*)(wsb + o_posA);
  float* posB = (float*)(wsb + o_posB);

  int nb_nodes = (N + 255) / 256;
  int nb_edges = (E + 255) / 256;
  int nb_tiled = (N + NB - 1) / NB;
  int G = out_size / 2;

  proj_kernel<<<nb_nodes, 256, 0, stream>>>(x, projW, projb, h, N);

  const float* pr[4] = {pos, posA, posB, posA};
  float* pw[4] = {posA, posB, posA, nullptr};

  bool use_sorted = (csr_end <= ws_size);

  if (use_sorted) {
    int* cnt = (int*)(wsb + o_cnt);
    int* rowptr = (int*)(wsb + o_rowptr);
    int* cursor = (int*)(wsb + o_cursor);
    int* srow = (int*)(wsb + o_srow);
    int* scol = (int*)(wsb + o_scol);
    float* sea4 = (float*)(wsb + o_sea4);
    ushort* w2h = (ushort*)(wsb + o_w2h);
    ushort* w2l = (ushort*)(wsb + o_w2l);
    ushort* c1h = (ushort*)(wsb + o_c1h);
    ushort* c1l = (ushort*)(wsb + o_c1l);

    hipMemsetAsync(cnt, 0, (size_t)N * sizeof(int), stream);
    hist_kernel<<<nb_edges, 256, 0, stream>>>(rowp, cnt, E);
    scan_kernel<<<1, 1024, 0, stream>>>(cnt, rowptr, cursor, N, E);
    scatter_kernel<<<nb_edges, 256, 0, stream>>>(rowp, colp, eattr, cursor, srow, scol, sea4, E);
    prep_wt_kernel<<<64, 256, 0, stream>>>(msgW2, cdW1, w2h, w2l, c1h, c1l);

    int nb_fused = (E + EB - 1) / EB;
    for (int i = 0; i < 4; i++) {
      premul_tiled_kernel<<<nb_tiled, 256, 0, stream>>>(h, msgW1 + (size_t)i * 132 * 64, Pb, Qb,
                                                        N);
      hipMemsetAsync(agg, 0, nh, stream);
      if (i < 3) {
        hipMemcpyAsync(pw[i], pr[i], (size_t)N * 3 * sizeof(float), hipMemcpyDeviceToDevice,
                       stream);
        edge_fused_kernel<1><<<nb_fused, 256, 0, stream>>>(
            srow, scol, rowptr, pr[i], pw[i], sea4, Pb, Qb,
            msgW1 + (size_t)i * 132 * 64 + 128 * 64, msgb1 + i * 64,
            w2h + (size_t)i * 4096, w2l + (size_t)i * 4096, msgb2 + i * 64,
            c1h + (size_t)i * 4096, c1l + (size_t)i * 4096,
            cdb1 + i * 64, cdW2 + i * 64, cdb2 + i, agg, E);
      } else {
        edge_fused_kernel<0><<<nb_fused, 256, 0, stream>>>(
            srow, scol, rowptr, pr[i], nullptr, sea4, Pb, Qb,
            msgW1 + (size_t)i * 132 * 64 + 128 * 64, msgb1 + i * 64,
            w2h + (size_t)i * 4096, w2l + (size_t)i * 4096, msgb2 + i * 64,
            nullptr, nullptr, nullptr, nullptr, nullptr, agg, E);
      }
      node_tiled_kernel<<<nb_tiled, 256, 0, stream>>>(
          h, agg, ndW1 + (size_t)i * 8192, ndb1 + i * 64, ndW2 + (size_t)i * 4096, ndb2 + i * 64,
          N);
    }
  } else {
    for (int i = 0; i < 4; i++) {
      premul_tiled_kernel<<<nb_tiled, 256, 0, stream>>>(h, msgW1 + (size_t)i * 132 * 64, Pb, Qb,
                                                        N);
      hipMemsetAsync(agg, 0, nh, stream);
      node_tiled_kernel<<<nb_tiled, 256, 0, stream>>>(
          h, agg, ndW1 + (size_t)i * 8192, ndb1 + i * 64, ndW2 + (size_t)i * 4096, ndb2 + i * 64,
          N);
    }
  }

  pool_cls_kernel<<<G, 256, 0, stream>>>(h, batch, N, clsW1, clsb1, clsW2, clsb2, (float*)d_out);
}

// Round 12
// 1032.113 us; speedup vs baseline: 13.7517x; 1.0567x over previous
//
#include <hip/hip_runtime.h>
#include <math.h>

// EGNN forward. P/Q factorization + CSR sort + fused MFMA edge kernel.
// Round 12: operand-swapped MFMA (compute m^T) -> packed b64 m-writeback;
// stage-3 in-thread reduce (2 shfl) with m-hi-only A (4 MFMA);
// premul fused into node_tiled for layers 1-3.

typedef __attribute__((ext_vector_type(8))) short bshort8;
typedef __attribute__((ext_vector_type(4))) float f32x4;
typedef unsigned short ushort;
typedef unsigned int uint;

__device__ __forceinline__ float silu_f(float x) { return x / (1.0f + __expf(-x)); }

__device__ __forceinline__ void bf16_split(float x, ushort& h, ushort& l)
{
  uint bx = __float_as_uint(x);
  ushort hb = (ushort)(bx >> 16);
  float hf = __uint_as_float((uint)hb << 16);
  float r = x - hf;
  l = (ushort)(__float_as_uint(r) >> 16);
  h = hb;
}

#define ROW_FMA(acc, scal, rowptr)                                                   \
  {                                                                                  \
    const float4* _w = (const float4*)(rowptr);                                      \
    _Pragma("unroll") for (int _j = 0; _j < 16; _j++)                                \
    {                                                                                \
      float4 _wv = _w[_j];                                                           \
      acc[4 * _j + 0] += (scal) * _wv.x;                                             \
      acc[4 * _j + 1] += (scal) * _wv.y;                                             \
      acc[4 * _j + 2] += (scal) * _wv.z;                                             \
      acc[4 * _j + 3] += (scal) * _wv.w;                                             \
    }                                                                                \
  }

// ---------------- proj ----------------
__global__ __launch_bounds__(256) void proj_kernel(
    const float* __restrict__ x, const float* __restrict__ W, const float* __restrict__ b,
    float* __restrict__ h, int N)
{
  __shared__ float sW[26 * 64];
  __shared__ float sb[64];
  for (int i = threadIdx.x; i < 26 * 64; i += 256) sW[i] = W[i];
  if (threadIdx.x < 64) sb[threadIdx.x] = b[threadIdx.x];
  __syncthreads();
  int n = blockIdx.x * 256 + threadIdx.x;
  if (n >= N) return;
  float acc[64];
#pragma unroll
  for (int j = 0; j < 64; j++) acc[j] = sb[j];
#pragma unroll
  for (int k = 0; k < 26; k++) {
    float xk = x[(size_t)n * 26 + k];
    ROW_FMA(acc, xk, sW + k * 64);
  }
  float4* h4 = (float4*)(h + (size_t)n * 64);
#pragma unroll
  for (int j4 = 0; j4 < 16; j4++) {
    float4 v;
    v.x = acc[4 * j4 + 0]; v.y = acc[4 * j4 + 1]; v.z = acc[4 * j4 + 2]; v.w = acc[4 * j4 + 3];
    h4[j4] = v;
  }
}

// ---------------- tiled premul (layer 0 only) ----------------
#define NB 128
#define ASTR 132

__global__ __launch_bounds__(256) void premul_tiled_kernel(
    const float* __restrict__ h, const float* __restrict__ W1,
    float* __restrict__ P, float* __restrict__ Q, int N)
{
  __shared__ float sA[64 * ASTR];
  __shared__ float sW[64 * 64];
  int t = threadIdx.x;
  int n0 = blockIdx.x * NB;

#pragma unroll
  for (int it = 0; it < 8; it++) {
    int f = t + 256 * it;
    int nl = f >> 4;
    int k4 = f & 15;
    int n = n0 + nl;
    float4 v;
    if (n < N) v = ((const float4*)(h + (size_t)n * 64))[k4];
    else { v.x = v.y = v.z = v.w = 0.f; }
    sA[(4 * k4 + 0) * ASTR + nl] = v.x;
    sA[(4 * k4 + 1) * ASTR + nl] = v.y;
    sA[(4 * k4 + 2) * ASTR + nl] = v.z;
    sA[(4 * k4 + 3) * ASTR + nl] = v.w;
  }
  for (int i = t; i < 4096; i += 256) sW[i] = W1[i];
  __syncthreads();

  int rg = t & 31, cg = t >> 5;
  const float4* sA4 = (const float4*)sA;
  const float4* sW4 = (const float4*)sW;

  float aP[4][8];
#pragma unroll
  for (int i = 0; i < 4; i++)
#pragma unroll
    for (int j = 0; j < 8; j++) aP[i][j] = 0.f;
#pragma unroll 8
  for (int k = 0; k < 64; k++) {
    float4 a = sA4[k * (ASTR / 4) + rg];
    float4 w0 = sW4[k * 16 + 2 * cg];
    float4 w1 = sW4[k * 16 + 2 * cg + 1];
#pragma unroll
    for (int i = 0; i < 4; i++) {
      float av = (i == 0) ? a.x : (i == 1) ? a.y : (i == 2) ? a.z : a.w;
      aP[i][0] += av * w0.x; aP[i][1] += av * w0.y;
      aP[i][2] += av * w0.z; aP[i][3] += av * w0.w;
      aP[i][4] += av * w1.x; aP[i][5] += av * w1.y;
      aP[i][6] += av * w1.z; aP[i][7] += av * w1.w;
    }
  }
  __syncthreads();
  for (int i = t; i < 4096; i += 256) sW[i] = W1[4096 + i];
  __syncthreads();
  float aQ[4][8];
#pragma unroll
  for (int i = 0; i < 4; i++)
#pragma unroll
    for (int j = 0; j < 8; j++) aQ[i][j] = 0.f;
#pragma unroll 8
  for (int k = 0; k < 64; k++) {
    float4 a = sA4[k * (ASTR / 4) + rg];
    float4 w0 = sW4[k * 16 + 2 * cg];
    float4 w1 = sW4[k * 16 + 2 * cg + 1];
#pragma unroll
    for (int i = 0; i < 4; i++) {
      float av = (i == 0) ? a.x : (i == 1) ? a.y : (i == 2) ? a.z : a.w;
      aQ[i][0] += av * w0.x; aQ[i][1] += av * w0.y;
      aQ[i][2] += av * w0.z; aQ[i][3] += av * w0.w;
      aQ[i][4] += av * w1.x; aQ[i][5] += av * w1.y;
      aQ[i][6] += av * w1.z; aQ[i][7] += av * w1.w;
    }
  }
#pragma unroll
  for (int i = 0; i < 4; i++) {
    int n = n0 + 4 * rg + i;
    if (n < N) {
      float4 o0, o1;
      o0.x = aP[i][0]; o0.y = aP[i][1]; o0.z = aP[i][2]; o0.w = aP[i][3];
      o1.x = aP[i][4]; o1.y = aP[i][5]; o1.z = aP[i][6]; o1.w = aP[i][7];
      float4* Pp = (float4*)(P + (size_t)n * 64 + 8 * cg);
      Pp[0] = o0; Pp[1] = o1;
      o0.x = aQ[i][0]; o0.y = aQ[i][1]; o0.z = aQ[i][2]; o0.w = aQ[i][3];
      o1.x = aQ[i][4]; o1.y = aQ[i][5]; o1.z = aQ[i][6]; o1.w = aQ[i][7];
      float4* Qp = (float4*)(Q + (size_t)n * 64 + 8 * cg);
      Qp[0] = o0; Qp[1] = o1;
    }
  }
}

// ---------------- tiled node MLP (+fused premul for next layer) ----------------
template <int PREMUL>
__global__ __launch_bounds__(256) void node_tiled_kernel(
    float* __restrict__ h, const float* __restrict__ agg,
    const float* __restrict__ W1, const float* __restrict__ b1,
    const float* __restrict__ W2, const float* __restrict__ b2, int N,
    const float* __restrict__ W1n, float* __restrict__ P, float* __restrict__ Q)
{
  __shared__ float sA[64 * ASTR];
  __shared__ float sW[64 * 64];
  __shared__ float sb1v[64], sb2v[64];
  int t = threadIdx.x;
  int n0 = blockIdx.x * NB;
  int rg = t & 31, cg = t >> 5;
  const float4* sA4 = (const float4*)sA;
  const float4* sW4 = (const float4*)sW;

#pragma unroll
  for (int it = 0; it < 8; it++) {
    int f = t + 256 * it;
    int nl = f >> 4;
    int k4 = f & 15;
    int n = n0 + nl;
    float4 v;
    if (n < N) v = ((const float4*)(h + (size_t)n * 64))[k4];
    else { v.x = v.y = v.z = v.w = 0.f; }
    sA[(4 * k4 + 0) * ASTR + nl] = v.x;
    sA[(4 * k4 + 1) * ASTR + nl] = v.y;
    sA[(4 * k4 + 2) * ASTR + nl] = v.z;
    sA[(4 * k4 + 3) * ASTR + nl] = v.w;
  }
  for (int i = t; i < 4096; i += 256) sW[i] = W1[i];
  if (t < 64) { sb1v[t] = b1[t]; sb2v[t] = b2[t]; }
  __syncthreads();

  float u[4][8];
#pragma unroll
  for (int i = 0; i < 4; i++)
#pragma unroll
    for (int j = 0; j < 8; j++) u[i][j] = 0.f;
#pragma unroll 8
  for (int k = 0; k < 64; k++) {
    float4 a = sA4[k * (ASTR / 4) + rg];
    float4 w0 = sW4[k * 16 + 2 * cg];
    float4 w1 = sW4[k * 16 + 2 * cg + 1];
#pragma unroll
    for (int i = 0; i < 4; i++) {
      float av = (i == 0) ? a.x : (i == 1) ? a.y : (i == 2) ? a.z : a.w;
      u[i][0] += av * w0.x; u[i][1] += av * w0.y;
      u[i][2] += av * w0.z; u[i][3] += av * w0.w;
      u[i][4] += av * w1.x; u[i][5] += av * w1.y;
      u[i][6] += av * w1.z; u[i][7] += av * w1.w;
    }
  }
  __syncthreads();

#pragma unroll
  for (int it = 0; it < 8; it++) {
    int f = t + 256 * it;
    int nl = f >> 4;
    int k4 = f & 15;
    int n = n0 + nl;
    float4 v;
    if (n < N) v = ((const float4*)(agg + (size_t)n * 64))[k4];
    else { v.x = v.y = v.z = v.w = 0.f; }
    sA[(4 * k4 + 0) * ASTR + nl] = v.x;
    sA[(4 * k4 + 1) * ASTR + nl] = v.y;
    sA[(4 * k4 + 2) * ASTR + nl] = v.z;
    sA[(4 * k4 + 3) * ASTR + nl] = v.w;
  }
  for (int i = t; i < 4096; i += 256) sW[i] = W1[4096 + i];
  __syncthreads();
#pragma unroll 8
  for (int k = 0; k < 64; k++) {
    float4 a = sA4[k * (ASTR / 4) + rg];
    float4 w0 = sW4[k * 16 + 2 * cg];
    float4 w1 = sW4[k * 16 + 2 * cg + 1];
#pragma unroll
    for (int i = 0; i < 4; i++) {
      float av = (i == 0) ? a.x : (i == 1) ? a.y : (i == 2) ? a.z : a.w;
      u[i][0] += av * w0.x; u[i][1] += av * w0.y;
      u[i][2] += av * w0.z; u[i][3] += av * w0.w;
      u[i][4] += av * w1.x; u[i][5] += av * w1.y;
      u[i][6] += av * w1.z; u[i][7] += av * w1.w;
    }
  }
#pragma unroll
  for (int i = 0; i < 4; i++)
#pragma unroll
    for (int j = 0; j < 8; j++) u[i][j] = silu_f(u[i][j] + sb1v[8 * cg + j]);
  __syncthreads();

#pragma unroll
  for (int j = 0; j < 8; j++)
#pragma unroll
    for (int i = 0; i < 4; i++) sA[(8 * cg + j) * ASTR + (4 * rg + i)] = u[i][j];
  for (int i = t; i < 4096; i += 256) sW[i] = W2[i];
  __syncthreads();

  float o[4][8];
#pragma unroll
  for (int i = 0; i < 4; i++)
#pragma unroll
    for (int j = 0; j < 8; j++) o[i][j] = 0.f;
#pragma unroll 8
  for (int k = 0; k < 64; k++) {
    float4 a = sA4[k * (ASTR / 4) + rg];
    float4 w0 = sW4[k * 16 + 2 * cg];
    float4 w1 = sW4[k * 16 + 2 * cg + 1];
#pragma unroll
    for (int i = 0; i < 4; i++) {
      float av = (i == 0) ? a.x : (i == 1) ? a.y : (i == 2) ? a.z : a.w;
      o[i][0] += av * w0.x; o[i][1] += av * w0.y;
      o[i][2] += av * w0.z; o[i][3] += av * w0.w;
      o[i][4] += av * w1.x; o[i][5] += av * w1.y;
      o[i][6] += av * w1.z; o[i][7] += av * w1.w;
    }
  }
  float hnew[4][8];
#pragma unroll
  for (int i = 0; i < 4; i++) {
    int n = n0 + 4 * rg + i;
    if (n < N) {
      float4* hp = (float4*)(h + (size_t)n * 64 + 8 * cg);
      float4 h0 = hp[0], h1 = hp[1];
      hnew[i][0] = h0.x + o[i][0] + sb2v[8 * cg + 0];
      hnew[i][1] = h0.y + o[i][1] + sb2v[8 * cg + 1];
      hnew[i][2] = h0.z + o[i][2] + sb2v[8 * cg + 2];
      hnew[i][3] = h0.w + o[i][3] + sb2v[8 * cg + 3];
      hnew[i][4] = h1.x + o[i][4] + sb2v[8 * cg + 4];
      hnew[i][5] = h1.y + o[i][5] + sb2v[8 * cg + 5];
      hnew[i][6] = h1.z + o[i][6] + sb2v[8 * cg + 6];
      hnew[i][7] = h1.w + o[i][7] + sb2v[8 * cg + 7];
      float4 s0, s1;
      s0.x = hnew[i][0]; s0.y = hnew[i][1]; s0.z = hnew[i][2]; s0.w = hnew[i][3];
      s1.x = hnew[i][4]; s1.y = hnew[i][5]; s1.z = hnew[i][6]; s1.w = hnew[i][7];
      hp[0] = s0; hp[1] = s1;
    } else {
#pragma unroll
      for (int j = 0; j < 8; j++) hnew[i][j] = 0.f;
    }
  }

  if (PREMUL) {
    __syncthreads();  // all o-GEMM sA reads done
#pragma unroll
    for (int j = 0; j < 8; j++)
#pragma unroll
      for (int i = 0; i < 4; i++) sA[(8 * cg + j) * ASTR + (4 * rg + i)] = hnew[i][j];
    for (int i = t; i < 4096; i += 256) sW[i] = W1n[i];
    __syncthreads();
    float aP[4][8];
#pragma unroll
    for (int i = 0; i < 4; i++)
#pragma unroll
      for (int j = 0; j < 8; j++) aP[i][j] = 0.f;
#pragma unroll 8
    for (int k = 0; k < 64; k++) {
      float4 a = sA4[k * (ASTR / 4) + rg];
      float4 w0 = sW4[k * 16 + 2 * cg];
      float4 w1 = sW4[k * 16 + 2 * cg + 1];
#pragma unroll
      for (int i = 0; i < 4; i++) {
        float av = (i == 0) ? a.x : (i == 1) ? a.y : (i == 2) ? a.z : a.w;
        aP[i][0] += av * w0.x; aP[i][1] += av * w0.y;
        aP[i][2] += av * w0.z; aP[i][3] += av * w0.w;
        aP[i][4] += av * w1.x; aP[i][5] += av * w1.y;
        aP[i][6] += av * w1.z; aP[i][7] += av * w1.w;
      }
    }
#pragma unroll
    for (int i = 0; i < 4; i++) {
      int n = n0 + 4 * rg + i;
      if (n < N) {
        float4 o0, o1;
        o0.x = aP[i][0]; o0.y = aP[i][1]; o0.z = aP[i][2]; o0.w = aP[i][3];
        o1.x = aP[i][4]; o1.y = aP[i][5]; o1.z = aP[i][6]; o1.w = aP[i][7];
        float4* Pp = (float4*)(P + (size_t)n * 64 + 8 * cg);
        Pp[0] = o0; Pp[1] = o1;
      }
    }
    __syncthreads();
    for (int i = t; i < 4096; i += 256) sW[i] = W1n[4096 + i];
    __syncthreads();
    float aQ[4][8];
#pragma unroll
    for (int i = 0; i < 4; i++)
#pragma unroll
      for (int j = 0; j < 8; j++) aQ[i][j] = 0.f;
#pragma unroll 8
    for (int k = 0; k < 64; k++) {
      float4 a = sA4[k * (ASTR / 4) + rg];
      float4 w0 = sW4[k * 16 + 2 * cg];
      float4 w1 = sW4[k * 16 + 2 * cg + 1];
#pragma unroll
      for (int i = 0; i < 4; i++) {
        float av = (i == 0) ? a.x : (i == 1) ? a.y : (i == 2) ? a.z : a.w;
        aQ[i][0] += av * w0.x; aQ[i][1] += av * w0.y;
        aQ[i][2] += av * w0.z; aQ[i][3] += av * w0.w;
        aQ[i][4] += av * w1.x; aQ[i][5] += av * w1.y;
        aQ[i][6] += av * w1.z; aQ[i][7] += av * w1.w;
      }
    }
#pragma unroll
    for (int i = 0; i < 4; i++) {
      int n = n0 + 4 * rg + i;
      if (n < N) {
        float4 o0, o1;
        o0.x = aQ[i][0]; o0.y = aQ[i][1]; o0.z = aQ[i][2]; o0.w = aQ[i][3];
        o1.x = aQ[i][4]; o1.y = aQ[i][5]; o1.z = aQ[i][6]; o1.w = aQ[i][7];
        float4* Qp = (float4*)(Q + (size_t)n * 64 + 8 * cg);
        Qp[0] = o0; Qp[1] = o1;
      }
    }
  }
}

// ---------------- CSR build ----------------
__global__ __launch_bounds__(256) void hist_kernel(
    const int* __restrict__ row, int* __restrict__ cnt, int E)
{
  int e = blockIdx.x * 256 + threadIdx.x;
  if (e < E) atomicAdd(&cnt[row[e]], 1);
}

__global__ __launch_bounds__(1024) void scan_kernel(
    const int* __restrict__ cnt, int* __restrict__ rowptr, int* __restrict__ cursor, int N, int E)
{
  __shared__ int part[1024];
  int t = threadIdx.x;
  int chunk = (N + 1023) >> 10;
  int lo = t * chunk;
  int hi = lo + chunk;
  if (lo > N) lo = N;
  if (hi > N) hi = N;
  int s = 0;
  for (int i = lo; i < hi; i++) s += cnt[i];
  part[t] = s;
  __syncthreads();
  for (int off = 1; off < 1024; off <<= 1) {
    int v = 0;
    if (t >= off) v = part[t - off];
    __syncthreads();
    if (t >= off) part[t] += v;
    __syncthreads();
  }
  int run = part[t] - s;
  for (int i = lo; i < hi; i++) {
    rowptr[i] = run;
    cursor[i] = run;
    run += cnt[i];
  }
  if (t == 0) rowptr[N] = E;
}

__global__ __launch_bounds__(256) void scatter_kernel(
    const int* __restrict__ row, const int* __restrict__ col, const float* __restrict__ eattr,
    int* __restrict__ cursor, int* __restrict__ srow, int* __restrict__ scol,
    float* __restrict__ sea4, int E)
{
  int e = blockIdx.x * 256 + threadIdx.x;
  if (e >= E) return;
  int r = row[e];
  int p = atomicAdd(&cursor[r], 1);
  srow[p] = r;
  scol[p] = col[e];
  float4 v;
  v.x = eattr[(size_t)e * 3 + 0];
  v.y = eattr[(size_t)e * 3 + 1];
  v.z = eattr[(size_t)e * 3 + 2];
  v.w = 0.f;
  ((float4*)sea4)[p] = v;
}

// ---------------- weight prep: bf16 hi/lo of W^T ----------------
__global__ __launch_bounds__(256) void prep_wt_kernel(
    const float* __restrict__ W2all, const float* __restrict__ C1all,
    ushort* __restrict__ w2h, ushort* __restrict__ w2l,
    ushort* __restrict__ c1h, ushort* __restrict__ c1l)
{
  int idx = blockIdx.x * 256 + threadIdx.x;
  if (idx >= 4 * 4096) return;
  int layer = idx >> 12, rem = idx & 4095;
  int k = rem >> 6, c = rem & 63;
  int oidx = layer * 4096 + c * 64 + k;
  ushort h, l;
  bf16_split(W2all[idx], h, l);
  w2h[oidx] = h; w2l[oidx] = l;
  if (layer < 3) {
    bf16_split(C1all[idx], h, l);
    c1h[oidx] = h; c1l[oidx] = l;
  }
}

// ---------------- fused edge kernel (MFMA, operand-swapped) ----------------
#define EB 128

__device__ __forceinline__ bshort8 lds_frag(const ushort* base, int edge, int kb)
{
  int byte = edge * 128 + kb * 2;
  byte ^= (edge & 7) << 4;
  return *(const bshort8*)((const char*)base + byte);
}

template <int COORD>
__global__ __launch_bounds__(256) void edge_fused_kernel(
    const int* __restrict__ srow, const int* __restrict__ scol, const int* __restrict__ rowptr,
    const float* __restrict__ posr, float* __restrict__ posw,
    const float* __restrict__ sea4,
    const float* __restrict__ P, const float* __restrict__ Q,
    const float* __restrict__ W1t, const float* __restrict__ b1,
    const ushort* __restrict__ w2h, const ushort* __restrict__ w2l,
    const float* __restrict__ b2,
    const ushort* __restrict__ c1h, const ushort* __restrict__ c1l,
    const float* __restrict__ cb1, const float* __restrict__ cW2,
    const float* __restrict__ cb2,
    float* __restrict__ agg, int E)
{
  __shared__ ushort sUhi[EB * 64];  // [edge][k] bf16 hi, XOR-swizzled rows
  __shared__ ushort sUlo[EB * 64];
  __shared__ float sW1t[4 * 64];
  __shared__ float sb1v[64], sb2v[64];
  __shared__ float sDiff[3][EB];
  __shared__ float sWe[EB];
  __shared__ int sShare[COORD ? EB * 4 : EB];  // s_srow then sPart
  __shared__ float scb1v[COORD ? 64 : 1];
  __shared__ float scW2v[COORD ? 64 : 1];
  __shared__ int sSlotCnt[2];
  __shared__ int sSlotStart[EB + 2];
  __shared__ int sSlotRowF[EB];

  int* s_srow = sShare;
  float* sPart = (float*)sShare;

  int t = threadIdx.x;
  sW1t[t] = W1t[t];
  if (t < 64) { sb1v[t] = b1[t]; sb2v[t] = b2[t]; }
  if (COORD && t >= 64 && t < 128) { scb1v[t - 64] = cb1[t - 64]; scW2v[t - 64] = cW2[t - 64]; }
  __syncthreads();

  int e0 = blockIdx.x * EB;
  int nE = E - e0; if (nE > EB) nE = EB;

  // ---- stage 1: u tile -> bf16 hi/lo, conflict-free b128 writes ----
#pragma unroll
  for (int p = 0; p < 4; p++) {
    int eloc = p * 32 + (t >> 3);
    int ks = t & 7;
    int e = e0 + eloc;
    int base = eloc * 128 + ks * 16;
    int swz = (eloc & 7) << 4;
    if (e < E) {
      int r = srow[e];
      int c = scol[e];
      float prx = posr[(size_t)r * 3 + 0], pry = posr[(size_t)r * 3 + 1],
            prz = posr[(size_t)r * 3 + 2];
      float pcx = posr[(size_t)c * 3 + 0], pcy = posr[(size_t)c * 3 + 1],
            pcz = posr[(size_t)c * 3 + 2];
      float dx = prx - pcx, dy = pry - pcy, dz = prz - pcz;
      float dist = sqrtf(dx * dx + dy * dy + dz * dz);
      if (ks == 0) {
        s_srow[eloc] = r;
        sDiff[0][eloc] = dx; sDiff[1][eloc] = dy; sDiff[2][eloc] = dz;
      }
      float4 ea = ((const float4*)sea4)[e];
      const float4* P4p = (const float4*)(P + (size_t)r * 64) + ks * 2;
      const float4* Q4p = (const float4*)(Q + (size_t)c * 64) + ks * 2;
      float4 a0 = P4p[0], a1 = P4p[1];
      float4 q0 = Q4p[0], q1 = Q4p[1];
      float pa[8] = {a0.x, a0.y, a0.z, a0.w, a1.x, a1.y, a1.z, a1.w};
      float qa[8] = {q0.x, q0.y, q0.z, q0.w, q1.x, q1.y, q1.z, q1.w};
      ushort hh[8], ll[8];
#pragma unroll
      for (int kk = 0; kk < 8; kk++) {
        int k = ks * 8 + kk;
        float val = pa[kk] + qa[kk] + sb1v[k] + dist * sW1t[k] + ea.x * sW1t[64 + k] +
                    ea.y * sW1t[128 + k] + ea.z * sW1t[192 + k];
        float uv = silu_f(val);
        bf16_split(uv, hh[kk], ll[kk]);
      }
      uint4 hv, lv;
      hv.x = (uint)hh[0] | ((uint)hh[1] << 16);
      hv.y = (uint)hh[2] | ((uint)hh[3] << 16);
      hv.z = (uint)hh[4] | ((uint)hh[5] << 16);
      hv.w = (uint)hh[6] | ((uint)hh[7] << 16);
      lv.x = (uint)ll[0] | ((uint)ll[1] << 16);
      lv.y = (uint)ll[2] | ((uint)ll[3] << 16);
      lv.z = (uint)ll[4] | ((uint)ll[5] << 16);
      lv.w = (uint)ll[6] | ((uint)ll[7] << 16);
      *(uint4*)((char*)sUhi + (base ^ swz)) = hv;
      *(uint4*)((char*)sUlo + (base ^ swz)) = lv;
    } else {
      uint4 z; z.x = 0; z.y = 0; z.z = 0; z.w = 0;
      *(uint4*)((char*)sUhi + (base ^ swz)) = z;
      *(uint4*)((char*)sUlo + (base ^ swz)) = z;
    }
  }
  __syncthreads();

  // ---- phase A: slot ballot (waves 0,1 cover edges 0..127) ----
  bool isstart = false;
  int pre = 0;
  if (t < 128) {
    int le = t;
    isstart = (le < nE) && (le == 0 || s_srow[le] != s_srow[le - 1]);
    unsigned long long m = __ballot(isstart ? 1 : 0);
    int lane = t & 63;
    pre = __popcll(m & ((lane == 0) ? 0ull : ((~0ull) >> (64 - lane))));
    if (lane == 0) sSlotCnt[t >> 6] = __popcll(m);
  }
  __syncthreads();
  if (t < 128 && isstart) {
    int le = t;
    int slot = ((t >> 6) ? sSlotCnt[0] : 0) + pre;
    int row = s_srow[le];
    sSlotStart[slot] = le;
    int rs = rowptr[row], re = rowptr[row + 1];
    int interior = (rs >= e0 && re <= e0 + nE) ? 1 : 0;
    sSlotRowF[slot] = row | (interior << 30);
  }
  if (t == 0) sSlotStart[sSlotCnt[0] + sSlotCnt[1]] = nE;
  // published by stage-2's internal barrier

  // ---- stage 2: m^T = W2^T · u^T (operand-swapped MFMA, bf16 3-split) ----
  int l = t & 63;
  int wv = t >> 6;      // col-tile: cols wv*16 .. +15
  int lane16 = l & 15;  // edge-in-tile (B) / weight-row-in-tile (A)
  int kq = l >> 4;      // k-octet quarter

  {
    const ushort* bhp = w2h + (wv * 16 + lane16) * 64 + kq * 8;
    const ushort* blp = w2l + (wv * 16 + lane16) * 64 + kq * 8;
    bshort8 wh0 = *(const bshort8*)(bhp);
    bshort8 wh1 = *(const bshort8*)(bhp + 32);
    bshort8 wl0 = *(const bshort8*)(blp);
    bshort8 wl1 = *(const bshort8*)(blp + 32);

    f32x4 acc[8];
#pragma unroll
    for (int et = 0; et < 8; et++) {
      int edge = et * 16 + lane16;
      bshort8 uh0 = lds_frag(sUhi, edge, kq * 8);
      bshort8 uh1 = lds_frag(sUhi, edge, 32 + kq * 8);
      bshort8 ul0 = lds_frag(sUlo, edge, kq * 8);
      bshort8 ul1 = lds_frag(sUlo, edge, 32 + kq * 8);
      f32x4 a = {0.f, 0.f, 0.f, 0.f};
      a = __builtin_amdgcn_mfma_f32_16x16x32_bf16(wh0, uh0, a, 0, 0, 0);
      a = __builtin_amdgcn_mfma_f32_16x16x32_bf16(wh1, uh1, a, 0, 0, 0);
      a = __builtin_amdgcn_mfma_f32_16x16x32_bf16(wh0, ul0, a, 0, 0, 0);
      a = __builtin_amdgcn_mfma_f32_16x16x32_bf16(wh1, ul1, a, 0, 0, 0);
      a = __builtin_amdgcn_mfma_f32_16x16x32_bf16(wl0, uh0, a, 0, 0, 0);
      a = __builtin_amdgcn_mfma_f32_16x16x32_bf16(wl1, uh1, a, 0, 0, 0);
      acc[et] = a;
    }
    __syncthreads();  // all u reads done; also publishes slot tables

    float b2r[4];
#pragma unroll
    for (int r = 0; r < 4; r++) b2r[r] = sb2v[wv * 16 + kq * 4 + r];
#pragma unroll
    for (int et = 0; et < 8; et++) {
      int edge = et * 16 + lane16;
      ushort mh[4], ml[4];
#pragma unroll
      for (int r = 0; r < 4; r++) {
        float mv = silu_f(acc[et][r] + b2r[r]);
        bf16_split(mv, mh[r], ml[r]);
      }
      int byte = (edge * 128 + (wv * 16 + kq * 4) * 2) ^ ((edge & 7) << 4);
      uint2 hv, lv;
      hv.x = (uint)mh[0] | ((uint)mh[1] << 16);
      hv.y = (uint)mh[2] | ((uint)mh[3] << 16);
      lv.x = (uint)ml[0] | ((uint)ml[1] << 16);
      lv.y = (uint)ml[2] | ((uint)ml[3] << 16);
      *(uint2*)((char*)sUhi + byte) = hv;
      *(uint2*)((char*)sUlo + byte) = lv;
    }
  }
  __syncthreads();

  // ---- stage 3 (COORD): v^T = cW1^T · m^T (m hi-only), in-thread reduce ----
  if (COORD) {
    const ushort* chp = c1h + (wv * 16 + lane16) * 64 + kq * 8;
    const ushort* clp = c1l + (wv * 16 + lane16) * 64 + kq * 8;
    bshort8 ch0 = *(const bshort8*)(chp);
    bshort8 ch1 = *(const bshort8*)(chp + 32);
    bshort8 cl0 = *(const bshort8*)(clp);
    bshort8 cl1 = *(const bshort8*)(clp + 32);
    float cb1r[4], cw2r[4];
#pragma unroll
    for (int r = 0; r < 4; r++) {
      cb1r[r] = scb1v[wv * 16 + kq * 4 + r];
      cw2r[r] = scW2v[wv * 16 + kq * 4 + r];
    }
#pragma unroll
    for (int et = 0; et < 8; et++) {
      int edge = et * 16 + lane16;
      bshort8 mh0 = lds_frag(sUhi, edge, kq * 8);
      bshort8 mh1 = lds_frag(sUhi, edge, 32 + kq * 8);
      f32x4 a = {0.f, 0.f, 0.f, 0.f};
      a = __builtin_amdgcn_mfma_f32_16x16x32_bf16(ch0, mh0, a, 0, 0, 0);
      a = __builtin_amdgcn_mfma_f32_16x16x32_bf16(ch1, mh1, a, 0, 0, 0);
      a = __builtin_amdgcn_mfma_f32_16x16x32_bf16(cl0, mh0, a, 0, 0, 0);
      a = __builtin_amdgcn_mfma_f32_16x16x32_bf16(cl1, mh1, a, 0, 0, 0);
      float pr = 0.f;
#pragma unroll
      for (int r = 0; r < 4; r++) pr += silu_f(a[r] + cb1r[r]) * cw2r[r];
      pr += __shfl_xor(pr, 16);
      pr += __shfl_xor(pr, 32);
      if (kq == 0) sPart[edge * 4 + wv] = pr;
    }
  }
  __syncthreads();
  if (COORD) {
    if (t >= 128) {
      int e = t - 128;
      sWe[e] = sPart[4 * e + 0] + sPart[4 * e + 1] + sPart[4 * e + 2] + sPart[4 * e + 3] + cb2[0];
    }
  }
  __syncthreads();

  // ---- stage 4: slot-based segmented reductions ----
  int nslots = sSlotCnt[0] + sSlotCnt[1];
  for (int task = t; task < (nslots << 5); task += 256) {
    int s = task >> 5, cp = task & 31;  // channel pair 2cp, 2cp+1
    int a = sSlotStart[s], b = sSlotStart[s + 1];
    float acc0 = 0.f, acc1 = 0.f;
    for (int le = a; le < b; le++) {
      int byte = (le * 128 + cp * 4) ^ ((le & 7) << 4);
      uint hv = *(const uint*)((const char*)sUhi + byte);
      uint lv = *(const uint*)((const char*)sUlo + byte);
      acc0 += __uint_as_float(hv << 16) + __uint_as_float(lv << 16);
      acc1 += __uint_as_float(hv & 0xffff0000u) + __uint_as_float(lv & 0xffff0000u);
    }
    int rowf = sSlotRowF[s];
    int row = rowf & 0x3fffffff;
    float* ap = agg + (size_t)row * 64 + 2 * cp;
    if (rowf & (1 << 30)) {
      ap[0] = acc0; ap[1] = acc1;
    } else {
      atomicAdd(ap, acc0);
      atomicAdd(ap + 1, acc1);
    }
  }
  if (COORD) {
    for (int task = t; task < (nslots << 2); task += 256) {
      int s = task >> 2, d = task & 3;
      if (d < 3) {
        int a = sSlotStart[s], b = sSlotStart[s + 1];
        float acc = 0.f;
        for (int le = a; le < b; le++) acc += sDiff[d][le] * sWe[le];
        int row = sSlotRowF[s] & 0x3fffffff;
        atomicAdd(&posw[(size_t)row * 3 + d], acc);
      }
    }
  }
}

// ---------------- pooling + classifier ----------------
__device__ __forceinline__ int lbound(const int* __restrict__ a, int n, int v)
{
  int lo = 0, hi = n;
  while (lo < hi) {
    int mid = (lo + hi) >> 1;
    if (a[mid] < v) lo = mid + 1;
    else hi = mid;
  }
  return lo;
}

__global__ __launch_bounds__(256) void pool_cls_kernel(
    const float* __restrict__ h, const int* __restrict__ batch, int N,
    const float* __restrict__ W1, const float* __restrict__ b1,
    const float* __restrict__ W2, const float* __restrict__ b2, float* __restrict__ out)
{
  int g = blockIdx.x;
  int start = lbound(batch, N, g);
  int end = lbound(batch, N, g + 1);
  int j = threadIdx.x & 63;
  int grp = threadIdx.x >> 6;
  float s = 0.f, mx = -INFINITY;
  for (int n = start + grp; n < end; n += 4) {
    float v = h[(size_t)n * 64 + j];
    s += v;
    mx = fmaxf(mx, v);
  }
  __shared__ float ssum[4][64];
  __shared__ float smax[4][64];
  __shared__ float pooled[128];
  __shared__ float su[64];
  ssum[grp][j] = s;
  smax[grp][j] = mx;
  __syncthreads();
  if (grp == 0) {
    float S = ssum[0][j] + ssum[1][j] + ssum[2][j] + ssum[3][j];
    float M = fmaxf(fmaxf(smax[0][j], smax[1][j]), fmaxf(smax[2][j], smax[3][j]));
    float cnt = (float)(end - start);
    pooled[j] = S / fmaxf(cnt, 1.0f);
    pooled[64 + j] = M;
  }
  __syncthreads();
  if (threadIdx.x < 64) {
    float a = b1[j];
#pragma unroll
    for (int k = 0; k < 128; k++) a += pooled[k] * W1[k * 64 + j];
    su[j] = fmaxf(a, 0.f);
  }
  __syncthreads();
  if (threadIdx.x < 2) {
    float a = b2[threadIdx.x];
#pragma unroll
    for (int k = 0; k < 64; k++) a += su[k] * W2[k * 2 + threadIdx.x];
    out[g * 2 + threadIdx.x] = a;
  }
}

extern "C" void kernel_launch(void* const* d_in, const int* in_sizes, int n_in,
                              void* d_out, int out_size, void* d_ws, size_t ws_size,
                              hipStream_t stream)
{
  const float* x = (const float*)d_in[0];
  const float* pos = (const float*)d_in[1];
  const int* ei = (const int*)d_in[2];
  const float* eattr = (const float*)d_in[3];
  const int* batch = (const int*)d_in[4];
  const float* projW = (const float*)d_in[5];
  const float* projb = (const float*)d_in[6];
  const float* msgW1 = (const float*)d_in[7];
  const float* msgb1 = (const float*)d_in[8];
  const float* msgW2 = (const float*)d_in[9];
  const float* msgb2 = (const float*)d_in[10];
  const float* ndW1 = (const float*)d_in[11];
  const float* ndb1 = (const float*)d_in[12];
  const float* ndW2 = (const float*)d_in[13];
  const float* ndb2 = (const float*)d_in[14];
  const float* cdW1 = (const float*)d_in[15];
  const float* cdb1 = (const float*)d_in[16];
  const float* cdW2 = (const float*)d_in[17];
  const float* cdb2 = (const float*)d_in[18];
  const float* clsW1 = (const float*)d_in[19];
  const float* clsb1 = (const float*)d_in[20];
  const float* clsW2 = (const float*)d_in[21];
  const float* clsb2 = (const float*)d_in[22];

  int N = in_sizes[4];
  int E = in_sizes[3] / 3;
  const int* rowp = ei;
  const int* colp = ei + E;

  char* wsb = (char*)d_ws;
  size_t off = 0;
  auto alloc = [&](size_t bytes) {
    size_t o = off;
    off = (off + bytes + 255) & ~(size_t)255;
    return o;
  };
  size_t nh = (size_t)N * 64 * sizeof(float);
  size_t o_h = alloc(nh);
  size_t o_P = alloc(nh);
  size_t o_Q = alloc(nh);
  size_t o_agg = alloc(nh);
  size_t o_posA = alloc((size_t)N * 3 * sizeof(float));
  size_t o_posB = alloc((size_t)N * 3 * sizeof(float));
  size_t o_cnt = alloc((size_t)N * sizeof(int));
  size_t o_rowptr = alloc(((size_t)N + 1) * sizeof(int));
  size_t o_cursor = alloc((size_t)N * sizeof(int));
  size_t o_srow = alloc((size_t)E * sizeof(int));
  size_t o_scol = alloc((size_t)E * sizeof(int));
  size_t o_sea4 = alloc((size_t)E * 4 * sizeof(float));
  size_t o_w2h = alloc(4 * 4096 * sizeof(ushort));
  size_t o_w2l = alloc(4 * 4096 * sizeof(ushort));
  size_t o_c1h = alloc(4 * 4096 * sizeof(ushort));
  size_t o_c1l = alloc(4 * 4096 * sizeof(ushort));
  size_t csr_end = off;

  float* h = (float*)(wsb + o_h);
  float* Pb = (float*)(wsb + o_P);
  float* Qb = (float*)(wsb + o_Q);
  float* agg = (float*)(wsb + o_agg);
  float* posA = (float*)(wsb + o_posA);
  float* posB = (float*)(wsb + o_posB);

  int nb_nodes = (N + 255) / 256;
  int nb_edges = (E + 255) / 256;
  int nb_tiled = (N + NB - 1) / NB;
  int G = out_size / 2;

  proj_kernel<<<nb_nodes, 256, 0, stream>>>(x, projW, projb, h, N);

  const float* pr[4] = {pos, posA, posB, posA};
  float* pw[4] = {posA, posB, posA, nullptr};

  bool use_sorted = (csr_end <= ws_size);

  if (use_sorted) {
    int* cnt = (int*)(wsb + o_cnt);
    int* rowptr = (int*)(wsb + o_rowptr);
    int* cursor = (int*)(wsb + o_cursor);
    int* srow = (int*)(wsb + o_srow);
    int* scol = (int*)(wsb + o_scol);
    float* sea4 = (float*)(wsb + o_sea4);
    ushort* w2h = (ushort*)(wsb + o_w2h);
    ushort* w2l = (ushort*)(wsb + o_w2l);
    ushort* c1h = (ushort*)(wsb + o_c1h);
    ushort* c1l = (ushort*)(wsb + o_c1l);

    hipMemsetAsync(cnt, 0, (size_t)N * sizeof(int), stream);
    hist_kernel<<<nb_edges, 256, 0, stream>>>(rowp, cnt, E);
    scan_kernel<<<1, 1024, 0, stream>>>(cnt, rowptr, cursor, N, E);
    scatter_kernel<<<nb_edges, 256, 0, stream>>>(rowp, colp, eattr, cursor, srow, scol, sea4, E);
    prep_wt_kernel<<<64, 256, 0, stream>>>(msgW2, cdW1, w2h, w2l, c1h, c1l);

    // premul for layer 0; layers 1-3 fused into node_tiled
    premul_tiled_kernel<<<nb_tiled, 256, 0, stream>>>(h, msgW1, Pb, Qb, N);

    int nb_fused = (E + EB - 1) / EB;
    for (int i = 0; i < 4; i++) {
      hipMemsetAsync(agg, 0, nh, stream);
      if (i < 3) {
        hipMemcpyAsync(pw[i], pr[i], (size_t)N * 3 * sizeof(float), hipMemcpyDeviceToDevice,
                       stream);
        edge_fused_kernel<1><<<nb_fused, 256, 0, stream>>>(
            srow, scol, rowptr, pr[i], pw[i], sea4, Pb, Qb,
            msgW1 + (size_t)i * 132 * 64 + 128 * 64, msgb1 + i * 64,
            w2h + (size_t)i * 4096, w2l + (size_t)i * 4096, msgb2 + i * 64,
            c1h + (size_t)i * 4096, c1l + (size_t)i * 4096,
            cdb1 + i * 64, cdW2 + i * 64, cdb2 + i, agg, E);
        node_tiled_kernel<1><<<nb_tiled, 256, 0, stream>>>(
            h, agg, ndW1 + (size_t)i * 8192, ndb1 + i * 64, ndW2 + (size_t)i * 4096,
            ndb2 + i * 64, N, msgW1 + (size_t)(i + 1) * 132 * 64, Pb, Qb);
      } else {
        edge_fused_kernel<0><<<nb_fused, 256, 0, stream>>>(
            srow, scol, rowptr, pr[i], nullptr, sea4, Pb, Qb,
            msgW1 + (size_t)i * 132 * 64 + 128 * 64, msgb1 + i * 64,
            w2h + (size_t)i * 4096, w2l + (size_t)i * 4096, msgb2 + i * 64,
            nullptr, nullptr, nullptr, nullptr, nullptr, agg, E);
        node_tiled_kernel<0><<<nb_tiled, 256, 0, stream>>>(
            h, agg, ndW1 + (size_t)i * 8192, ndb1 + i * 64, ndW2 + (size_t)i * 4096,
            ndb2 + i * 64, N, nullptr, nullptr, nullptr);
      }
    }
  } else {
    for (int i = 0; i < 4; i++) {
      premul_tiled_kernel<<<nb_tiled, 256, 0, stream>>>(h, msgW1 + (size_t)i * 132 * 64, Pb, Qb,
                                                        N);
      hipMemsetAsync(agg, 0, nh, stream);
      node_tiled_kernel<0><<<nb_tiled, 256, 0, stream>>>(
          h, agg, ndW1 + (size_t)i * 8192, ndb1 + i * 64, ndW2 + (size_t)i * 4096, ndb2 + i * 64,
          N, nullptr, nullptr, nullptr);
    }
  }

  pool_cls_kernel<<<G, 256, 0, stream>>>(h, batch, N, clsW1, clsb1, clsW2, clsb2, (float*)d_out);
}

// Round 13
// 913.696 us; speedup vs baseline: 15.5339x; 1.1296x over previous
//
#include <hip/hip_runtime.h>
#include <math.h>

// EGNN forward. P/Q factorization + CSR sort + fused MFMA edge kernel.
// Round 13: fast silu via v_rcp_f32 (plain fp32 div = ~9-op sequence; rcp = 1
// op, ~1ulp). Applied everywhere. Otherwise identical to round 12.

typedef __attribute__((ext_vector_type(8))) short bshort8;
typedef __attribute__((ext_vector_type(4))) float f32x4;
typedef unsigned short ushort;
typedef unsigned int uint;

__device__ __forceinline__ float silu_f(float x)
{
  return x * __builtin_amdgcn_rcpf(1.0f + __expf(-x));
}

__device__ __forceinline__ void bf16_split(float x, ushort& h, ushort& l)
{
  uint bx = __float_as_uint(x);
  ushort hb = (ushort)(bx >> 16);
  float hf = __uint_as_float((uint)hb << 16);
  float r = x - hf;
  l = (ushort)(__float_as_uint(r) >> 16);
  h = hb;
}

#define ROW_FMA(acc, scal, rowptr)                                                   \
  {                                                                                  \
    const float4* _w = (const float4*)(rowptr);                                      \
    _Pragma("unroll") for (int _j = 0; _j < 16; _j++)                                \
    {                                                                                \
      float4 _wv = _w[_j];                                                           \
      acc[4 * _j + 0] += (scal) * _wv.x;                                             \
      acc[4 * _j + 1] += (scal) * _wv.y;                                             \
      acc[4 * _j + 2] += (scal) * _wv.z;                                             \
      acc[4 * _j + 3] += (scal) * _wv.w;                                             \
    }                                                                                \
  }

// ---------------- proj ----------------
__global__ __launch_bounds__(256) void proj_kernel(
    const float* __restrict__ x, const float* __restrict__ W, const float* __restrict__ b,
    float* __restrict__ h, int N)
{
  __shared__ float sW[26 * 64];
  __shared__ float sb[64];
  for (int i = threadIdx.x; i < 26 * 64; i += 256) sW[i] = W[i];
  if (threadIdx.x < 64) sb[threadIdx.x] = b[threadIdx.x];
  __syncthreads();
  int n = blockIdx.x * 256 + threadIdx.x;
  if (n >= N) return;
  float acc[64];
#pragma unroll
  for (int j = 0; j < 64; j++) acc[j] = sb[j];
#pragma unroll
  for (int k = 0; k < 26; k++) {
    float xk = x[(size_t)n * 26 + k];
    ROW_FMA(acc, xk, sW + k * 64);
  }
  float4* h4 = (float4*)(h + (size_t)n * 64);
#pragma unroll
  for (int j4 = 0; j4 < 16; j4++) {
    float4 v;
    v.x = acc[4 * j4 + 0]; v.y = acc[4 * j4 + 1]; v.z = acc[4 * j4 + 2]; v.w = acc[4 * j4 + 3];
    h4[j4] = v;
  }
}

// ---------------- tiled premul (layer 0 only) ----------------
#define NB 128
#define ASTR 132

__global__ __launch_bounds__(256) void premul_tiled_kernel(
    const float* __restrict__ h, const float* __restrict__ W1,
    float* __restrict__ P, float* __restrict__ Q, int N)
{
  __shared__ float sA[64 * ASTR];
  __shared__ float sW[64 * 64];
  int t = threadIdx.x;
  int n0 = blockIdx.x * NB;

#pragma unroll
  for (int it = 0; it < 8; it++) {
    int f = t + 256 * it;
    int nl = f >> 4;
    int k4 = f & 15;
    int n = n0 + nl;
    float4 v;
    if (n < N) v = ((const float4*)(h + (size_t)n * 64))[k4];
    else { v.x = v.y = v.z = v.w = 0.f; }
    sA[(4 * k4 + 0) * ASTR + nl] = v.x;
    sA[(4 * k4 + 1) * ASTR + nl] = v.y;
    sA[(4 * k4 + 2) * ASTR + nl] = v.z;
    sA[(4 * k4 + 3) * ASTR + nl] = v.w;
  }
  for (int i = t; i < 4096; i += 256) sW[i] = W1[i];
  __syncthreads();

  int rg = t & 31, cg = t >> 5;
  const float4* sA4 = (const float4*)sA;
  const float4* sW4 = (const float4*)sW;

  float aP[4][8];
#pragma unroll
  for (int i = 0; i < 4; i++)
#pragma unroll
    for (int j = 0; j < 8; j++) aP[i][j] = 0.f;
#pragma unroll 8
  for (int k = 0; k < 64; k++) {
    float4 a = sA4[k * (ASTR / 4) + rg];
    float4 w0 = sW4[k * 16 + 2 * cg];
    float4 w1 = sW4[k * 16 + 2 * cg + 1];
#pragma unroll
    for (int i = 0; i < 4; i++) {
      float av = (i == 0) ? a.x : (i == 1) ? a.y : (i == 2) ? a.z : a.w;
      aP[i][0] += av * w0.x; aP[i][1] += av * w0.y;
      aP[i][2] += av * w0.z; aP[i][3] += av * w0.w;
      aP[i][4] += av * w1.x; aP[i][5] += av * w1.y;
      aP[i][6] += av * w1.z; aP[i][7] += av * w1.w;
    }
  }
  __syncthreads();
  for (int i = t; i < 4096; i += 256) sW[i] = W1[4096 + i];
  __syncthreads();
  float aQ[4][8];
#pragma unroll
  for (int i = 0; i < 4; i++)
#pragma unroll
    for (int j = 0; j < 8; j++) aQ[i][j] = 0.f;
#pragma unroll 8
  for (int k = 0; k < 64; k++) {
    float4 a = sA4[k * (ASTR / 4) + rg];
    float4 w0 = sW4[k * 16 + 2 * cg];
    float4 w1 = sW4[k * 16 + 2 * cg + 1];
#pragma unroll
    for (int i = 0; i < 4; i++) {
      float av = (i == 0) ? a.x : (i == 1) ? a.y : (i == 2) ? a.z : a.w;
      aQ[i][0] += av * w0.x; aQ[i][1] += av * w0.y;
      aQ[i][2] += av * w0.z; aQ[i][3] += av * w0.w;
      aQ[i][4] += av * w1.x; aQ[i][5] += av * w1.y;
      aQ[i][6] += av * w1.z; aQ[i][7] += av * w1.w;
    }
  }
#pragma unroll
  for (int i = 0; i < 4; i++) {
    int n = n0 + 4 * rg + i;
    if (n < N) {
      float4 o0, o1;
      o0.x = aP[i][0]; o0.y = aP[i][1]; o0.z = aP[i][2]; o0.w = aP[i][3];
      o1.x = aP[i][4]; o1.y = aP[i][5]; o1.z = aP[i][6]; o1.w = aP[i][7];
      float4* Pp = (float4*)(P + (size_t)n * 64 + 8 * cg);
      Pp[0] = o0; Pp[1] = o1;
      o0.x = aQ[i][0]; o0.y = aQ[i][1]; o0.z = aQ[i][2]; o0.w = aQ[i][3];
      o1.x = aQ[i][4]; o1.y = aQ[i][5]; o1.z = aQ[i][6]; o1.w = aQ[i][7];
      float4* Qp = (float4*)(Q + (size_t)n * 64 + 8 * cg);
      Qp[0] = o0; Qp[1] = o1;
    }
  }
}

// ---------------- tiled node MLP (+fused premul for next layer) ----------------
template <int PREMUL>
__global__ __launch_bounds__(256) void node_tiled_kernel(
    float* __restrict__ h, const float* __restrict__ agg,
    const float* __restrict__ W1, const float* __restrict__ b1,
    const float* __restrict__ W2, const float* __restrict__ b2, int N,
    const float* __restrict__ W1n, float* __restrict__ P, float* __restrict__ Q)
{
  __shared__ float sA[64 * ASTR];
  __shared__ float sW[64 * 64];
  __shared__ float sb1v[64], sb2v[64];
  int t = threadIdx.x;
  int n0 = blockIdx.x * NB;
  int rg = t & 31, cg = t >> 5;
  const float4* sA4 = (const float4*)sA;
  const float4* sW4 = (const float4*)sW;

#pragma unroll
  for (int it = 0; it < 8; it++) {
    int f = t + 256 * it;
    int nl = f >> 4;
    int k4 = f & 15;
    int n = n0 + nl;
    float4 v;
    if (n < N) v = ((const float4*)(h + (size_t)n * 64))[k4];
    else { v.x = v.y = v.z = v.w = 0.f; }
    sA[(4 * k4 + 0) * ASTR + nl] = v.x;
    sA[(4 * k4 + 1) * ASTR + nl] = v.y;
    sA[(4 * k4 + 2) * ASTR + nl] = v.z;
    sA[(4 * k4 + 3) * ASTR + nl] = v.w;
  }
  for (int i = t; i < 4096; i += 256) sW[i] = W1[i];
  if (t < 64) { sb1v[t] = b1[t]; sb2v[t] = b2[t]; }
  __syncthreads();

  float u[4][8];
#pragma unroll
  for (int i = 0; i < 4; i++)
#pragma unroll
    for (int j = 0; j < 8; j++) u[i][j] = 0.f;
#pragma unroll 8
  for (int k = 0; k < 64; k++) {
    float4 a = sA4[k * (ASTR / 4) + rg];
    float4 w0 = sW4[k * 16 + 2 * cg];
    float4 w1 = sW4[k * 16 + 2 * cg + 1];
#pragma unroll
    for (int i = 0; i < 4; i++) {
      float av = (i == 0) ? a.x : (i == 1) ? a.y : (i == 2) ? a.z : a.w;
      u[i][0] += av * w0.x; u[i][1] += av * w0.y;
      u[i][2] += av * w0.z; u[i][3] += av * w0.w;
      u[i][4] += av * w1.x; u[i][5] += av * w1.y;
      u[i][6] += av * w1.z; u[i][7] += av * w1.w;
    }
  }
  __syncthreads();

#pragma unroll
  for (int it = 0; it < 8; it++) {
    int f = t + 256 * it;
    int nl = f >> 4;
    int k4 = f & 15;
    int n = n0 + nl;
    float4 v;
    if (n < N) v = ((const float4*)(agg + (size_t)n * 64))[k4];
    else { v.x = v.y = v.z = v.w = 0.f; }
    sA[(4 * k4 + 0) * ASTR + nl] = v.x;
    sA[(4 * k4 + 1) * ASTR + nl] = v.y;
    sA[(4 * k4 + 2) * ASTR + nl] = v.z;
    sA[(4 * k4 + 3) * ASTR + nl] = v.w;
  }
  for (int i = t; i < 4096; i += 256) sW[i] = W1[4096 + i];
  __syncthreads();
#pragma unroll 8
  for (int k = 0; k < 64; k++) {
    float4 a = sA4[k * (ASTR / 4) + rg];
    float4 w0 = sW4[k * 16 + 2 * cg];
    float4 w1 = sW4[k * 16 + 2 * cg + 1];
#pragma unroll
    for (int i = 0; i < 4; i++) {
      float av = (i == 0) ? a.x : (i == 1) ? a.y : (i == 2) ? a.z : a.w;
      u[i][0] += av * w0.x; u[i][1] += av * w0.y;
      u[i][2] += av * w0.z; u[i][3] += av * w0.w;
      u[i][4] += av * w1.x; u[i][5] += av * w1.y;
      u[i][6] += av * w1.z; u[i][7] += av * w1.w;
    }
  }
#pragma unroll
  for (int i = 0; i < 4; i++)
#pragma unroll
    for (int j = 0; j < 8; j++) u[i][j] = silu_f(u[i][j] + sb1v[8 * cg + j]);
  __syncthreads();

#pragma unroll
  for (int j = 0; j < 8; j++)
#pragma unroll
    for (int i = 0; i < 4; i++) sA[(8 * cg + j) * ASTR + (4 * rg + i)] = u[i][j];
  for (int i = t; i < 4096; i += 256) sW[i] = W2[i];
  __syncthreads();

  float o[4][8];
#pragma unroll
  for (int i = 0; i < 4; i++)
#pragma unroll
    for (int j = 0; j < 8; j++) o[i][j] = 0.f;
#pragma unroll 8
  for (int k = 0; k < 64; k++) {
    float4 a = sA4[k * (ASTR / 4) + rg];
    float4 w0 = sW4[k * 16 + 2 * cg];
    float4 w1 = sW4[k * 16 + 2 * cg + 1];
#pragma unroll
    for (int i = 0; i < 4; i++) {
      float av = (i == 0) ? a.x : (i == 1) ? a.y : (i == 2) ? a.z : a.w;
      o[i][0] += av * w0.x; o[i][1] += av * w0.y;
      o[i][2] += av * w0.z; o[i][3] += av * w0.w;
      o[i][4] += av * w1.x; o[i][5] += av * w1.y;
      o[i][6] += av * w1.z; o[i][7] += av * w1.w;
    }
  }
  float hnew[4][8];
#pragma unroll
  for (int i = 0; i < 4; i++) {
    int n = n0 + 4 * rg + i;
    if (n < N) {
      float4* hp = (float4*)(h + (size_t)n * 64 + 8 * cg);
      float4 h0 = hp[0], h1 = hp[1];
      hnew[i][0] = h0.x + o[i][0] + sb2v[8 * cg + 0];
      hnew[i][1] = h0.y + o[i][1] + sb2v[8 * cg + 1];
      hnew[i][2] = h0.z + o[i][2] + sb2v[8 * cg + 2];
      hnew[i][3] = h0.w + o[i][3] + sb2v[8 * cg + 3];
      hnew[i][4] = h1.x + o[i][4] + sb2v[8 * cg + 4];
      hnew[i][5] = h1.y + o[i][5] + sb2v[8 * cg + 5];
      hnew[i][6] = h1.z + o[i][6] + sb2v[8 * cg + 6];
      hnew[i][7] = h1.w + o[i][7] + sb2v[8 * cg + 7];
      float4 s0, s1;
      s0.x = hnew[i][0]; s0.y = hnew[i][1]; s0.z = hnew[i][2]; s0.w = hnew[i][3];
      s1.x = hnew[i][4]; s1.y = hnew[i][5]; s1.z = hnew[i][6]; s1.w = hnew[i][7];
      hp[0] = s0; hp[1] = s1;
    } else {
#pragma unroll
      for (int j = 0; j < 8; j++) hnew[i][j] = 0.f;
    }
  }

  if (PREMUL) {
    __syncthreads();  // all o-GEMM sA reads done
#pragma unroll
    for (int j = 0; j < 8; j++)
#pragma unroll
      for (int i = 0; i < 4; i++) sA[(8 * cg + j) * ASTR + (4 * rg + i)] = hnew[i][j];
    for (int i = t; i < 4096; i += 256) sW[i] = W1n[i];
    __syncthreads();
    float aP[4][8];
#pragma unroll
    for (int i = 0; i < 4; i++)
#pragma unroll
      for (int j = 0; j < 8; j++) aP[i][j] = 0.f;
#pragma unroll 8
    for (int k = 0; k < 64; k++) {
      float4 a = sA4[k * (ASTR / 4) + rg];
      float4 w0 = sW4[k * 16 + 2 * cg];
      float4 w1 = sW4[k * 16 + 2 * cg + 1];
#pragma unroll
      for (int i = 0; i < 4; i++) {
        float av = (i == 0) ? a.x : (i == 1) ? a.y : (i == 2) ? a.z : a.w;
        aP[i][0] += av * w0.x; aP[i][1] += av * w0.y;
        aP[i][2] += av * w0.z; aP[i][3] += av * w0.w;
        aP[i][4] += av * w1.x; aP[i][5] += av * w1.y;
        aP[i][6] += av * w1.z; aP[i][7] += av * w1.w;
      }
    }
#pragma unroll
    for (int i = 0; i < 4; i++) {
      int n = n0 + 4 * rg + i;
      if (n < N) {
        float4 o0, o1;
        o0.x = aP[i][0]; o0.y = aP[i][1]; o0.z = aP[i][2]; o0.w = aP[i][3];
        o1.x = aP[i][4]; o1.y = aP[i][5]; o1.z = aP[i][6]; o1.w = aP[i][7];
        float4* Pp = (float4*)(P + (size_t)n * 64 + 8 * cg);
        Pp[0] = o0; Pp[1] = o1;
      }
    }
    __syncthreads();
    for (int i = t; i < 4096; i += 256) sW[i] = W1n[4096 + i];
    __syncthreads();
    float aQ[4][8];
#pragma unroll
    for (int i = 0; i < 4; i++)
#pragma unroll
      for (int j = 0; j < 8; j++) aQ[i][j] = 0.f;
#pragma unroll 8
    for (int k = 0; k < 64; k++) {
      float4 a = sA4[k * (ASTR / 4) + rg];
      float4 w0 = sW4[k * 16 + 2 * cg];
      float4 w1 = sW4[k * 16 + 2 * cg + 1];
#pragma unroll
      for (int i = 0; i < 4; i++) {
        float av = (i == 0) ? a.x : (i == 1) ? a.y : (i == 2) ? a.z : a.w;
        aQ[i][0] += av * w0.x; aQ[i][1] += av * w0.y;
        aQ[i][2] += av * w0.z; aQ[i][3] += av * w0.w;
        aQ[i][4] += av * w1.x; aQ[i][5] += av * w1.y;
        aQ[i][6] += av * w1.z; aQ[i][7] += av * w1.w;
      }
    }
#pragma unroll
    for (int i = 0; i < 4; i++) {
      int n = n0 + 4 * rg + i;
      if (n < N) {
        float4 o0, o1;
        o0.x = aQ[i][0]; o0.y = aQ[i][1]; o0.z = aQ[i][2]; o0.w = aQ[i][3];
        o1.x = aQ[i][4]; o1.y = aQ[i][5]; o1.z = aQ[i][6]; o1.w = aQ[i][7];
        float4* Qp = (float4*)(Q + (size_t)n * 64 + 8 * cg);
        Qp[0] = o0; Qp[1] = o1;
      }
    }
  }
}

// ---------------- CSR build ----------------
__global__ __launch_bounds__(256) void hist_kernel(
    const int* __restrict__ row, int* __restrict__ cnt, int E)
{
  int e = blockIdx.x * 256 + threadIdx.x;
  if (e < E) atomicAdd(&cnt[row[e]], 1);
}

__global__ __launch_bounds__(1024) void scan_kernel(
    const int* __restrict__ cnt, int* __restrict__ rowptr, int* __restrict__ cursor, int N, int E)
{
  __shared__ int part[1024];
  int t = threadIdx.x;
  int chunk = (N + 1023) >> 10;
  int lo = t * chunk;
  int hi = lo + chunk;
  if (lo > N) lo = N;
  if (hi > N) hi = N;
  int s = 0;
  for (int i = lo; i < hi; i++) s += cnt[i];
  part[t] = s;
  __syncthreads();
  for (int off = 1; off < 1024; off <<= 1) {
    int v = 0;
    if (t >= off) v = part[t - off];
    __syncthreads();
    if (t >= off) part[t] += v;
    __syncthreads();
  }
  int run = part[t] - s;
  for (int i = lo; i < hi; i++) {
    rowptr[i] = run;
    cursor[i] = run;
    run += cnt[i];
  }
  if (t == 0) rowptr[N] = E;
}

__global__ __launch_bounds__(256) void scatter_kernel(
    const int* __restrict__ row, const int* __restrict__ col, const float* __restrict__ eattr,
    int* __restrict__ cursor, int* __restrict__ srow, int* __restrict__ scol,
    float* __restrict__ sea4, int E)
{
  int e = blockIdx.x * 256 + threadIdx.x;
  if (e >= E) return;
  int r = row[e];
  int p = atomicAdd(&cursor[r], 1);
  srow[p] = r;
  scol[p] = col[e];
  float4 v;
  v.x = eattr[(size_t)e * 3 + 0];
  v.y = eattr[(size_t)e * 3 + 1];
  v.z = eattr[(size_t)e * 3 + 2];
  v.w = 0.f;
  ((float4*)sea4)[p] = v;
}

// ---------------- weight prep: bf16 hi/lo of W^T ----------------
__global__ __launch_bounds__(256) void prep_wt_kernel(
    const float* __restrict__ W2all, const float* __restrict__ C1all,
    ushort* __restrict__ w2h, ushort* __restrict__ w2l,
    ushort* __restrict__ c1h, ushort* __restrict__ c1l)
{
  int idx = blockIdx.x * 256 + threadIdx.x;
  if (idx >= 4 * 4096) return;
  int layer = idx >> 12, rem = idx & 4095;
  int k = rem >> 6, c = rem & 63;
  int oidx = layer * 4096 + c * 64 + k;
  ushort h, l;
  bf16_split(W2all[idx], h, l);
  w2h[oidx] = h; w2l[oidx] = l;
  if (layer < 3) {
    bf16_split(C1all[idx], h, l);
    c1h[oidx] = h; c1l[oidx] = l;
  }
}

// ---------------- fused edge kernel (MFMA, operand-swapped) ----------------
#define EB 128

__device__ __forceinline__ bshort8 lds_frag(const ushort* base, int edge, int kb)
{
  int byte = edge * 128 + kb * 2;
  byte ^= (edge & 7) << 4;
  return *(const bshort8*)((const char*)base + byte);
}

template <int COORD>
__global__ __launch_bounds__(256) void edge_fused_kernel(
    const int* __restrict__ srow, const int* __restrict__ scol, const int* __restrict__ rowptr,
    const float* __restrict__ posr, float* __restrict__ posw,
    const float* __restrict__ sea4,
    const float* __restrict__ P, const float* __restrict__ Q,
    const float* __restrict__ W1t, const float* __restrict__ b1,
    const ushort* __restrict__ w2h, const ushort* __restrict__ w2l,
    const float* __restrict__ b2,
    const ushort* __restrict__ c1h, const ushort* __restrict__ c1l,
    const float* __restrict__ cb1, const float* __restrict__ cW2,
    const float* __restrict__ cb2,
    float* __restrict__ agg, int E)
{
  __shared__ ushort sUhi[EB * 64];  // [edge][k] bf16 hi, XOR-swizzled rows
  __shared__ ushort sUlo[EB * 64];
  __shared__ float sW1t[4 * 64];
  __shared__ float sb1v[64], sb2v[64];
  __shared__ float sDiff[3][EB];
  __shared__ float sWe[EB];
  __shared__ int sShare[COORD ? EB * 4 : EB];  // s_srow then sPart
  __shared__ float scb1v[COORD ? 64 : 1];
  __shared__ float scW2v[COORD ? 64 : 1];
  __shared__ int sSlotCnt[2];
  __shared__ int sSlotStart[EB + 2];
  __shared__ int sSlotRowF[EB];

  int* s_srow = sShare;
  float* sPart = (float*)sShare;

  int t = threadIdx.x;
  sW1t[t] = W1t[t];
  if (t < 64) { sb1v[t] = b1[t]; sb2v[t] = b2[t]; }
  if (COORD && t >= 64 && t < 128) { scb1v[t - 64] = cb1[t - 64]; scW2v[t - 64] = cW2[t - 64]; }
  __syncthreads();

  int e0 = blockIdx.x * EB;
  int nE = E - e0; if (nE > EB) nE = EB;

  // ---- stage 1: u tile -> bf16 hi/lo, conflict-free b128 writes ----
#pragma unroll
  for (int p = 0; p < 4; p++) {
    int eloc = p * 32 + (t >> 3);
    int ks = t & 7;
    int e = e0 + eloc;
    int base = eloc * 128 + ks * 16;
    int swz = (eloc & 7) << 4;
    if (e < E) {
      int r = srow[e];
      int c = scol[e];
      float prx = posr[(size_t)r * 3 + 0], pry = posr[(size_t)r * 3 + 1],
            prz = posr[(size_t)r * 3 + 2];
      float pcx = posr[(size_t)c * 3 + 0], pcy = posr[(size_t)c * 3 + 1],
            pcz = posr[(size_t)c * 3 + 2];
      float dx = prx - pcx, dy = pry - pcy, dz = prz - pcz;
      float dist = sqrtf(dx * dx + dy * dy + dz * dz);
      if (ks == 0) {
        s_srow[eloc] = r;
        sDiff[0][eloc] = dx; sDiff[1][eloc] = dy; sDiff[2][eloc] = dz;
      }
      float4 ea = ((const float4*)sea4)[e];
      const float4* P4p = (const float4*)(P + (size_t)r * 64) + ks * 2;
      const float4* Q4p = (const float4*)(Q + (size_t)c * 64) + ks * 2;
      float4 a0 = P4p[0], a1 = P4p[1];
      float4 q0 = Q4p[0], q1 = Q4p[1];
      float pa[8] = {a0.x, a0.y, a0.z, a0.w, a1.x, a1.y, a1.z, a1.w};
      float qa[8] = {q0.x, q0.y, q0.z, q0.w, q1.x, q1.y, q1.z, q1.w};
      ushort hh[8], ll[8];
#pragma unroll
      for (int kk = 0; kk < 8; kk++) {
        int k = ks * 8 + kk;
        float val = pa[kk] + qa[kk] + sb1v[k] + dist * sW1t[k] + ea.x * sW1t[64 + k] +
                    ea.y * sW1t[128 + k] + ea.z * sW1t[192 + k];
        float uv = silu_f(val);
        bf16_split(uv, hh[kk], ll[kk]);
      }
      uint4 hv, lv;
      hv.x = (uint)hh[0] | ((uint)hh[1] << 16);
      hv.y = (uint)hh[2] | ((uint)hh[3] << 16);
      hv.z = (uint)hh[4] | ((uint)hh[5] << 16);
      hv.w = (uint)hh[6] | ((uint)hh[7] << 16);
      lv.x = (uint)ll[0] | ((uint)ll[1] << 16);
      lv.y = (uint)ll[2] | ((uint)ll[3] << 16);
      lv.z = (uint)ll[4] | ((uint)ll[5] << 16);
      lv.w = (uint)ll[6] | ((uint)ll[7] << 16);
      *(uint4*)((char*)sUhi + (base ^ swz)) = hv;
      *(uint4*)((char*)sUlo + (base ^ swz)) = lv;
    } else {
      uint4 z; z.x = 0; z.y = 0; z.z = 0; z.w = 0;
      *(uint4*)((char*)sUhi + (base ^ swz)) = z;
      *(uint4*)((char*)sUlo + (base ^ swz)) = z;
    }
  }
  __syncthreads();

  // ---- phase A: slot ballot (waves 0,1 cover edges 0..127) ----
  bool isstart = false;
  int pre = 0;
  if (t < 128) {
    int le = t;
    isstart = (le < nE) && (le == 0 || s_srow[le] != s_srow[le - 1]);
    unsigned long long m = __ballot(isstart ? 1 : 0);
    int lane = t & 63;
    pre = __popcll(m & ((lane == 0) ? 0ull : ((~0ull) >> (64 - lane))));
    if (lane == 0) sSlotCnt[t >> 6] = __popcll(m);
  }
  __syncthreads();
  if (t < 128 && isstart) {
    int le = t;
    int slot = ((t >> 6) ? sSlotCnt[0] : 0) + pre;
    int row = s_srow[le];
    sSlotStart[slot] = le;
    int rs = rowptr[row], re = rowptr[row + 1];
    int interior = (rs >= e0 && re <= e0 + nE) ? 1 : 0;
    sSlotRowF[slot] = row | (interior << 30);
  }
  if (t == 0) sSlotStart[sSlotCnt[0] + sSlotCnt[1]] = nE;
  // published by stage-2's internal barrier

  // ---- stage 2: m^T = W2^T · u^T (operand-swapped MFMA, bf16 3-split) ----
  int l = t & 63;
  int wv = t >> 6;      // col-tile: cols wv*16 .. +15
  int lane16 = l & 15;  // edge-in-tile (B) / weight-row-in-tile (A)
  int kq = l >> 4;      // k-octet quarter

  {
    const ushort* bhp = w2h + (wv * 16 + lane16) * 64 + kq * 8;
    const ushort* blp = w2l + (wv * 16 + lane16) * 64 + kq * 8;
    bshort8 wh0 = *(const bshort8*)(bhp);
    bshort8 wh1 = *(const bshort8*)(bhp + 32);
    bshort8 wl0 = *(const bshort8*)(blp);
    bshort8 wl1 = *(const bshort8*)(blp + 32);

    f32x4 acc[8];
#pragma unroll
    for (int et = 0; et < 8; et++) {
      int edge = et * 16 + lane16;
      bshort8 uh0 = lds_frag(sUhi, edge, kq * 8);
      bshort8 uh1 = lds_frag(sUhi, edge, 32 + kq * 8);
      bshort8 ul0 = lds_frag(sUlo, edge, kq * 8);
      bshort8 ul1 = lds_frag(sUlo, edge, 32 + kq * 8);
      f32x4 a = {0.f, 0.f, 0.f, 0.f};
      a = __builtin_amdgcn_mfma_f32_16x16x32_bf16(wh0, uh0, a, 0, 0, 0);
      a = __builtin_amdgcn_mfma_f32_16x16x32_bf16(wh1, uh1, a, 0, 0, 0);
      a = __builtin_amdgcn_mfma_f32_16x16x32_bf16(wh0, ul0, a, 0, 0, 0);
      a = __builtin_amdgcn_mfma_f32_16x16x32_bf16(wh1, ul1, a, 0, 0, 0);
      a = __builtin_amdgcn_mfma_f32_16x16x32_bf16(wl0, uh0, a, 0, 0, 0);
      a = __builtin_amdgcn_mfma_f32_16x16x32_bf16(wl1, uh1, a, 0, 0, 0);
      acc[et] = a;
    }
    __syncthreads();  // all u reads done; also publishes slot tables

    float b2r[4];
#pragma unroll
    for (int r = 0; r < 4; r++) b2r[r] = sb2v[wv * 16 + kq * 4 + r];
#pragma unroll
    for (int et = 0; et < 8; et++) {
      int edge = et * 16 + lane16;
      ushort mh[4], ml[4];
#pragma unroll
      for (int r = 0; r < 4; r++) {
        float mv = silu_f(acc[et][r] + b2r[r]);
        bf16_split(mv, mh[r], ml[r]);
      }
      int byte = (edge * 128 + (wv * 16 + kq * 4) * 2) ^ ((edge & 7) << 4);
      uint2 hv, lv;
      hv.x = (uint)mh[0] | ((uint)mh[1] << 16);
      hv.y = (uint)mh[2] | ((uint)mh[3] << 16);
      lv.x = (uint)ml[0] | ((uint)ml[1] << 16);
      lv.y = (uint)ml[2] | ((uint)ml[3] << 16);
      *(uint2*)((char*)sUhi + byte) = hv;
      *(uint2*)((char*)sUlo + byte) = lv;
    }
  }
  __syncthreads();

  // ---- stage 3 (COORD): v^T = cW1^T · m^T (m hi-only), in-thread reduce ----
  if (COORD) {
    const ushort* chp = c1h + (wv * 16 + lane16) * 64 + kq * 8;
    const ushort* clp = c1l + (wv * 16 + lane16) * 64 + kq * 8;
    bshort8 ch0 = *(const bshort8*)(chp);
    bshort8 ch1 = *(const bshort8*)(chp + 32);
    bshort8 cl0 = *(const bshort8*)(clp);
    bshort8 cl1 = *(const bshort8*)(clp + 32);
    float cb1r[4], cw2r[4];
#pragma unroll
    for (int r = 0; r < 4; r++) {
      cb1r[r] = scb1v[wv * 16 + kq * 4 + r];
      cw2r[r] = scW2v[wv * 16 + kq * 4 + r];
    }
#pragma unroll
    for (int et = 0; et < 8; et++) {
      int edge = et * 16 + lane16;
      bshort8 mh0 = lds_frag(sUhi, edge, kq * 8);
      bshort8 mh1 = lds_frag(sUhi, edge, 32 + kq * 8);
      f32x4 a = {0.f, 0.f, 0.f, 0.f};
      a = __builtin_amdgcn_mfma_f32_16x16x32_bf16(ch0, mh0, a, 0, 0, 0);
      a = __builtin_amdgcn_mfma_f32_16x16x32_bf16(ch1, mh1, a, 0, 0, 0);
      a = __builtin_amdgcn_mfma_f32_16x16x32_bf16(cl0, mh0, a, 0, 0, 0);
      a = __builtin_amdgcn_mfma_f32_16x16x32_bf16(cl1, mh1, a, 0, 0, 0);
      float pr = 0.f;
#pragma unroll
      for (int r = 0; r < 4; r++) pr += silu_f(a[r] + cb1r[r]) * cw2r[r];
      pr += __shfl_xor(pr, 16);
      pr += __shfl_xor(pr, 32);
      if (kq == 0) sPart[edge * 4 + wv] = pr;
    }
  }
  __syncthreads();
  if (COORD) {
    if (t >= 128) {
      int e = t - 128;
      sWe[e] = sPart[4 * e + 0] + sPart[4 * e + 1] + sPart[4 * e + 2] + sPart[4 * e + 3] + cb2[0];
    }
  }
  __syncthreads();

  // ---- stage 4: slot-based segmented reductions ----
  int nslots = sSlotCnt[0] + sSlotCnt[1];
  for (int task = t; task < (nslots << 5); task += 256) {
    int s = task >> 5, cp = task & 31;  // channel pair 2cp, 2cp+1
    int a = sSlotStart[s], b = sSlotStart[s + 1];
    float acc0 = 0.f, acc1 = 0.f;
    for (int le = a; le < b; le++) {
      int byte = (le * 128 + cp * 4) ^ ((le & 7) << 4);
      uint hv = *(const uint*)((const char*)sUhi + byte);
      uint lv = *(const uint*)((const char*)sUlo + byte);
      acc0 += __uint_as_float(hv << 16) + __uint_as_float(lv << 16);
      acc1 += __uint_as_float(hv & 0xffff0000u) + __uint_as_float(lv & 0xffff0000u);
    }
    int rowf = sSlotRowF[s];
    int row = rowf & 0x3fffffff;
    float* ap = agg + (size_t)row * 64 + 2 * cp;
    if (rowf & (1 << 30)) {
      ap[0] = acc0; ap[1] = acc1;
    } else {
      atomicAdd(ap, acc0);
      atomicAdd(ap + 1, acc1);
    }
  }
  if (COORD) {
    for (int task = t; task < (nslots << 2); task += 256) {
      int s = task >> 2, d = task & 3;
      if (d < 3) {
        int a = sSlotStart[s], b = sSlotStart[s + 1];
        float acc = 0.f;
        for (int le = a; le < b; le++) acc += sDiff[d][le] * sWe[le];
        int row = sSlotRowF[s] & 0x3fffffff;
        atomicAdd(&posw[(size_t)row * 3 + d], acc);
      }
    }
  }
}

// ---------------- pooling + classifier ----------------
__device__ __forceinline__ int lbound(const int* __restrict__ a, int n, int v)
{
  int lo = 0, hi = n;
  while (lo < hi) {
    int mid = (lo + hi) >> 1;
    if (a[mid] < v) lo = mid + 1;
    else hi = mid;
  }
  return lo;
}

__global__ __launch_bounds__(256) void pool_cls_kernel(
    const float* __restrict__ h, const int* __restrict__ batch, int N,
    const float* __restrict__ W1, const float* __restrict__ b1,
    const float* __restrict__ W2, const float* __restrict__ b2, float* __restrict__ out)
{
  int g = blockIdx.x;
  int start = lbound(batch, N, g);
  int end = lbound(batch, N, g + 1);
  int j = threadIdx.x & 63;
  int grp = threadIdx.x >> 6;
  float s = 0.f, mx = -INFINITY;
  for (int n = start + grp; n < end; n += 4) {
    float v = h[(size_t)n * 64 + j];
    s += v;
    mx = fmaxf(mx, v);
  }
  __shared__ float ssum[4][64];
  __shared__ float smax[4][64];
  __shared__ float pooled[128];
  __shared__ float su[64];
  ssum[grp][j] = s;
  smax[grp][j] = mx;
  __syncthreads();
  if (grp == 0) {
    float S = ssum[0][j] + ssum[1][j] + ssum[2][j] + ssum[3][j];
    float M = fmaxf(fmaxf(smax[0][j], smax[1][j]), fmaxf(smax[2][j], smax[3][j]));
    float cnt = (float)(end - start);
    pooled[j] = S / fmaxf(cnt, 1.0f);
    pooled[64 + j] = M;
  }
  __syncthreads();
  if (threadIdx.x < 64) {
    float a = b1[j];
#pragma unroll
    for (int k = 0; k < 128; k++) a += pooled[k] * W1[k * 64 + j];
    su[j] = fmaxf(a, 0.f);
  }
  __syncthreads();
  if (threadIdx.x < 2) {
    float a = b2[threadIdx.x];
#pragma unroll
    for (int k = 0; k < 64; k++) a += su[k] * W2[k * 2 + threadIdx.x];
    out[g * 2 + threadIdx.x] = a;
  }
}

extern "C" void kernel_launch(void* const* d_in, const int* in_sizes, int n_in,
                              void* d_out, int out_size, void* d_ws, size_t ws_size,
                              hipStream_t stream)
{
  const float* x = (const float*)d_in[0];
  const float* pos = (const float*)d_in[1];
  const int* ei = (const int*)d_in[2];
  const float* eattr = (const float*)d_in[3];
  const int* batch = (const int*)d_in[4];
  const float* projW = (const float*)d_in[5];
  const float* projb = (const float*)d_in[6];
  const float* msgW1 = (const float*)d_in[7];
  const float* msgb1 = (const float*)d_in[8];
  const float* msgW2 = (const float*)d_in[9];
  const float* msgb2 = (const float*)d_in[10];
  const float* ndW1 = (const float*)d_in[11];
  const float* ndb1 = (const float*)d_in[12];
  const float* ndW2 = (const float*)d_in[13];
  const float* ndb2 = (const float*)d_in[14];
  const float* cdW1 = (const float*)d_in[15];
  const float* cdb1 = (const float*)d_in[16];
  const float* cdW2 = (const float*)d_in[17];
  const float* cdb2 = (const float*)d_in[18];
  const float* clsW1 = (const float*)d_in[19];
  const float* clsb1 = (const float*)d_in[20];
  const float* clsW2 = (const float*)d_in[21];
  const float* clsb2 = (const float*)d_in[22];

  int N = in_sizes[4];
  int E = in_sizes[3] / 3;
  const int* rowp = ei;
  const int* colp = ei + E;

  char* wsb = (char*)d_ws;
  size_t off = 0;
  auto alloc = [&](size_t bytes) {
    size_t o = off;
    off = (off + bytes + 255) & ~(size_t)255;
    return o;
  };
  size_t nh = (size_t)N * 64 * sizeof(float);
  size_t o_h = alloc(nh);
  size_t o_P = alloc(nh);
  size_t o_Q = alloc(nh);
  size_t o_agg = alloc(nh);
  size_t o_posA = alloc((size_t)N * 3 * sizeof(float));
  size_t o_posB = alloc((size_t)N * 3 * sizeof(float));
  size_t o_cnt = alloc((size_t)N * sizeof(int));
  size_t o_rowptr = alloc(((size_t)N + 1) * sizeof(int));
  size_t o_cursor = alloc((size_t)N * sizeof(int));
  size_t o_srow = alloc((size_t)E * sizeof(int));
  size_t o_scol = alloc((size_t)E * sizeof(int));
  size_t o_sea4 = alloc((size_t)E * 4 * sizeof(float));
  size_t o_w2h = alloc(4 * 4096 * sizeof(ushort));
  size_t o_w2l = alloc(4 * 4096 * sizeof(ushort));
  size_t o_c1h = alloc(4 * 4096 * sizeof(ushort));
  size_t o_c1l = alloc(4 * 4096 * sizeof(ushort));
  size_t csr_end = off;

  float* h = (float*)(wsb + o_h);
  float* Pb = (float*)(wsb + o_P);
  float* Qb = (float*)(wsb + o_Q);
  float* agg = (float*)(wsb + o_agg);
  float* posA = (float*)(wsb + o_posA);
  float* posB = (float*)(wsb + o_posB);

  int nb_nodes = (N + 255) / 256;
  int nb_edges = (E + 255) / 256;
  int nb_tiled = (N + NB - 1) / NB;
  int G = out_size / 2;

  proj_kernel<<<nb_nodes, 256, 0, stream>>>(x, projW, projb, h, N);

  const float* pr[4] = {pos, posA, posB, posA};
  float* pw[4] = {posA, posB, posA, nullptr};

  bool use_sorted = (csr_end <= ws_size);

  if (use_sorted) {
    int* cnt = (int*)(wsb + o_cnt);
    int* rowptr = (int*)(wsb + o_rowptr);
    int* cursor = (int*)(wsb + o_cursor);
    int* srow = (int*)(wsb + o_srow);
    int* scol = (int*)(wsb + o_scol);
    float* sea4 = (float*)(wsb + o_sea4);
    ushort* w2h = (ushort*)(wsb + o_w2h);
    ushort* w2l = (ushort*)(wsb + o_w2l);
    ushort* c1h = (ushort*)(wsb + o_c1h);
    ushort* c1l = (ushort*)(wsb + o_c1l);

    hipMemsetAsync(cnt, 0, (size_t)N * sizeof(int), stream);
    hist_kernel<<<nb_edges, 256, 0, stream>>>(rowp, cnt, E);
    scan_kernel<<<1, 1024, 0, stream>>>(cnt, rowptr, cursor, N, E);
    scatter_kernel<<<nb_edges, 256, 0, stream>>>(rowp, colp, eattr, cursor, srow, scol, sea4, E);
    prep_wt_kernel<<<64, 256, 0, stream>>>(msgW2, cdW1, w2h, w2l, c1h, c1l);

    // premul for layer 0; layers 1-3 fused into node_tiled
    premul_tiled_kernel<<<nb_tiled, 256, 0, stream>>>(h, msgW1, Pb, Qb, N);

    int nb_fused = (E + EB - 1) / EB;
    for (int i = 0; i < 4; i++) {
      hipMemsetAsync(agg, 0, nh, stream);
      if (i < 3) {
        hipMemcpyAsync(pw[i], pr[i], (size_t)N * 3 * sizeof(float), hipMemcpyDeviceToDevice,
                       stream);
        edge_fused_kernel<1><<<nb_fused, 256, 0, stream>>>(
            srow, scol, rowptr, pr[i], pw[i], sea4, Pb, Qb,
            msgW1 + (size_t)i * 132 * 64 + 128 * 64, msgb1 + i * 64,
            w2h + (size_t)i * 4096, w2l + (size_t)i * 4096, msgb2 + i * 64,
            c1h + (size_t)i * 4096, c1l + (size_t)i * 4096,
            cdb1 + i * 64, cdW2 + i * 64, cdb2 + i, agg, E);
        node_tiled_kernel<1><<<nb_tiled, 256, 0, stream>>>(
            h, agg, ndW1 + (size_t)i * 8192, ndb1 + i * 64, ndW2 + (size_t)i * 4096,
            ndb2 + i * 64, N, msgW1 + (size_t)(i + 1) * 132 * 64, Pb, Qb);
      } else {
        edge_fused_kernel<0><<<nb_fused, 256, 0, stream>>>(
            srow, scol, rowptr, pr[i], nullptr, sea4, Pb, Qb,
            msgW1 + (size_t)i * 132 * 64 + 128 * 64, msgb1 + i * 64,
            w2h + (size_t)i * 4096, w2l + (size_t)i * 4096, msgb2 + i * 64,
            nullptr, nullptr, nullptr, nullptr, nullptr, agg, E);
        node_tiled_kernel<0><<<nb_tiled, 256, 0, stream>>>(
            h, agg, ndW1 + (size_t)i * 8192, ndb1 + i * 64, ndW2 + (size_t)i * 4096,
            ndb2 + i * 64, N, nullptr, nullptr, nullptr);
      }
    }
  } else {
    for (int i = 0; i < 4; i++) {
      premul_tiled_kernel<<<nb_tiled, 256, 0, stream>>>(h, msgW1 + (size_t)i * 132 * 64, Pb, Qb,
                                                        N);
      hipMemsetAsync(agg, 0, nh, stream);
      node_tiled_kernel<0><<<nb_tiled, 256, 0, stream>>>(
          h, agg, ndW1 + (size_t)i * 8192, ndb1 + i * 64, ndW2 + (size_t)i * 4096, ndb2 + i * 64,
          N, nullptr, nullptr, nullptr);
    }
  }

  pool_cls_kernel<<<G, 256, 0, stream>>>(h, batch, N, clsW1, clsb1, clsW2, clsb2, (float*)d_out);
}

// Round 14
// 796.007 us; speedup vs baseline: 17.8306x; 1.1478x over previous
//
#include <hip/hip_runtime.h>
#include <math.h>

// EGNN forward. P/Q factorization + CSR sort + fused MFMA edge kernel.
// Round 14: node-side GEMMs (node MLP + fused premul + layer-0 premul) ported
// to the proven operand-swapped bf16-3-split MFMA template. Edge unchanged.

typedef __attribute__((ext_vector_type(8))) short bshort8;
typedef __attribute__((ext_vector_type(4))) float f32x4;
typedef unsigned short ushort;
typedef unsigned int uint;

__device__ __forceinline__ float silu_f(float x)
{
  return x * __builtin_amdgcn_rcpf(1.0f + __expf(-x));
}

__device__ __forceinline__ void bf16_split(float x, ushort& h, ushort& l)
{
  uint bx = __float_as_uint(x);
  ushort hb = (ushort)(bx >> 16);
  float hf = __uint_as_float((uint)hb << 16);
  float r = x - hf;
  l = (ushort)(__float_as_uint(r) >> 16);
  h = hb;
}

#define ROW_FMA(acc, scal, rowptr)                                                   \
  {                                                                                  \
    const float4* _w = (const float4*)(rowptr);                                      \
    _Pragma("unroll") for (int _j = 0; _j < 16; _j++)                                \
    {                                                                                \
      float4 _wv = _w[_j];                                                           \
      acc[4 * _j + 0] += (scal) * _wv.x;                                             \
      acc[4 * _j + 1] += (scal) * _wv.y;                                             \
      acc[4 * _j + 2] += (scal) * _wv.z;                                             \
      acc[4 * _j + 3] += (scal) * _wv.w;                                             \
    }                                                                                \
  }

// ---------------- proj ----------------
__global__ __launch_bounds__(256) void proj_kernel(
    const float* __restrict__ x, const float* __restrict__ W, const float* __restrict__ b,
    float* __restrict__ h, int N)
{
  __shared__ float sW[26 * 64];
  __shared__ float sb[64];
  for (int i = threadIdx.x; i < 26 * 64; i += 256) sW[i] = W[i];
  if (threadIdx.x < 64) sb[threadIdx.x] = b[threadIdx.x];
  __syncthreads();
  int n = blockIdx.x * 256 + threadIdx.x;
  if (n >= N) return;
  float acc[64];
#pragma unroll
  for (int j = 0; j < 64; j++) acc[j] = sb[j];
#pragma unroll
  for (int k = 0; k < 26; k++) {
    float xk = x[(size_t)n * 26 + k];
    ROW_FMA(acc, xk, sW + k * 64);
  }
  float4* h4 = (float4*)(h + (size_t)n * 64);
#pragma unroll
  for (int j4 = 0; j4 < 16; j4++) {
    float4 v;
    v.x = acc[4 * j4 + 0]; v.y = acc[4 * j4 + 1]; v.z = acc[4 * j4 + 2]; v.w = acc[4 * j4 + 3];
    h4[j4] = v;
  }
}

// ---------------- shared helpers for MFMA tile kernels ----------------
#define EB 128

__device__ __forceinline__ bshort8 lds_frag(const ushort* base, int edge, int kb)
{
  int byte = edge * 128 + kb * 2;
  byte ^= (edge & 7) << 4;
  return *(const bshort8*)((const char*)base + byte);
}

// stage a [128][64] fp32 tile -> bf16 hi/lo XOR-swizzled LDS (conflict-free b128)
__device__ __forceinline__ void stage_tile_f32(
    const float* __restrict__ src, int n0, int N, ushort* sHi, ushort* sLo, int t)
{
#pragma unroll
  for (int p = 0; p < 4; p++) {
    int nl = p * 32 + (t >> 3);
    int ks = t & 7;
    int n = n0 + nl;
    int base = nl * 128 + ks * 16;
    int swz = (nl & 7) << 4;
    if (n < N) {
      const float4* sp = (const float4*)(src + (size_t)n * 64) + ks * 2;
      float4 a0 = sp[0], a1 = sp[1];
      float va[8] = {a0.x, a0.y, a0.z, a0.w, a1.x, a1.y, a1.z, a1.w};
      ushort hh[8], ll[8];
#pragma unroll
      for (int kk = 0; kk < 8; kk++) bf16_split(va[kk], hh[kk], ll[kk]);
      uint4 hv, lv;
      hv.x = (uint)hh[0] | ((uint)hh[1] << 16);
      hv.y = (uint)hh[2] | ((uint)hh[3] << 16);
      hv.z = (uint)hh[4] | ((uint)hh[5] << 16);
      hv.w = (uint)hh[6] | ((uint)hh[7] << 16);
      lv.x = (uint)ll[0] | ((uint)ll[1] << 16);
      lv.y = (uint)ll[2] | ((uint)ll[3] << 16);
      lv.z = (uint)ll[4] | ((uint)ll[5] << 16);
      lv.w = (uint)ll[6] | ((uint)ll[7] << 16);
      *(uint4*)((char*)sHi + (base ^ swz)) = hv;
      *(uint4*)((char*)sLo + (base ^ swz)) = lv;
    } else {
      uint4 z; z.x = 0; z.y = 0; z.z = 0; z.w = 0;
      *(uint4*)((char*)sHi + (base ^ swz)) = z;
      *(uint4*)((char*)sLo + (base ^ swz)) = z;
    }
  }
}

// 3-split GEMM panel: acc[et] += Wt(col) · A(node) over one 64-k panel.
// Bh/Bl point at [col*kstride + koff + kq*8]; frags at +0 and +32.
#define PANEL_MFMA(accv, bhp, blp, sHi, sLo)                                         \
  {                                                                                  \
    bshort8 wh0 = *(const bshort8*)(bhp);                                            \
    bshort8 wh1 = *(const bshort8*)((bhp) + 32);                                     \
    bshort8 wl0 = *(const bshort8*)(blp);                                            \
    bshort8 wl1 = *(const bshort8*)((blp) + 32);                                     \
    _Pragma("unroll") for (int et = 0; et < 8; et++)                                 \
    {                                                                                \
      int nd = et * 16 + lane16;                                                     \
      bshort8 ah0 = lds_frag(sHi, nd, kq * 8);                                       \
      bshort8 ah1 = lds_frag(sHi, nd, 32 + kq * 8);                                  \
      bshort8 al0 = lds_frag(sLo, nd, kq * 8);                                       \
      bshort8 al1 = lds_frag(sLo, nd, 32 + kq * 8);                                  \
      f32x4 a = accv[et];                                                            \
      a = __builtin_amdgcn_mfma_f32_16x16x32_bf16(wh0, ah0, a, 0, 0, 0);             \
      a = __builtin_amdgcn_mfma_f32_16x16x32_bf16(wh1, ah1, a, 0, 0, 0);             \
      a = __builtin_amdgcn_mfma_f32_16x16x32_bf16(wh0, al0, a, 0, 0, 0);             \
      a = __builtin_amdgcn_mfma_f32_16x16x32_bf16(wh1, al1, a, 0, 0, 0);             \
      a = __builtin_amdgcn_mfma_f32_16x16x32_bf16(wl0, ah0, a, 0, 0, 0);             \
      a = __builtin_amdgcn_mfma_f32_16x16x32_bf16(wl1, ah1, a, 0, 0, 0);             \
      accv[et] = a;                                                                  \
    }                                                                                \
  }

// ---------------- MFMA premul (layer 0): P=h@W1[0:64], Q=h@W1[64:128] ----------------
__global__ __launch_bounds__(256) void premul_mfma_kernel(
    const float* __restrict__ h, const ushort* __restrict__ pqh, const ushort* __restrict__ pql,
    float* __restrict__ P, float* __restrict__ Q, int N)
{
  __shared__ ushort sAhi[EB * 64];
  __shared__ ushort sAlo[EB * 64];
  int t = threadIdx.x;
  int n0 = blockIdx.x * EB;
  stage_tile_f32(h, n0, N, sAhi, sAlo, t);
  __syncthreads();

  int l = t & 63, wv = t >> 6, lane16 = l & 15, kq = l >> 4;
  int col = wv * 16 + kq * 4;  // output channel base for this thread (rows of C)

  f32x4 acc[8];
#pragma unroll
  for (int et = 0; et < 8; et++) { f32x4 z = {0.f, 0.f, 0.f, 0.f}; acc[et] = z; }
  {
    const ushort* bh = pqh + (wv * 16 + lane16) * 64 + kq * 8;
    const ushort* bl = pql + (wv * 16 + lane16) * 64 + kq * 8;
    PANEL_MFMA(acc, bh, bl, sAhi, sAlo);
  }
#pragma unroll
  for (int et = 0; et < 8; et++) {
    int n = n0 + et * 16 + lane16;
    if (n < N) {
      float4 v; v.x = acc[et][0]; v.y = acc[et][1]; v.z = acc[et][2]; v.w = acc[et][3];
      *(float4*)(P + (size_t)n * 64 + col) = v;
    }
  }
#pragma unroll
  for (int et = 0; et < 8; et++) { f32x4 z = {0.f, 0.f, 0.f, 0.f}; acc[et] = z; }
  {
    const ushort* bh = pqh + 4096 + (wv * 16 + lane16) * 64 + kq * 8;
    const ushort* bl = pql + 4096 + (wv * 16 + lane16) * 64 + kq * 8;
    PANEL_MFMA(acc, bh, bl, sAhi, sAlo);
  }
#pragma unroll
  for (int et = 0; et < 8; et++) {
    int n = n0 + et * 16 + lane16;
    if (n < N) {
      float4 v; v.x = acc[et][0]; v.y = acc[et][1]; v.z = acc[et][2]; v.w = acc[et][3];
      *(float4*)(Q + (size_t)n * 64 + col) = v;
    }
  }
}

// ---------------- MFMA node MLP (+fused premul for next layer) ----------------
template <int PREMUL>
__global__ __launch_bounds__(256) void node_mfma_kernel(
    float* __restrict__ h, const float* __restrict__ agg,
    const ushort* __restrict__ n1h, const ushort* __restrict__ n1l,  // [col][128]
    const float* __restrict__ b1,
    const ushort* __restrict__ n2h, const ushort* __restrict__ n2l,  // [col][64]
    const float* __restrict__ b2,
    const ushort* __restrict__ pqh, const ushort* __restrict__ pql,  // next layer [2][col][64]
    float* __restrict__ P, float* __restrict__ Q, int N)
{
  __shared__ ushort sAhi[EB * 64];
  __shared__ ushort sAlo[EB * 64];
  __shared__ float sb1v[64], sb2v[64];
  int t = threadIdx.x;
  int n0 = blockIdx.x * EB;
  if (t < 64) { sb1v[t] = b1[t]; sb2v[t] = b2[t]; }

  stage_tile_f32(h, n0, N, sAhi, sAlo, t);
  __syncthreads();

  int l = t & 63, wv = t >> 6, lane16 = l & 15, kq = l >> 4;
  int col = wv * 16 + kq * 4;  // output-channel base held by this thread

  // u = silu([h,agg]@W1 + b1): panel 1 (h, k 0..63)
  f32x4 acc[8];
#pragma unroll
  for (int et = 0; et < 8; et++) { f32x4 z = {0.f, 0.f, 0.f, 0.f}; acc[et] = z; }
  {
    const ushort* bh = n1h + (wv * 16 + lane16) * 128 + kq * 8;
    const ushort* bl = n1l + (wv * 16 + lane16) * 128 + kq * 8;
    PANEL_MFMA(acc, bh, bl, sAhi, sAlo);
  }
  __syncthreads();  // done reading h tile
  stage_tile_f32(agg, n0, N, sAhi, sAlo, t);
  __syncthreads();
  // panel 2 (agg, k 64..127)
  {
    const ushort* bh = n1h + (wv * 16 + lane16) * 128 + 64 + kq * 8;
    const ushort* bl = n1l + (wv * 16 + lane16) * 128 + 64 + kq * 8;
    PANEL_MFMA(acc, bh, bl, sAhi, sAlo);
  }
  __syncthreads();  // done reading agg tile

  // u writeback (packed, swizzled)
  {
    float b1r[4];
#pragma unroll
    for (int r = 0; r < 4; r++) b1r[r] = sb1v[col + r];
#pragma unroll
    for (int et = 0; et < 8; et++) {
      int nd = et * 16 + lane16;
      ushort uh[4], ul[4];
#pragma unroll
      for (int r = 0; r < 4; r++) {
        float uv = silu_f(acc[et][r] + b1r[r]);
        bf16_split(uv, uh[r], ul[r]);
      }
      int byte = (nd * 128 + col * 2) ^ ((nd & 7) << 4);
      uint2 hv, lv;
      hv.x = (uint)uh[0] | ((uint)uh[1] << 16);
      hv.y = (uint)uh[2] | ((uint)uh[3] << 16);
      lv.x = (uint)ul[0] | ((uint)ul[1] << 16);
      lv.y = (uint)ul[2] | ((uint)ul[3] << 16);
      *(uint2*)((char*)sAhi + byte) = hv;
      *(uint2*)((char*)sAlo + byte) = lv;
    }
  }
  __syncthreads();

  // o = u @ W2 ; hnew = h + o + b2
#pragma unroll
  for (int et = 0; et < 8; et++) { f32x4 z = {0.f, 0.f, 0.f, 0.f}; acc[et] = z; }
  {
    const ushort* bh = n2h + (wv * 16 + lane16) * 64 + kq * 8;
    const ushort* bl = n2l + (wv * 16 + lane16) * 64 + kq * 8;
    PANEL_MFMA(acc, bh, bl, sAhi, sAlo);
  }
  uint2 hnh[8], hnl[8];  // packed hnew for PREMUL tile write
  {
    float b2r[4];
#pragma unroll
    for (int r = 0; r < 4; r++) b2r[r] = sb2v[col + r];
#pragma unroll
    for (int et = 0; et < 8; et++) {
      int n = n0 + et * 16 + lane16;
      float hn[4];
      if (n < N) {
        float4 hv = *(float4*)(h + (size_t)n * 64 + col);
        hn[0] = hv.x + acc[et][0] + b2r[0];
        hn[1] = hv.y + acc[et][1] + b2r[1];
        hn[2] = hv.z + acc[et][2] + b2r[2];
        hn[3] = hv.w + acc[et][3] + b2r[3];
        float4 sv; sv.x = hn[0]; sv.y = hn[1]; sv.z = hn[2]; sv.w = hn[3];
        *(float4*)(h + (size_t)n * 64 + col) = sv;
      } else {
        hn[0] = hn[1] = hn[2] = hn[3] = 0.f;
      }
      if (PREMUL) {
        ushort sh[4], sl[4];
#pragma unroll
        for (int r = 0; r < 4; r++) bf16_split(hn[r], sh[r], sl[r]);
        hnh[et].x = (uint)sh[0] | ((uint)sh[1] << 16);
        hnh[et].y = (uint)sh[2] | ((uint)sh[3] << 16);
        hnl[et].x = (uint)sl[0] | ((uint)sl[1] << 16);
        hnl[et].y = (uint)sl[2] | ((uint)sl[3] << 16);
      }
    }
  }

  if (PREMUL) {
    __syncthreads();  // done reading u tile
#pragma unroll
    for (int et = 0; et < 8; et++) {
      int nd = et * 16 + lane16;
      int byte = (nd * 128 + col * 2) ^ ((nd & 7) << 4);
      *(uint2*)((char*)sAhi + byte) = hnh[et];
      *(uint2*)((char*)sAlo + byte) = hnl[et];
    }
    __syncthreads();
    // P = hnew @ W1n[0:64]
#pragma unroll
    for (int et = 0; et < 8; et++) { f32x4 z = {0.f, 0.f, 0.f, 0.f}; acc[et] = z; }
    {
      const ushort* bh = pqh + (wv * 16 + lane16) * 64 + kq * 8;
      const ushort* bl = pql + (wv * 16 + lane16) * 64 + kq * 8;
      PANEL_MFMA(acc, bh, bl, sAhi, sAlo);
    }
#pragma unroll
    for (int et = 0; et < 8; et++) {
      int n = n0 + et * 16 + lane16;
      if (n < N) {
        float4 v; v.x = acc[et][0]; v.y = acc[et][1]; v.z = acc[et][2]; v.w = acc[et][3];
        *(float4*)(P + (size_t)n * 64 + col) = v;
      }
    }
    // Q = hnew @ W1n[64:128]
#pragma unroll
    for (int et = 0; et < 8; et++) { f32x4 z = {0.f, 0.f, 0.f, 0.f}; acc[et] = z; }
    {
      const ushort* bh = pqh + 4096 + (wv * 16 + lane16) * 64 + kq * 8;
      const ushort* bl = pql + 4096 + (wv * 16 + lane16) * 64 + kq * 8;
      PANEL_MFMA(acc, bh, bl, sAhi, sAlo);
    }
#pragma unroll
    for (int et = 0; et < 8; et++) {
      int n = n0 + et * 16 + lane16;
      if (n < N) {
        float4 v; v.x = acc[et][0]; v.y = acc[et][1]; v.z = acc[et][2]; v.w = acc[et][3];
        *(float4*)(Q + (size_t)n * 64 + col) = v;
      }
    }
  }
}

// ---------------- CSR build ----------------
__global__ __launch_bounds__(256) void hist_kernel(
    const int* __restrict__ row, int* __restrict__ cnt, int E)
{
  int e = blockIdx.x * 256 + threadIdx.x;
  if (e < E) atomicAdd(&cnt[row[e]], 1);
}

__global__ __launch_bounds__(1024) void scan_kernel(
    const int* __restrict__ cnt, int* __restrict__ rowptr, int* __restrict__ cursor, int N, int E)
{
  __shared__ int part[1024];
  int t = threadIdx.x;
  int chunk = (N + 1023) >> 10;
  int lo = t * chunk;
  int hi = lo + chunk;
  if (lo > N) lo = N;
  if (hi > N) hi = N;
  int s = 0;
  for (int i = lo; i < hi; i++) s += cnt[i];
  part[t] = s;
  __syncthreads();
  for (int off = 1; off < 1024; off <<= 1) {
    int v = 0;
    if (t >= off) v = part[t - off];
    __syncthreads();
    if (t >= off) part[t] += v;
    __syncthreads();
  }
  int run = part[t] - s;
  for (int i = lo; i < hi; i++) {
    rowptr[i] = run;
    cursor[i] = run;
    run += cnt[i];
  }
  if (t == 0) rowptr[N] = E;
}

__global__ __launch_bounds__(256) void scatter_kernel(
    const int* __restrict__ row, const int* __restrict__ col, const float* __restrict__ eattr,
    int* __restrict__ cursor, int* __restrict__ srow, int* __restrict__ scol,
    float* __restrict__ sea4, int E)
{
  int e = blockIdx.x * 256 + threadIdx.x;
  if (e >= E) return;
  int r = row[e];
  int p = atomicAdd(&cursor[r], 1);
  srow[p] = r;
  scol[p] = col[e];
  float4 v;
  v.x = eattr[(size_t)e * 3 + 0];
  v.y = eattr[(size_t)e * 3 + 1];
  v.z = eattr[(size_t)e * 3 + 2];
  v.w = 0.f;
  ((float4*)sea4)[p] = v;
}

// ---------------- weight prep: bf16 hi/lo transposed tables ----------------
__global__ __launch_bounds__(256) void prep_wt_kernel(
    const float* __restrict__ W2all, const float* __restrict__ C1all,
    ushort* __restrict__ w2h, ushort* __restrict__ w2l,
    ushort* __restrict__ c1h, ushort* __restrict__ c1l)
{
  int idx = blockIdx.x * 256 + threadIdx.x;
  if (idx >= 4 * 4096) return;
  int layer = idx >> 12, rem = idx & 4095;
  int k = rem >> 6, c = rem & 63;
  int oidx = layer * 4096 + c * 64 + k;
  ushort h, l;
  bf16_split(W2all[idx], h, l);
  w2h[oidx] = h; w2l[oidx] = l;
  if (layer < 3) {
    bf16_split(C1all[idx], h, l);
    c1h[oidx] = h; c1l[oidx] = l;
  }
}

__global__ __launch_bounds__(256) void prep_nd_kernel(
    const float* __restrict__ ndW1, const float* __restrict__ ndW2,
    const float* __restrict__ msgW1,
    ushort* __restrict__ n1h, ushort* __restrict__ n1l,
    ushort* __restrict__ n2h, ushort* __restrict__ n2l,
    ushort* __restrict__ pqh, ushort* __restrict__ pql)
{
  int idx = blockIdx.x * 256 + threadIdx.x;
  if (idx < 4 * 8192) {
    // ndW1[i][k][c], k<128 -> n1[i][c*128+k]
    int i = idx >> 13, rem = idx & 8191;
    int k = rem >> 6, c = rem & 63;
    ushort h, l;
    bf16_split(ndW1[idx], h, l);
    int o = i * 8192 + c * 128 + k;
    n1h[o] = h; n1l[o] = l;
  }
  if (idx < 4 * 4096) {
    int i = idx >> 12, rem = idx & 4095;
    int k = rem >> 6, c = rem & 63;
    ushort h, l;
    bf16_split(ndW2[idx], h, l);
    int o = i * 4096 + c * 64 + k;
    n2h[o] = h; n2l[o] = l;
  }
  if (idx < 4 * 8192) {
    // msgW1[i] rows 0..127 -> pq[i][k>=64][c*64+k%64]
    int i = idx >> 13, rem = idx & 8191;
    int k = rem >> 6, c = rem & 63;
    ushort h, l;
    bf16_split(msgW1[(size_t)i * 132 * 64 + k * 64 + c], h, l);
    int o = i * 8192 + (k >> 6) * 4096 + c * 64 + (k & 63);
    pqh[o] = h; pql[o] = l;
  }
}

// ---------------- fused edge kernel (unchanged from round 13) ----------------
template <int COORD>
__global__ __launch_bounds__(256) void edge_fused_kernel(
    const int* __restrict__ srow, const int* __restrict__ scol, const int* __restrict__ rowptr,
    const float* __restrict__ posr, float* __restrict__ posw,
    const float* __restrict__ sea4,
    const float* __restrict__ P, const float* __restrict__ Q,
    const float* __restrict__ W1t, const float* __restrict__ b1,
    const ushort* __restrict__ w2h, const ushort* __restrict__ w2l,
    const float* __restrict__ b2,
    const ushort* __restrict__ c1h, const ushort* __restrict__ c1l,
    const float* __restrict__ cb1, const float* __restrict__ cW2,
    const float* __restrict__ cb2,
    float* __restrict__ agg, int E)
{
  __shared__ ushort sUhi[EB * 64];
  __shared__ ushort sUlo[EB * 64];
  __shared__ float sW1t[4 * 64];
  __shared__ float sb1v[64], sb2v[64];
  __shared__ float sDiff[3][EB];
  __shared__ float sWe[EB];
  __shared__ int sShare[COORD ? EB * 4 : EB];  // s_srow then sPart
  __shared__ float scb1v[COORD ? 64 : 1];
  __shared__ float scW2v[COORD ? 64 : 1];
  __shared__ int sSlotCnt[2];
  __shared__ int sSlotStart[EB + 2];
  __shared__ int sSlotRowF[EB];

  int* s_srow = sShare;
  float* sPart = (float*)sShare;

  int t = threadIdx.x;
  sW1t[t] = W1t[t];
  if (t < 64) { sb1v[t] = b1[t]; sb2v[t] = b2[t]; }
  if (COORD && t >= 64 && t < 128) { scb1v[t - 64] = cb1[t - 64]; scW2v[t - 64] = cW2[t - 64]; }
  __syncthreads();

  int e0 = blockIdx.x * EB;
  int nE = E - e0; if (nE > EB) nE = EB;

  // ---- stage 1 ----
#pragma unroll
  for (int p = 0; p < 4; p++) {
    int eloc = p * 32 + (t >> 3);
    int ks = t & 7;
    int e = e0 + eloc;
    int base = eloc * 128 + ks * 16;
    int swz = (eloc & 7) << 4;
    if (e < E) {
      int r = srow[e];
      int c = scol[e];
      float prx = posr[(size_t)r * 3 + 0], pry = posr[(size_t)r * 3 + 1],
            prz = posr[(size_t)r * 3 + 2];
      float pcx = posr[(size_t)c * 3 + 0], pcy = posr[(size_t)c * 3 + 1],
            pcz = posr[(size_t)c * 3 + 2];
      float dx = prx - pcx, dy = pry - pcy, dz = prz - pcz;
      float dist = sqrtf(dx * dx + dy * dy + dz * dz);
      if (ks == 0) {
        s_srow[eloc] = r;
        sDiff[0][eloc] = dx; sDiff[1][eloc] = dy; sDiff[2][eloc] = dz;
      }
      float4 ea = ((const float4*)sea4)[e];
      const float4* P4p = (const float4*)(P + (size_t)r * 64) + ks * 2;
      const float4* Q4p = (const float4*)(Q + (size_t)c * 64) + ks * 2;
      float4 a0 = P4p[0], a1 = P4p[1];
      float4 q0 = Q4p[0], q1 = Q4p[1];
      float pa[8] = {a0.x, a0.y, a0.z, a0.w, a1.x, a1.y, a1.z, a1.w};
      float qa[8] = {q0.x, q0.y, q0.z, q0.w, q1.x, q1.y, q1.z, q1.w};
      ushort hh[8], ll[8];
#pragma unroll
      for (int kk = 0; kk < 8; kk++) {
        int k = ks * 8 + kk;
        float val = pa[kk] + qa[kk] + sb1v[k] + dist * sW1t[k] + ea.x * sW1t[64 + k] +
                    ea.y * sW1t[128 + k] + ea.z * sW1t[192 + k];
        float uv = silu_f(val);
        bf16_split(uv, hh[kk], ll[kk]);
      }
      uint4 hv, lv;
      hv.x = (uint)hh[0] | ((uint)hh[1] << 16);
      hv.y = (uint)hh[2] | ((uint)hh[3] << 16);
      hv.z = (uint)hh[4] | ((uint)hh[5] << 16);
      hv.w = (uint)hh[6] | ((uint)hh[7] << 16);
      lv.x = (uint)ll[0] | ((uint)ll[1] << 16);
      lv.y = (uint)ll[2] | ((uint)ll[3] << 16);
      lv.z = (uint)ll[4] | ((uint)ll[5] << 16);
      lv.w = (uint)ll[6] | ((uint)ll[7] << 16);
      *(uint4*)((char*)sUhi + (base ^ swz)) = hv;
      *(uint4*)((char*)sUlo + (base ^ swz)) = lv;
    } else {
      uint4 z; z.x = 0; z.y = 0; z.z = 0; z.w = 0;
      *(uint4*)((char*)sUhi + (base ^ swz)) = z;
      *(uint4*)((char*)sUlo + (base ^ swz)) = z;
    }
  }
  __syncthreads();

  // ---- phase A: slot ballot ----
  bool isstart = false;
  int pre = 0;
  if (t < 128) {
    int le = t;
    isstart = (le < nE) && (le == 0 || s_srow[le] != s_srow[le - 1]);
    unsigned long long m = __ballot(isstart ? 1 : 0);
    int lane = t & 63;
    pre = __popcll(m & ((lane == 0) ? 0ull : ((~0ull) >> (64 - lane))));
    if (lane == 0) sSlotCnt[t >> 6] = __popcll(m);
  }
  __syncthreads();
  if (t < 128 && isstart) {
    int le = t;
    int slot = ((t >> 6) ? sSlotCnt[0] : 0) + pre;
    int row = s_srow[le];
    sSlotStart[slot] = le;
    int rs = rowptr[row], re = rowptr[row + 1];
    int interior = (rs >= e0 && re <= e0 + nE) ? 1 : 0;
    sSlotRowF[slot] = row | (interior << 30);
  }
  if (t == 0) sSlotStart[sSlotCnt[0] + sSlotCnt[1]] = nE;

  // ---- stage 2: m^T = W2^T · u^T ----
  int l = t & 63;
  int wv = t >> 6;
  int lane16 = l & 15;
  int kq = l >> 4;

  {
    const ushort* bhp = w2h + (wv * 16 + lane16) * 64 + kq * 8;
    const ushort* blp = w2l + (wv * 16 + lane16) * 64 + kq * 8;
    bshort8 wh0 = *(const bshort8*)(bhp);
    bshort8 wh1 = *(const bshort8*)(bhp + 32);
    bshort8 wl0 = *(const bshort8*)(blp);
    bshort8 wl1 = *(const bshort8*)(blp + 32);

    f32x4 acc[8];
#pragma unroll
    for (int et = 0; et < 8; et++) {
      int edge = et * 16 + lane16;
      bshort8 uh0 = lds_frag(sUhi, edge, kq * 8);
      bshort8 uh1 = lds_frag(sUhi, edge, 32 + kq * 8);
      bshort8 ul0 = lds_frag(sUlo, edge, kq * 8);
      bshort8 ul1 = lds_frag(sUlo, edge, 32 + kq * 8);
      f32x4 a = {0.f, 0.f, 0.f, 0.f};
      a = __builtin_amdgcn_mfma_f32_16x16x32_bf16(wh0, uh0, a, 0, 0, 0);
      a = __builtin_amdgcn_mfma_f32_16x16x32_bf16(wh1, uh1, a, 0, 0, 0);
      a = __builtin_amdgcn_mfma_f32_16x16x32_bf16(wh0, ul0, a, 0, 0, 0);
      a = __builtin_amdgcn_mfma_f32_16x16x32_bf16(wh1, ul1, a, 0, 0, 0);
      a = __builtin_amdgcn_mfma_f32_16x16x32_bf16(wl0, uh0, a, 0, 0, 0);
      a = __builtin_amdgcn_mfma_f32_16x16x32_bf16(wl1, uh1, a, 0, 0, 0);
      acc[et] = a;
    }
    __syncthreads();

    float b2r[4];
#pragma unroll
    for (int r = 0; r < 4; r++) b2r[r] = sb2v[wv * 16 + kq * 4 + r];
#pragma unroll
    for (int et = 0; et < 8; et++) {
      int edge = et * 16 + lane16;
      ushort mh[4], ml[4];
#pragma unroll
      for (int r = 0; r < 4; r++) {
        float mv = silu_f(acc[et][r] + b2r[r]);
        bf16_split(mv, mh[r], ml[r]);
      }
      int byte = (edge * 128 + (wv * 16 + kq * 4) * 2) ^ ((edge & 7) << 4);
      uint2 hv, lv;
      hv.x = (uint)mh[0] | ((uint)mh[1] << 16);
      hv.y = (uint)mh[2] | ((uint)mh[3] << 16);
      lv.x = (uint)ml[0] | ((uint)ml[1] << 16);
      lv.y = (uint)ml[2] | ((uint)ml[3] << 16);
      *(uint2*)((char*)sUhi + byte) = hv;
      *(uint2*)((char*)sUlo + byte) = lv;
    }
  }
  __syncthreads();

  // ---- stage 3 (COORD) ----
  if (COORD) {
    const ushort* chp = c1h + (wv * 16 + lane16) * 64 + kq * 8;
    const ushort* clp = c1l + (wv * 16 + lane16) * 64 + kq * 8;
    bshort8 ch0 = *(const bshort8*)(chp);
    bshort8 ch1 = *(const bshort8*)(chp + 32);
    bshort8 cl0 = *(const bshort8*)(clp);
    bshort8 cl1 = *(const bshort8*)(clp + 32);
    float cb1r[4], cw2r[4];
#pragma unroll
    for (int r = 0; r < 4; r++) {
      cb1r[r] = scb1v[wv * 16 + kq * 4 + r];
      cw2r[r] = scW2v[wv * 16 + kq * 4 + r];
    }
#pragma unroll
    for (int et = 0; et < 8; et++) {
      int edge = et * 16 + lane16;
      bshort8 mh0 = lds_frag(sUhi, edge, kq * 8);
      bshort8 mh1 = lds_frag(sUhi, edge, 32 + kq * 8);
      f32x4 a = {0.f, 0.f, 0.f, 0.f};
      a = __builtin_amdgcn_mfma_f32_16x16x32_bf16(ch0, mh0, a, 0, 0, 0);
      a = __builtin_amdgcn_mfma_f32_16x16x32_bf16(ch1, mh1, a, 0, 0, 0);
      a = __builtin_amdgcn_mfma_f32_16x16x32_bf16(cl0, mh0, a, 0, 0, 0);
      a = __builtin_amdgcn_mfma_f32_16x16x32_bf16(cl1, mh1, a, 0, 0, 0);
      float pr = 0.f;
#pragma unroll
      for (int r = 0; r < 4; r++) pr += silu_f(a[r] + cb1r[r]) * cw2r[r];
      pr += __shfl_xor(pr, 16);
      pr += __shfl_xor(pr, 32);
      if (kq == 0) sPart[edge * 4 + wv] = pr;
    }
  }
  __syncthreads();
  if (COORD) {
    if (t >= 128) {
      int e = t - 128;
      sWe[e] = sPart[4 * e + 0] + sPart[4 * e + 1] + sPart[4 * e + 2] + sPart[4 * e + 3] + cb2[0];
    }
  }
  __syncthreads();

  // ---- stage 4: slot-based segmented reductions ----
  int nslots = sSlotCnt[0] + sSlotCnt[1];
  for (int task = t; task < (nslots << 5); task += 256) {
    int s = task >> 5, cp = task & 31;
    int a = sSlotStart[s], b = sSlotStart[s + 1];
    float acc0 = 0.f, acc1 = 0.f;
    for (int le = a; le < b; le++) {
      int byte = (le * 128 + cp * 4) ^ ((le & 7) << 4);
      uint hv = *(const uint*)((const char*)sUhi + byte);
      uint lv = *(const uint*)((const char*)sUlo + byte);
      acc0 += __uint_as_float(hv << 16) + __uint_as_float(lv << 16);
      acc1 += __uint_as_float(hv & 0xffff0000u) + __uint_as_float(lv & 0xffff0000u);
    }
    int rowf = sSlotRowF[s];
    int row = rowf & 0x3fffffff;
    float* ap = agg + (size_t)row * 64 + 2 * cp;
    if (rowf & (1 << 30)) {
      ap[0] = acc0; ap[1] = acc1;
    } else {
      atomicAdd(ap, acc0);
      atomicAdd(ap + 1, acc1);
    }
  }
  if (COORD) {
    for (int task = t; task < (nslots << 2); task += 256) {
      int s = task >> 2, d = task & 3;
      if (d < 3) {
        int a = sSlotStart[s], b = sSlotStart[s + 1];
        float acc = 0.f;
        for (int le = a; le < b; le++) acc += sDiff[d][le] * sWe[le];
        int row = sSlotRowF[s] & 0x3fffffff;
        atomicAdd(&posw[(size_t)row * 3 + d], acc);
      }
    }
  }
}

// ---------------- pooling + classifier ----------------
__device__ __forceinline__ int lbound(const int* __restrict__ a, int n, int v)
{
  int lo = 0, hi = n;
  while (lo < hi) {
    int mid = (lo + hi) >> 1;
    if (a[mid] < v) lo = mid + 1;
    else hi = mid;
  }
  return lo;
}

__global__ __launch_bounds__(256) void pool_cls_kernel(
    const float* __restrict__ h, const int* __restrict__ batch, int N,
    const float* __restrict__ W1, const float* __restrict__ b1,
    const float* __restrict__ W2, const float* __restrict__ b2, float* __restrict__ out)
{
  int g = blockIdx.x;
  int start = lbound(batch, N, g);
  int end = lbound(batch, N, g + 1);
  int j = threadIdx.x & 63;
  int grp = threadIdx.x >> 6;
  float s = 0.f, mx = -INFINITY;
  for (int n = start + grp; n < end; n += 4) {
    float v = h[(size_t)n * 64 + j];
    s += v;
    mx = fmaxf(mx, v);
  }
  __shared__ float ssum[4][64];
  __shared__ float smax[4][64];
  __shared__ float pooled[128];
  __shared__ float su[64];
  ssum[grp][j] = s;
  smax[grp][j] = mx;
  __syncthreads();
  if (grp == 0) {
    float S = ssum[0][j] + ssum[1][j] + ssum[2][j] + ssum[3][j];
    float M = fmaxf(fmaxf(smax[0][j], smax[1][j]), fmaxf(smax[2][j], smax[3][j]));
    float cnt = (float)(end - start);
    pooled[j] = S / fmaxf(cnt, 1.0f);
    pooled[64 + j] = M;
  }
  __syncthreads();
  if (threadIdx.x < 64) {
    float a = b1[j];
#pragma unroll
    for (int k = 0; k < 128; k++) a += pooled[k] * W1[k * 64 + j];
    su[j] = fmaxf(a, 0.f);
  }
  __syncthreads();
  if (threadIdx.x < 2) {
    float a = b2[threadIdx.x];
#pragma unroll
    for (int k = 0; k < 64; k++) a += su[k] * W2[k * 2 + threadIdx.x];
    out[g * 2 + threadIdx.x] = a;
  }
}

extern "C" void kernel_launch(void* const* d_in, const int* in_sizes, int n_in,
                              void* d_out, int out_size, void* d_ws, size_t ws_size,
                              hipStream_t stream)
{
  const float* x = (const float*)d_in[0];
  const float* pos = (const float*)d_in[1];
  const int* ei = (const int*)d_in[2];
  const float* eattr = (const float*)d_in[3];
  const int* batch = (const int*)d_in[4];
  const float* projW = (const float*)d_in[5];
  const float* projb = (const float*)d_in[6];
  const float* msgW1 = (const float*)d_in[7];
  const float* msgb1 = (const float*)d_in[8];
  const float* msgW2 = (const float*)d_in[9];
  const float* msgb2 = (const float*)d_in[10];
  const float* ndW1 = (const float*)d_in[11];
  const float* ndb1 = (const float*)d_in[12];
  const float* ndW2 = (const float*)d_in[13];
  const float* ndb2 = (const float*)d_in[14];
  const float* cdW1 = (const float*)d_in[15];
  const float* cdb1 = (const float*)d_in[16];
  const float* cdW2 = (const float*)d_in[17];
  const float* cdb2 = (const float*)d_in[18];
  const float* clsW1 = (const float*)d_in[19];
  const float* clsb1 = (const float*)d_in[20];
  const float* clsW2 = (const float*)d_in[21];
  const float* clsb2 = (const float*)d_in[22];

  int N = in_sizes[4];
  int E = in_sizes[3] / 3;
  const int* rowp = ei;
  const int* colp = ei + E;

  char* wsb = (char*)d_ws;
  size_t off = 0;
  auto alloc = [&](size_t bytes) {
    size_t o = off;
    off = (off + bytes + 255) & ~(size_t)255;
    return o;
  };
  size_t nh = (size_t)N * 64 * sizeof(float);
  size_t o_h = alloc(nh);
  size_t o_P = alloc(nh);
  size_t o_Q = alloc(nh);
  size_t o_agg = alloc(nh);
  size_t o_posA = alloc((size_t)N * 3 * sizeof(float));
  size_t o_posB = alloc((size_t)N * 3 * sizeof(float));
  size_t o_cnt = alloc((size_t)N * sizeof(int));
  size_t o_rowptr = alloc(((size_t)N + 1) * sizeof(int));
  size_t o_cursor = alloc((size_t)N * sizeof(int));
  size_t o_srow = alloc((size_t)E * sizeof(int));
  size_t o_scol = alloc((size_t)E * sizeof(int));
  size_t o_sea4 = alloc((size_t)E * 4 * sizeof(float));
  size_t o_w2h = alloc(4 * 4096 * sizeof(ushort));
  size_t o_w2l = alloc(4 * 4096 * sizeof(ushort));
  size_t o_c1h = alloc(4 * 4096 * sizeof(ushort));
  size_t o_c1l = alloc(4 * 4096 * sizeof(ushort));
  size_t o_n1h = alloc(4 * 8192 * sizeof(ushort));
  size_t o_n1l = alloc(4 * 8192 * sizeof(ushort));
  size_t o_n2h = alloc(4 * 4096 * sizeof(ushort));
  size_t o_n2l = alloc(4 * 4096 * sizeof(ushort));
  size_t o_pqh = alloc(4 * 8192 * sizeof(ushort));
  size_t o_pql = alloc(4 * 8192 * sizeof(ushort));
  size_t csr_end = off;

  float* h = (float*)(wsb + o_h);
  float* Pb = (float*)(wsb + o_P);
  float* Qb = (float*)(wsb + o_Q);
  float* agg = (float*)(wsb + o_agg);
  float* posA = (float*)(wsb + o_posA);
  float* posB = (float*)(wsb + o_posB);

  int nb_nodes = (N + 255) / 256;
  int nb_edges = (E + 255) / 256;
  int nb_tiled = (N + EB - 1) / EB;
  int G = out_size / 2;

  proj_kernel<<<nb_nodes, 256, 0, stream>>>(x, projW, projb, h, N);

  const float* pr[4] = {pos, posA, posB, posA};
  float* pw[4] = {posA, posB, posA, nullptr};

  bool use_sorted = (csr_end <= ws_size);

  if (use_sorted) {
    int* cnt = (int*)(wsb + o_cnt);
    int* rowptr = (int*)(wsb + o_rowptr);
    int* cursor = (int*)(wsb + o_cursor);
    int* srow = (int*)(wsb + o_srow);
    int* scol = (int*)(wsb + o_scol);
    float* sea4 = (float*)(wsb + o_sea4);
    ushort* w2h = (ushort*)(wsb + o_w2h);
    ushort* w2l = (ushort*)(wsb + o_w2l);
    ushort* c1h = (ushort*)(wsb + o_c1h);
    ushort* c1l = (ushort*)(wsb + o_c1l);
    ushort* n1h = (ushort*)(wsb + o_n1h);
    ushort* n1l = (ushort*)(wsb + o_n1l);
    ushort* n2h = (ushort*)(wsb + o_n2h);
    ushort* n2l = (ushort*)(wsb + o_n2l);
    ushort* pqh = (ushort*)(wsb + o_pqh);
    ushort* pql = (ushort*)(wsb + o_pql);

    hipMemsetAsync(cnt, 0, (size_t)N * sizeof(int), stream);
    hist_kernel<<<nb_edges, 256, 0, stream>>>(rowp, cnt, E);
    scan_kernel<<<1, 1024, 0, stream>>>(cnt, rowptr, cursor, N, E);
    scatter_kernel<<<nb_edges, 256, 0, stream>>>(rowp, colp, eattr, cursor, srow, scol, sea4, E);
    prep_wt_kernel<<<64, 256, 0, stream>>>(msgW2, cdW1, w2h, w2l, c1h, c1l);
    prep_nd_kernel<<<128, 256, 0, stream>>>(ndW1, ndW2, msgW1, n1h, n1l, n2h, n2l, pqh, pql);

    premul_mfma_kernel<<<nb_tiled, 256, 0, stream>>>(h, pqh, pql, Pb, Qb, N);

    int nb_fused = (E + EB - 1) / EB;
    for (int i = 0; i < 4; i++) {
      hipMemsetAsync(agg, 0, nh, stream);
      if (i < 3) {
        hipMemcpyAsync(pw[i], pr[i], (size_t)N * 3 * sizeof(float), hipMemcpyDeviceToDevice,
                       stream);
        edge_fused_kernel<1><<<nb_fused, 256, 0, stream>>>(
            srow, scol, rowptr, pr[i], pw[i], sea4, Pb, Qb,
            msgW1 + (size_t)i * 132 * 64 + 128 * 64, msgb1 + i * 64,
            w2h + (size_t)i * 4096, w2l + (size_t)i * 4096, msgb2 + i * 64,
            c1h + (size_t)i * 4096, c1l + (size_t)i * 4096,
            cdb1 + i * 64, cdW2 + i * 64, cdb2 + i, agg, E);
        node_mfma_kernel<1><<<nb_tiled, 256, 0, stream>>>(
            h, agg, n1h + (size_t)i * 8192, n1l + (size_t)i * 8192, ndb1 + i * 64,
            n2h + (size_t)i * 4096, n2l + (size_t)i * 4096, ndb2 + i * 64,
            pqh + (size_t)(i + 1) * 8192, pql + (size_t)(i + 1) * 8192, Pb, Qb, N);
      } else {
        edge_fused_kernel<0><<<nb_fused, 256, 0, stream>>>(
            srow, scol, rowptr, pr[i], nullptr, sea4, Pb, Qb,
            msgW1 + (size_t)i * 132 * 64 + 128 * 64, msgb1 + i * 64,
            w2h + (size_t)i * 4096, w2l + (size_t)i * 4096, msgb2 + i * 64,
            nullptr, nullptr, nullptr, nullptr, nullptr, agg, E);
        node_mfma_kernel<0><<<nb_tiled, 256, 0, stream>>>(
            h, agg, n1h + (size_t)i * 8192, n1l + (size_t)i * 8192, ndb1 + i * 64,
            n2h + (size_t)i * 4096, n2l + (size_t)i * 4096, ndb2 + i * 64,
            nullptr, nullptr, nullptr, nullptr, N);
      }
    }
  }

  pool_cls_kernel<<<G, 256, 0, stream>>>(h, batch, N, clsW1, clsb1, clsW2, clsb2, (float*)d_out);
}